// Round 1
// baseline (1591.099 us; speedup 1.0000x reference)
//
#include <hip/hip_runtime.h>
#include <math.h>

#define N_NODES 50000
#define N_EDGES 600000
#define H 128
#define G_GRAPHS 100
#define C_CLS 10

// ---------------- utility kernels ----------------

__global__ void fill_kernel(float* __restrict__ p, float v, int n) {
    int i = blockIdx.x * 256 + threadIdx.x;
    if (i < n) p[i] = v;
}

__global__ void count_kernel(const int* __restrict__ batch, int* __restrict__ counts, int n) {
    int i = blockIdx.x * 256 + threadIdx.x;
    if (i < n) atomicAdd(&counts[batch[i]], 1);
}

__global__ void scan_kernel(const int* __restrict__ counts, int* __restrict__ starts) {
    if (threadIdx.x == 0) {
        int acc = 0;
        for (int g = 0; g < G_GRAPHS; ++g) { starts[g] = acc; acc += counts[g]; }
    }
}

// ---------------- degree / norm ----------------

__global__ void edge_deg_kernel(const int* __restrict__ src, const int* __restrict__ dst,
                                const float* __restrict__ mask, float* __restrict__ deg, int ne) {
    int e = blockIdx.x * 256 + threadIdx.x;
    if (e >= ne) return;
    int s = src[e], d = dst[e];
    float c = mask[s] * mask[d];
    if (c != 0.f) unsafeAtomicAdd(&deg[d], c);   // counts < 2^24 -> exact
}

__global__ void norm_kernel(const float* __restrict__ deg, float* __restrict__ norm, int n) {
    int i = blockIdx.x * 256 + threadIdx.x;
    if (i < n) norm[i] = rsqrtf(deg[i]);
}

// ---------------- GEMM: out[n][128] = A[n][128] @ W[128][128] ----------------
// 64-row tile per block, A tile transposed in LDS (ds_read_b128 on fragments),
// W rows read as float4 (L2/L1 resident, all blocks share).

__global__ __launch_bounds__(256) void gemm128_kernel(const float* __restrict__ A,
                                                      const float* __restrict__ W,
                                                      float* __restrict__ out, int nrows) {
    __shared__ float sT[128][68];     // [k][r], pad to 68 (272B row stride, 16B aligned)
    int row0 = blockIdx.x * 64;
    int tid = threadIdx.x;
    for (int i = tid; i < 2048; i += 256) {   // 64 rows * 32 float4
        int r = i >> 5, c4 = i & 31;
        int row = row0 + r;
        float4 v = make_float4(0.f, 0.f, 0.f, 0.f);
        if (row < nrows) v = ((const float4*)(A + (size_t)row * H))[c4];
        sT[c4 * 4 + 0][r] = v.x; sT[c4 * 4 + 1][r] = v.y;
        sT[c4 * 4 + 2][r] = v.z; sT[c4 * 4 + 3][r] = v.w;
    }
    __syncthreads();
    int cg = tid & 31;   // cols cg*4 .. cg*4+3
    int rg = tid >> 5;   // rows rg*8 .. rg*8+7
    float acc[8][4];
#pragma unroll
    for (int i = 0; i < 8; ++i)
#pragma unroll
        for (int j = 0; j < 4; ++j) acc[i][j] = 0.f;

    for (int k = 0; k < 128; ++k) {
        float4 w4 = ((const float4*)(W + k * H))[cg];
        const float4* pa = (const float4*)(&sT[k][rg * 8]);
        float4 a0 = pa[0], a1 = pa[1];
        float av[8] = {a0.x, a0.y, a0.z, a0.w, a1.x, a1.y, a1.z, a1.w};
#pragma unroll
        for (int i = 0; i < 8; ++i) {
            acc[i][0] = fmaf(av[i], w4.x, acc[i][0]);
            acc[i][1] = fmaf(av[i], w4.y, acc[i][1]);
            acc[i][2] = fmaf(av[i], w4.z, acc[i][2]);
            acc[i][3] = fmaf(av[i], w4.w, acc[i][3]);
        }
    }
#pragma unroll
    for (int i = 0; i < 8; ++i) {
        int row = row0 + rg * 8 + i;
        if (row < nrows) {
            float4 o = make_float4(acc[i][0], acc[i][1], acc[i][2], acc[i][3]);
            ((float4*)(out + (size_t)row * H))[cg] = o;
        }
    }
}

// ---------------- score projection: xws[n] = dot(h[n], Ws) ----------------

__global__ void dotws_kernel(const float* __restrict__ h, const float* __restrict__ Ws,
                             float* __restrict__ xws, int n) {
    int node = blockIdx.x * 4 + (threadIdx.x >> 6);
    int lane = threadIdx.x & 63;
    if (node >= n) return;
    const float* row = h + (size_t)node * H;
    float a = row[lane] * Ws[lane] + row[lane + 64] * Ws[lane + 64];
#pragma unroll
    for (int o = 32; o > 0; o >>= 1) a += __shfl_down(a, o);
    if (lane == 0) xws[node] = a;
}

// ---------------- edge scatter (feature aggregation) ----------------

__global__ __launch_bounds__(256) void edge_agg_kernel(const float* __restrict__ xw,
        const int* __restrict__ src, const int* __restrict__ dst,
        const float* __restrict__ mask, const float* __restrict__ norm,
        float* __restrict__ agg, int ne) {
    int e = blockIdx.x * 2 + (threadIdx.x >> 7);
    if (e >= ne) return;
    int f = threadIdx.x & 127;
    int s = src[e], d = dst[e];
    float c = mask[s] * mask[d];
    if (c == 0.f) return;
    c *= norm[s] * norm[d];
    unsafeAtomicAdd(&agg[(size_t)d * H + f], xw[(size_t)s * H + f] * c);
}

__global__ void edge_aggs_kernel(const float* __restrict__ xws,
        const int* __restrict__ src, const int* __restrict__ dst,
        const float* __restrict__ mask, const float* __restrict__ norm,
        float* __restrict__ aggs, int ne) {
    int e = blockIdx.x * 256 + threadIdx.x;
    if (e >= ne) return;
    int s = src[e], d = dst[e];
    float c = mask[s] * mask[d];
    if (c == 0.f) return;
    unsafeAtomicAdd(&aggs[d], xws[s] * c * norm[s] * norm[d]);
}

// ---------------- combine ----------------

__global__ void combine_relu_kernel(float* __restrict__ hout, const float* __restrict__ xw,
        const float* __restrict__ norm, const float* __restrict__ b, int n) {
    int idx = blockIdx.x * 256 + threadIdx.x;
    if (idx >= n * H) return;
    int node = idx >> 7, f = idx & 127;
    float nv = norm[node];
    float v = hout[idx] + xw[idx] * nv * nv + b[f];
    hout[idx] = fmaxf(v, 0.f);
}

__global__ void score_kernel(const float* __restrict__ aggs, const float* __restrict__ xws,
        const float* __restrict__ norm, const float* __restrict__ bs,
        float* __restrict__ score, int n) {
    int i = blockIdx.x * 256 + threadIdx.x;
    if (i >= n) return;
    float nv = norm[i];
    score[i] = aggs[i] + xws[i] * nv * nv + bs[0];
}

// ---------------- top-k per graph (exact reference semantics) ----------------
// keep node i iff active and #{j active: s_j > s_i or (s_j==s_i and j<i)} < ceil(0.5*active)

__global__ __launch_bounds__(256) void topk_kernel(const float* __restrict__ score,
        const float* __restrict__ mask, const int* __restrict__ starts,
        const int* __restrict__ counts, float* __restrict__ nmask) {
    int g = blockIdx.x;
    int s0 = starts[g], cnt = counts[g];
    __shared__ float ssc[1024];
    __shared__ float red[256];
    bool useL = (cnt <= 1024);
    float la = 0.f;
    for (int i = threadIdx.x; i < cnt; i += 256) {
        float m = mask[s0 + i];
        float sc = (m > 0.f) ? score[s0 + i] : -INFINITY;
        if (useL) ssc[i] = sc;
        if (m > 0.f) la += 1.f;
    }
    red[threadIdx.x] = la;
    __syncthreads();
    for (int o = 128; o > 0; o >>= 1) {
        if (threadIdx.x < o) red[threadIdx.x] += red[threadIdx.x + o];
        __syncthreads();
    }
    int kk = (int)ceilf(0.5f * red[0]);
    for (int i = threadIdx.x; i < cnt; i += 256) {
        float sci = useL ? ssc[i] : ((mask[s0 + i] > 0.f) ? score[s0 + i] : -INFINITY);
        float nm = 0.f;
        if (sci != -INFINITY) {
            int rank = 0;
            for (int j = 0; j < cnt; ++j) {
                float scj = useL ? ssc[j] : ((mask[s0 + j] > 0.f) ? score[s0 + j] : -INFINITY);
                rank += (scj > sci || (scj == sci && j < i)) ? 1 : 0;
            }
            if (rank < kk) nm = mask[s0 + i];
        }
        nmask[s0 + i] = nm;
    }
}

// ---------------- gate ----------------

__global__ void gate_kernel(float* __restrict__ h, const float* __restrict__ score,
                            const float* __restrict__ nmask, int n) {
    int idx = blockIdx.x * 256 + threadIdx.x;
    if (idx >= n * H) return;
    int node = idx >> 7;
    h[idx] = h[idx] * tanhf(score[node]) * nmask[node];
}

// ---------------- readout (max || mean), accumulated into r ----------------

__global__ __launch_bounds__(128) void readout_kernel(const float* __restrict__ h,
        const float* __restrict__ mask, const int* __restrict__ starts,
        const int* __restrict__ counts, float* __restrict__ r) {
    int g = blockIdx.x;
    int f = threadIdx.x;
    int s0 = starts[g], cnt = counts[g];
    float s = 0.f, mx = -INFINITY, c = 0.f;
    for (int i = 0; i < cnt; ++i) {
        float m = mask[s0 + i];
        if (m > 0.f) {
            float v = h[(size_t)(s0 + i) * H + f];
            s += v; mx = fmaxf(mx, v); c += 1.f;
        }
    }
    float mean = s / fmaxf(c, 1.f);
    if (c == 0.f) mx = 0.f;
    r[(size_t)g * 2 * H + f] += mx;
    r[(size_t)g * 2 * H + H + f] += mean;
}

// ---------------- MLP head + log_softmax ----------------

__global__ __launch_bounds__(128) void mlp_kernel(const float* __restrict__ r,
        const float* __restrict__ Wl1, const float* __restrict__ bl1,
        const float* __restrict__ Wl2, const float* __restrict__ bl2,
        const float* __restrict__ Wl3, const float* __restrict__ bl3,
        float* __restrict__ out) {
    int g = blockIdx.x;
    int t = threadIdx.x;
    __shared__ float sz[256];
    __shared__ float sy1[128];
    __shared__ float sy2[64];
    __shared__ float sy3[10];
    __shared__ float sred[2];
    sz[t] = r[g * 256 + t];
    sz[t + 128] = r[g * 256 + 128 + t];
    __syncthreads();
    float a = bl1[t];
    for (int k = 0; k < 256; ++k) a = fmaf(sz[k], Wl1[k * 128 + t], a);
    sy1[t] = fmaxf(a, 0.f);
    __syncthreads();
    if (t < 64) {
        float a2 = bl2[t];
        for (int k = 0; k < 128; ++k) a2 = fmaf(sy1[k], Wl2[k * 64 + t], a2);
        sy2[t] = fmaxf(a2, 0.f);
    }
    __syncthreads();
    if (t < 10) {
        float a3 = bl3[t];
        for (int k = 0; k < 64; ++k) a3 = fmaf(sy2[k], Wl3[k * 10 + t], a3);
        sy3[t] = a3;
    }
    __syncthreads();
    if (t == 0) {
        float m = sy3[0];
        for (int c2 = 1; c2 < 10; ++c2) m = fmaxf(m, sy3[c2]);
        float se = 0.f;
        for (int c2 = 0; c2 < 10; ++c2) se += expf(sy3[c2] - m);
        sred[0] = m; sred[1] = logf(se);
    }
    __syncthreads();
    if (t < 10) out[g * 10 + t] = sy3[t] - sred[0] - sred[1];
}

// ---------------- launch ----------------

extern "C" void kernel_launch(void* const* d_in, const int* in_sizes, int n_in,
                              void* d_out, int out_size, void* d_ws, size_t ws_size,
                              hipStream_t stream) {
    const float* x     = (const float*)d_in[0];
    const int*   ei    = (const int*)d_in[1];
    const int*   batch = (const int*)d_in[2];
    const int* src  = ei;
    const int* dstp = ei + N_EDGES;
    const float* Wb[3]  = {(const float*)d_in[3], (const float*)d_in[7],  (const float*)d_in[11]};
    const float* bbv[3] = {(const float*)d_in[4], (const float*)d_in[8],  (const float*)d_in[12]};
    const float* Wsb[3] = {(const float*)d_in[5], (const float*)d_in[9],  (const float*)d_in[13]};
    const float* bsb[3] = {(const float*)d_in[6], (const float*)d_in[10], (const float*)d_in[14]};
    const float* Wl1 = (const float*)d_in[15];
    const float* bl1 = (const float*)d_in[16];
    const float* Wl2 = (const float*)d_in[17];
    const float* bl2 = (const float*)d_in[18];
    const float* Wl3 = (const float*)d_in[19];
    const float* bl3 = (const float*)d_in[20];
    float* out = (float*)d_out;

    // workspace carve (floats; everything 4B-aligned)
    float* fws = (float*)d_ws;
    size_t off = 0;
    float* hA    = fws + off; off += (size_t)N_NODES * H;
    float* hB    = fws + off; off += (size_t)N_NODES * H;
    float* xw    = fws + off; off += (size_t)N_NODES * H;
    float* score = fws + off; off += N_NODES;
    float* xws   = fws + off; off += N_NODES;
    float* aggs  = fws + off; off += N_NODES;
    float* deg   = fws + off; off += N_NODES;
    float* norm  = fws + off; off += N_NODES;
    float* mA    = fws + off; off += N_NODES;
    float* mB    = fws + off; off += N_NODES;
    float* rbuf  = fws + off; off += (size_t)G_GRAPHS * 2 * H;
    int* counts  = (int*)(fws + off); off += G_GRAPHS;
    int* starts  = (int*)(fws + off); off += G_GRAPHS;

    int nblkN  = (N_NODES + 255) / 256;
    int nblkNH = (N_NODES * H + 255) / 256;
    int nblkE  = (N_EDGES + 255) / 256;

    // graph segment structure (batch is sorted)
    hipMemsetAsync(counts, 0, G_GRAPHS * sizeof(int), stream);
    count_kernel<<<nblkN, 256, 0, stream>>>(batch, counts, N_NODES);
    scan_kernel<<<1, 64, 0, stream>>>(counts, starts);
    fill_kernel<<<nblkN, 256, 0, stream>>>(mA, 1.f, N_NODES);
    hipMemsetAsync(rbuf, 0, G_GRAPHS * 2 * H * sizeof(float), stream);

    const float* hin = x;
    float* hout = hA;
    const float* mcur = mA;
    float* mnext = mB;

    for (int blk = 0; blk < 3; ++blk) {
        // deg / norm (from mask entering this block)
        fill_kernel<<<nblkN, 256, 0, stream>>>(deg, 1.f, N_NODES);
        edge_deg_kernel<<<nblkE, 256, 0, stream>>>(src, dstp, mcur, deg, N_EDGES);
        norm_kernel<<<nblkN, 256, 0, stream>>>(deg, norm, N_NODES);
        // xw = h @ W
        gemm128_kernel<<<(N_NODES + 63) / 64, 256, 0, stream>>>(hin, Wb[blk], xw, N_NODES);
        // agg (accumulated directly into hout)
        hipMemsetAsync(hout, 0, (size_t)N_NODES * H * sizeof(float), stream);
        edge_agg_kernel<<<(N_EDGES + 1) / 2, 256, 0, stream>>>(xw, src, dstp, mcur, norm, hout, N_EDGES);
        combine_relu_kernel<<<nblkNH, 256, 0, stream>>>(hout, xw, norm, bbv[blk], N_NODES);
        // score conv on the new h
        dotws_kernel<<<(N_NODES + 3) / 4, 256, 0, stream>>>(hout, Wsb[blk], xws, N_NODES);
        hipMemsetAsync(aggs, 0, N_NODES * sizeof(float), stream);
        edge_aggs_kernel<<<nblkE, 256, 0, stream>>>(xws, src, dstp, mcur, norm, aggs, N_EDGES);
        score_kernel<<<nblkN, 256, 0, stream>>>(aggs, xws, norm, bsb[blk], score, N_NODES);
        // top-k pooling mask
        topk_kernel<<<G_GRAPHS, 256, 0, stream>>>(score, mcur, starts, counts, mnext);
        // gate h
        gate_kernel<<<nblkNH, 256, 0, stream>>>(hout, score, mnext, N_NODES);
        // readout accumulate
        readout_kernel<<<G_GRAPHS, 128, 0, stream>>>(hout, mnext, starts, counts, rbuf);
        // rotate buffers
        hin = hout;
        hout = (hout == hA) ? hB : hA;
        const float* tm = mcur; mcur = mnext; mnext = (float*)tm;
    }

    mlp_kernel<<<G_GRAPHS, 128, 0, stream>>>(rbuf, Wl1, bl1, Wl2, bl2, Wl3, bl3, out);
}

// Round 2
// 1318.033 us; speedup vs baseline: 1.2072x; 1.2072x over previous
//
#include <hip/hip_runtime.h>
#include <math.h>

#define N_NODES 50000
#define N_EDGES 600000
#define H 128
#define G_GRAPHS 100
#define C_CLS 10

// ---------------- utility kernels ----------------

__global__ void fill_kernel(float* __restrict__ p, float v, int n) {
    int i = blockIdx.x * 256 + threadIdx.x;
    if (i < n) p[i] = v;
}

__global__ void count_kernel(const int* __restrict__ batch, int* __restrict__ counts, int n) {
    int i = blockIdx.x * 256 + threadIdx.x;
    if (i < n) atomicAdd(&counts[batch[i]], 1);
}

__global__ void scan_kernel(const int* __restrict__ counts, int* __restrict__ starts) {
    if (threadIdx.x == 0) {
        int acc = 0;
        for (int g = 0; g < G_GRAPHS; ++g) { starts[g] = acc; acc += counts[g]; }
    }
}

// ---------------- CSR build (dst-grouped, deterministic) ----------------

__global__ void indeg_kernel(const int* __restrict__ dst, int* __restrict__ indeg, int ne) {
    int e = blockIdx.x * 256 + threadIdx.x;
    if (e < ne) atomicAdd(&indeg[dst[e]], 1);
}

// single-block hierarchical exclusive scan over N_NODES ints -> rowptr[N+1]
__global__ __launch_bounds__(1024) void scan_nodes_kernel(const int* __restrict__ indeg,
                                                          int* __restrict__ rowptr) {
    __shared__ int part[1024];
    const int t = threadIdx.x;
    const int chunk = (N_NODES + 1023) / 1024;
    const int base = t * chunk;
    int s = 0;
    for (int i = 0; i < chunk; ++i) {
        int idx = base + i;
        if (idx < N_NODES) s += indeg[idx];
    }
    part[t] = s;
    __syncthreads();
    for (int off = 1; off < 1024; off <<= 1) {
        int v = 0;
        if (t >= off) v = part[t - off];
        __syncthreads();
        if (t >= off) part[t] += v;
        __syncthreads();
    }
    int run = (t == 0) ? 0 : part[t - 1];
    for (int i = 0; i < chunk; ++i) {
        int idx = base + i;
        if (idx < N_NODES) { rowptr[idx] = run; run += indeg[idx]; }
    }
    if (t == 1023) rowptr[N_NODES] = run;
}

__global__ void scatter_kernel(const int* __restrict__ src, const int* __restrict__ dst,
                               const int* __restrict__ rowptr, int* __restrict__ cursor,
                               int* __restrict__ srcC, int ne) {
    int e = blockIdx.x * 256 + threadIdx.x;
    if (e >= ne) return;
    int d = dst[e];
    int pos = rowptr[d] + atomicAdd(&cursor[d], 1);
    srcC[pos] = src[e];
}

// per-node insertion sort by src value -> deterministic gather order.
// (equal src values => identical summands => order among them irrelevant)
__global__ void sort_kernel(const int* __restrict__ rowptr, int* __restrict__ srcC, int n) {
    int d = blockIdx.x * 256 + threadIdx.x;
    if (d >= n) return;
    int e0 = rowptr[d], e1 = rowptr[d + 1];
    for (int i = e0 + 1; i < e1; ++i) {
        int key = srcC[i];
        int j = i - 1;
        while (j >= e0 && srcC[j] > key) { srcC[j + 1] = srcC[j]; --j; }
        srcC[j + 1] = key;
    }
}

// ---------------- degree / norm (gather) ----------------

__global__ void degnorm_kernel(const int* __restrict__ rowptr, const int* __restrict__ srcC,
                               const float* __restrict__ mask, float* __restrict__ norm, int n) {
    int d = blockIdx.x * 256 + threadIdx.x;
    if (d >= n) return;
    float md = mask[d];
    float s = 0.f;
    if (md != 0.f) {
        int e0 = rowptr[d], e1 = rowptr[d + 1];
        for (int e = e0; e < e1; ++e) s += mask[srcC[e]];
    }
    norm[d] = rsqrtf(1.f + md * s);
}

// ---------------- GEMM: out[n][128] = A[n][128] @ W[128][128] ----------------

__global__ __launch_bounds__(256) void gemm128_kernel(const float* __restrict__ A,
                                                      const float* __restrict__ W,
                                                      float* __restrict__ out, int nrows) {
    __shared__ float sT[128][68];
    int row0 = blockIdx.x * 64;
    int tid = threadIdx.x;
    for (int i = tid; i < 2048; i += 256) {
        int r = i >> 5, c4 = i & 31;
        int row = row0 + r;
        float4 v = make_float4(0.f, 0.f, 0.f, 0.f);
        if (row < nrows) v = ((const float4*)(A + (size_t)row * H))[c4];
        sT[c4 * 4 + 0][r] = v.x; sT[c4 * 4 + 1][r] = v.y;
        sT[c4 * 4 + 2][r] = v.z; sT[c4 * 4 + 3][r] = v.w;
    }
    __syncthreads();
    int cg = tid & 31;
    int rg = tid >> 5;
    float acc[8][4];
#pragma unroll
    for (int i = 0; i < 8; ++i)
#pragma unroll
        for (int j = 0; j < 4; ++j) acc[i][j] = 0.f;

    for (int k = 0; k < 128; ++k) {
        float4 w4 = ((const float4*)(W + k * H))[cg];
        const float4* pa = (const float4*)(&sT[k][rg * 8]);
        float4 a0 = pa[0], a1 = pa[1];
        float av[8] = {a0.x, a0.y, a0.z, a0.w, a1.x, a1.y, a1.z, a1.w};
#pragma unroll
        for (int i = 0; i < 8; ++i) {
            acc[i][0] = fmaf(av[i], w4.x, acc[i][0]);
            acc[i][1] = fmaf(av[i], w4.y, acc[i][1]);
            acc[i][2] = fmaf(av[i], w4.z, acc[i][2]);
            acc[i][3] = fmaf(av[i], w4.w, acc[i][3]);
        }
    }
#pragma unroll
    for (int i = 0; i < 8; ++i) {
        int row = row0 + rg * 8 + i;
        if (row < nrows) {
            float4 o = make_float4(acc[i][0], acc[i][1], acc[i][2], acc[i][3]);
            ((float4*)(out + (size_t)row * H))[cg] = o;
        }
    }
}

// ---------------- fused gather aggregation + self + bias + relu ----------------
// 2 nodes per 256-block; 128 threads per node (one feature each).

__global__ __launch_bounds__(256) void agg_fused_kernel(const float* __restrict__ xw,
        const int* __restrict__ rowptr, const int* __restrict__ srcC,
        const float* __restrict__ mask, const float* __restrict__ norm,
        const float* __restrict__ b, float* __restrict__ hout, int n) {
    int node = blockIdx.x * 2 + (threadIdx.x >> 7);
    if (node >= n) return;
    int f = threadIdx.x & 127;
    float md = mask[node];
    float nd = norm[node];
    float acc = 0.f;
    if (md != 0.f) {
        int e0 = rowptr[node], e1 = rowptr[node + 1];
        for (int e = e0; e < e1; ++e) {
            int s = srcC[e];
            float ms = mask[s];
            if (ms != 0.f) acc = fmaf(xw[(size_t)s * H + f], norm[s], acc);
        }
        acc *= md * nd;
    }
    float v = acc + xw[(size_t)node * H + f] * nd * nd + b[f];
    hout[(size_t)node * H + f] = fmaxf(v, 0.f);
}

// ---------------- score projection: xws[n] = dot(h[n], Ws) ----------------

__global__ void dotws_kernel(const float* __restrict__ h, const float* __restrict__ Ws,
                             float* __restrict__ xws, int n) {
    int node = blockIdx.x * 4 + (threadIdx.x >> 6);
    int lane = threadIdx.x & 63;
    if (node >= n) return;
    const float* row = h + (size_t)node * H;
    float a = row[lane] * Ws[lane] + row[lane + 64] * Ws[lane + 64];
#pragma unroll
    for (int o = 32; o > 0; o >>= 1) a += __shfl_down(a, o);
    if (lane == 0) xws[node] = a;
}

// ---------------- score gather (scalar conv) ----------------

__global__ void score_gather_kernel(const int* __restrict__ rowptr, const int* __restrict__ srcC,
        const float* __restrict__ xws, const float* __restrict__ mask,
        const float* __restrict__ norm, const float* __restrict__ bs,
        float* __restrict__ score, int n) {
    int d = blockIdx.x * 256 + threadIdx.x;
    if (d >= n) return;
    float md = mask[d];
    float nd = norm[d];
    float acc = 0.f;
    if (md != 0.f) {
        int e0 = rowptr[d], e1 = rowptr[d + 1];
        for (int e = e0; e < e1; ++e) {
            int s = srcC[e];
            float ms = mask[s];
            if (ms != 0.f) acc = fmaf(xws[s], norm[s], acc);
        }
        acc *= md * nd;
    }
    score[d] = acc + xws[d] * nd * nd + bs[0];
}

// ---------------- top-k per graph (exact reference semantics) ----------------

__global__ __launch_bounds__(256) void topk_kernel(const float* __restrict__ score,
        const float* __restrict__ mask, const int* __restrict__ starts,
        const int* __restrict__ counts, float* __restrict__ nmask) {
    int g = blockIdx.x;
    int s0 = starts[g], cnt = counts[g];
    __shared__ float ssc[1024];
    __shared__ float red[256];
    bool useL = (cnt <= 1024);
    float la = 0.f;
    for (int i = threadIdx.x; i < cnt; i += 256) {
        float m = mask[s0 + i];
        float sc = (m > 0.f) ? score[s0 + i] : -INFINITY;
        if (useL) ssc[i] = sc;
        if (m > 0.f) la += 1.f;
    }
    red[threadIdx.x] = la;
    __syncthreads();
    for (int o = 128; o > 0; o >>= 1) {
        if (threadIdx.x < o) red[threadIdx.x] += red[threadIdx.x + o];
        __syncthreads();
    }
    int kk = (int)ceilf(0.5f * red[0]);
    for (int i = threadIdx.x; i < cnt; i += 256) {
        float sci = useL ? ssc[i] : ((mask[s0 + i] > 0.f) ? score[s0 + i] : -INFINITY);
        float nm = 0.f;
        if (sci != -INFINITY) {
            int rank = 0;
            for (int j = 0; j < cnt; ++j) {
                float scj = useL ? ssc[j] : ((mask[s0 + j] > 0.f) ? score[s0 + j] : -INFINITY);
                rank += (scj > sci || (scj == sci && j < i)) ? 1 : 0;
            }
            if (rank < kk) nm = mask[s0 + i];
        }
        nmask[s0 + i] = nm;
    }
}

// ---------------- gate ----------------

__global__ void gate_kernel(float* __restrict__ h, const float* __restrict__ score,
                            const float* __restrict__ nmask, int n) {
    int idx = blockIdx.x * 256 + threadIdx.x;
    if (idx >= n * H) return;
    int node = idx >> 7;
    h[idx] = h[idx] * tanhf(score[node]) * nmask[node];
}

// ---------------- readout (max || mean), 4-way node-parallel ----------------

__global__ __launch_bounds__(512) void readout_kernel(const float* __restrict__ h,
        const float* __restrict__ mask, const int* __restrict__ starts,
        const int* __restrict__ counts, float* __restrict__ r) {
    int g = blockIdx.x;
    int f = threadIdx.x & 127;
    int sub = threadIdx.x >> 7;
    int s0 = starts[g], cnt = counts[g];
    float s = 0.f, mx = -INFINITY, c = 0.f;
    for (int i = sub; i < cnt; i += 4) {
        float m = mask[s0 + i];
        if (m > 0.f) {
            float v = h[(size_t)(s0 + i) * H + f];
            s += v; mx = fmaxf(mx, v); c += 1.f;
        }
    }
    __shared__ float ls[4][128];
    __shared__ float lm[4][128];
    __shared__ float lc[4];
    ls[sub][f] = s; lm[sub][f] = mx;
    if (f == 0) lc[sub] = c;
    __syncthreads();
    if (sub == 0) {
        float S = ((ls[0][f] + ls[1][f]) + ls[2][f]) + ls[3][f];
        float M = fmaxf(fmaxf(lm[0][f], lm[1][f]), fmaxf(lm[2][f], lm[3][f]));
        float C = ((lc[0] + lc[1]) + lc[2]) + lc[3];
        float mean = S / fmaxf(C, 1.f);
        if (C == 0.f) M = 0.f;
        r[(size_t)g * 2 * H + f] += M;
        r[(size_t)g * 2 * H + H + f] += mean;
    }
}

// ---------------- MLP head + log_softmax ----------------

__global__ __launch_bounds__(128) void mlp_kernel(const float* __restrict__ r,
        const float* __restrict__ Wl1, const float* __restrict__ bl1,
        const float* __restrict__ Wl2, const float* __restrict__ bl2,
        const float* __restrict__ Wl3, const float* __restrict__ bl3,
        float* __restrict__ out) {
    int g = blockIdx.x;
    int t = threadIdx.x;
    __shared__ float sz[256];
    __shared__ float sy1[128];
    __shared__ float sy2[64];
    __shared__ float sy3[10];
    __shared__ float sred[2];
    sz[t] = r[g * 256 + t];
    sz[t + 128] = r[g * 256 + 128 + t];
    __syncthreads();
    float a = bl1[t];
    for (int k = 0; k < 256; ++k) a = fmaf(sz[k], Wl1[k * 128 + t], a);
    sy1[t] = fmaxf(a, 0.f);
    __syncthreads();
    if (t < 64) {
        float a2 = bl2[t];
        for (int k = 0; k < 128; ++k) a2 = fmaf(sy1[k], Wl2[k * 64 + t], a2);
        sy2[t] = fmaxf(a2, 0.f);
    }
    __syncthreads();
    if (t < 10) {
        float a3 = bl3[t];
        for (int k = 0; k < 64; ++k) a3 = fmaf(sy2[k], Wl3[k * 10 + t], a3);
        sy3[t] = a3;
    }
    __syncthreads();
    if (t == 0) {
        float m = sy3[0];
        for (int c2 = 1; c2 < 10; ++c2) m = fmaxf(m, sy3[c2]);
        float se = 0.f;
        for (int c2 = 0; c2 < 10; ++c2) se += expf(sy3[c2] - m);
        sred[0] = m; sred[1] = logf(se);
    }
    __syncthreads();
    if (t < 10) out[g * 10 + t] = sy3[t] - sred[0] - sred[1];
}

// ---------------- launch ----------------

extern "C" void kernel_launch(void* const* d_in, const int* in_sizes, int n_in,
                              void* d_out, int out_size, void* d_ws, size_t ws_size,
                              hipStream_t stream) {
    const float* x     = (const float*)d_in[0];
    const int*   ei    = (const int*)d_in[1];
    const int*   batch = (const int*)d_in[2];
    const int* src  = ei;
    const int* dstp = ei + N_EDGES;
    const float* Wb[3]  = {(const float*)d_in[3], (const float*)d_in[7],  (const float*)d_in[11]};
    const float* bbv[3] = {(const float*)d_in[4], (const float*)d_in[8],  (const float*)d_in[12]};
    const float* Wsb[3] = {(const float*)d_in[5], (const float*)d_in[9],  (const float*)d_in[13]};
    const float* bsb[3] = {(const float*)d_in[6], (const float*)d_in[10], (const float*)d_in[14]};
    const float* Wl1 = (const float*)d_in[15];
    const float* bl1 = (const float*)d_in[16];
    const float* Wl2 = (const float*)d_in[17];
    const float* bl2 = (const float*)d_in[18];
    const float* Wl3 = (const float*)d_in[19];
    const float* bl3 = (const float*)d_in[20];
    float* out = (float*)d_out;

    // workspace carve (4B units)
    float* fws = (float*)d_ws;
    size_t off = 0;
    float* hA    = fws + off; off += (size_t)N_NODES * H;
    float* hB    = fws + off; off += (size_t)N_NODES * H;
    float* xw    = fws + off; off += (size_t)N_NODES * H;
    float* score = fws + off; off += N_NODES;
    float* xws   = fws + off; off += N_NODES;
    float* norm  = fws + off; off += N_NODES;
    float* mA    = fws + off; off += N_NODES;
    float* mB    = fws + off; off += N_NODES;
    float* rbuf  = fws + off; off += (size_t)G_GRAPHS * 2 * H;
    int* counts  = (int*)(fws + off); off += G_GRAPHS;
    int* starts  = (int*)(fws + off); off += G_GRAPHS;
    int* rowptr  = (int*)(fws + off); off += N_NODES + 1;
    int* indeg   = (int*)(fws + off); off += N_NODES;
    int* cursor  = (int*)(fws + off); off += N_NODES;
    int* srcC    = (int*)(fws + off); off += N_EDGES;

    int nblkN  = (N_NODES + 255) / 256;
    int nblkNH = (N_NODES * H + 255) / 256;
    int nblkE  = (N_EDGES + 255) / 256;

    // graph segment structure (batch is sorted)
    hipMemsetAsync(counts, 0, G_GRAPHS * sizeof(int), stream);
    count_kernel<<<nblkN, 256, 0, stream>>>(batch, counts, N_NODES);
    scan_kernel<<<1, 64, 0, stream>>>(counts, starts);

    // CSR build (dst-grouped), deterministic via per-node sort
    hipMemsetAsync(indeg, 0, N_NODES * sizeof(int), stream);
    hipMemsetAsync(cursor, 0, N_NODES * sizeof(int), stream);
    indeg_kernel<<<nblkE, 256, 0, stream>>>(dstp, indeg, N_EDGES);
    scan_nodes_kernel<<<1, 1024, 0, stream>>>(indeg, rowptr);
    scatter_kernel<<<nblkE, 256, 0, stream>>>(src, dstp, rowptr, cursor, srcC, N_EDGES);
    sort_kernel<<<nblkN, 256, 0, stream>>>(rowptr, srcC, N_NODES);

    fill_kernel<<<nblkN, 256, 0, stream>>>(mA, 1.f, N_NODES);
    hipMemsetAsync(rbuf, 0, G_GRAPHS * 2 * H * sizeof(float), stream);

    const float* hin = x;
    float* hout = hA;
    const float* mcur = mA;
    float* mnext = mB;

    for (int blk = 0; blk < 3; ++blk) {
        degnorm_kernel<<<nblkN, 256, 0, stream>>>(rowptr, srcC, mcur, norm, N_NODES);
        gemm128_kernel<<<(N_NODES + 63) / 64, 256, 0, stream>>>(hin, Wb[blk], xw, N_NODES);
        agg_fused_kernel<<<(N_NODES + 1) / 2, 256, 0, stream>>>(xw, rowptr, srcC, mcur, norm,
                                                                bbv[blk], hout, N_NODES);
        dotws_kernel<<<(N_NODES + 3) / 4, 256, 0, stream>>>(hout, Wsb[blk], xws, N_NODES);
        score_gather_kernel<<<nblkN, 256, 0, stream>>>(rowptr, srcC, xws, mcur, norm,
                                                       bsb[blk], score, N_NODES);
        topk_kernel<<<G_GRAPHS, 256, 0, stream>>>(score, mcur, starts, counts, mnext);
        gate_kernel<<<nblkNH, 256, 0, stream>>>(hout, score, mnext, N_NODES);
        readout_kernel<<<G_GRAPHS, 512, 0, stream>>>(hout, mnext, starts, counts, rbuf);
        hin = hout;
        hout = (hout == hA) ? hB : hA;
        const float* tm = mcur; mcur = mnext; mnext = (float*)tm;
    }

    mlp_kernel<<<G_GRAPHS, 128, 0, stream>>>(rbuf, Wl1, bl1, Wl2, bl2, Wl3, bl3, out);
}

// Round 4
// 1100.909 us; speedup vs baseline: 1.4453x; 1.1972x over previous
//
#include <hip/hip_runtime.h>
#include <math.h>

#define N_NODES 50000
#define N_EDGES 600000
#define H 128
#define G_GRAPHS 100
#define C_CLS 10

// ---------------- utility kernels ----------------

__global__ void fill_kernel(float* __restrict__ p, float v, int n) {
    int i = blockIdx.x * 256 + threadIdx.x;
    if (i < n) p[i] = v;
}

__global__ void count_kernel(const int* __restrict__ batch, int* __restrict__ counts, int n) {
    int i = blockIdx.x * 256 + threadIdx.x;
    if (i < n) atomicAdd(&counts[batch[i]], 1);
}

__global__ void scan_kernel(const int* __restrict__ counts, int* __restrict__ starts) {
    if (threadIdx.x == 0) {
        int acc = 0;
        for (int g = 0; g < G_GRAPHS; ++g) { starts[g] = acc; acc += counts[g]; }
    }
}

// ---------------- CSR build (dst-grouped, deterministic) ----------------

__global__ void indeg_kernel(const int* __restrict__ dst, int* __restrict__ indeg, int ne) {
    int e = blockIdx.x * 256 + threadIdx.x;
    if (e < ne) atomicAdd(&indeg[dst[e]], 1);
}

__global__ __launch_bounds__(1024) void scan_nodes_kernel(const int* __restrict__ indeg,
                                                          int* __restrict__ rowptr) {
    __shared__ int part[1024];
    const int t = threadIdx.x;
    const int chunk = (N_NODES + 1023) / 1024;
    const int base = t * chunk;
    int s = 0;
    for (int i = 0; i < chunk; ++i) {
        int idx = base + i;
        if (idx < N_NODES) s += indeg[idx];
    }
    part[t] = s;
    __syncthreads();
    for (int off = 1; off < 1024; off <<= 1) {
        int v = 0;
        if (t >= off) v = part[t - off];
        __syncthreads();
        if (t >= off) part[t] += v;
        __syncthreads();
    }
    int run = (t == 0) ? 0 : part[t - 1];
    for (int i = 0; i < chunk; ++i) {
        int idx = base + i;
        if (idx < N_NODES) { rowptr[idx] = run; run += indeg[idx]; }
    }
    if (t == 1023) rowptr[N_NODES] = run;
}

__global__ void scatter_kernel(const int* __restrict__ src, const int* __restrict__ dst,
                               const int* __restrict__ rowptr, int* __restrict__ cursor,
                               int* __restrict__ srcC, int ne) {
    int e = blockIdx.x * 256 + threadIdx.x;
    if (e >= ne) return;
    int d = dst[e];
    int pos = rowptr[d] + atomicAdd(&cursor[d], 1);
    srcC[pos] = src[e];
}

// per-node insertion sort by src -> deterministic gather order
__global__ void sort_kernel(const int* __restrict__ rowptr, int* __restrict__ srcC, int n) {
    int d = blockIdx.x * 256 + threadIdx.x;
    if (d >= n) return;
    int e0 = rowptr[d], e1 = rowptr[d + 1];
    for (int i = e0 + 1; i < e1; ++i) {
        int key = srcC[i];
        int j = i - 1;
        while (j >= e0 && srcC[j] > key) { srcC[j + 1] = srcC[j]; --j; }
        srcC[j + 1] = key;
    }
}

// ---------------- degree / norm (gather) ----------------

__global__ void degnorm_kernel(const int* __restrict__ rowptr, const int* __restrict__ srcC,
                               const float* __restrict__ mask, float* __restrict__ norm, int n) {
    int d = blockIdx.x * 256 + threadIdx.x;
    if (d >= n) return;
    float md = mask[d];
    float s = 0.f;
    if (md != 0.f) {
        int e0 = rowptr[d], e1 = rowptr[d + 1];
        for (int e = e0; e < e1; ++e) s += mask[srcC[e]];
    }
    norm[d] = rsqrtf(1.f + md * s);
}

// ---------------- GEMM: out[n][128] = (gfac[n] * A[n][128]) @ W[128][128] ----------------

__global__ __launch_bounds__(256) void gemm128_kernel(const float* __restrict__ A,
                                                      const float* __restrict__ W,
                                                      const float* __restrict__ gf,
                                                      float* __restrict__ out, int nrows) {
    __shared__ float sT[128][68];
    int row0 = blockIdx.x * 64;
    int tid = threadIdx.x;
    for (int i = tid; i < 2048; i += 256) {
        int r = i >> 5, c4 = i & 31;
        int row = row0 + r;
        float4 v = make_float4(0.f, 0.f, 0.f, 0.f);
        if (row < nrows) {
            float g = gf[row];
            v = ((const float4*)(A + (size_t)row * H))[c4];
            v.x *= g; v.y *= g; v.z *= g; v.w *= g;
        }
        sT[c4 * 4 + 0][r] = v.x; sT[c4 * 4 + 1][r] = v.y;
        sT[c4 * 4 + 2][r] = v.z; sT[c4 * 4 + 3][r] = v.w;
    }
    __syncthreads();
    int cg = tid & 31;
    int rg = tid >> 5;
    float acc[8][4];
#pragma unroll
    for (int i = 0; i < 8; ++i)
#pragma unroll
        for (int j = 0; j < 4; ++j) acc[i][j] = 0.f;

    for (int k = 0; k < 128; ++k) {
        float4 w4 = ((const float4*)(W + k * H))[cg];
        const float4* pa = (const float4*)(&sT[k][rg * 8]);
        float4 a0 = pa[0], a1 = pa[1];
        float av[8] = {a0.x, a0.y, a0.z, a0.w, a1.x, a1.y, a1.z, a1.w};
#pragma unroll
        for (int i = 0; i < 8; ++i) {
            acc[i][0] = fmaf(av[i], w4.x, acc[i][0]);
            acc[i][1] = fmaf(av[i], w4.y, acc[i][1]);
            acc[i][2] = fmaf(av[i], w4.z, acc[i][2]);
            acc[i][3] = fmaf(av[i], w4.w, acc[i][3]);
        }
    }
#pragma unroll
    for (int i = 0; i < 8; ++i) {
        int row = row0 + rg * 8 + i;
        if (row < nrows) {
            float4 o = make_float4(acc[i][0], acc[i][1], acc[i][2], acc[i][3]);
            ((float4*)(out + (size_t)row * H))[cg] = o;
        }
    }
}

// ---------------- fused gather agg + self + bias + relu + score-dot ----------------
// 8 nodes per 256-block, 32 threads/node, float4 per thread, 4-edge unroll (ILP).

__global__ __launch_bounds__(256) void agg_fused_kernel(const float* __restrict__ xw,
        const int* __restrict__ rowptr, const int* __restrict__ srcC,
        const float* __restrict__ mask, const float* __restrict__ norm,
        const float* __restrict__ b, const float* __restrict__ Ws,
        float* __restrict__ hout, float* __restrict__ xws, int n) {
    int node = blockIdx.x * 8 + (threadIdx.x >> 5);
    if (node >= n) return;
    int t = threadIdx.x & 31;
    const float4* xw4 = (const float4*)xw;
    float md = mask[node];
    float nd = norm[node];
    float4 a0 = make_float4(0.f, 0.f, 0.f, 0.f);
    float4 a1 = a0, a2 = a0, a3 = a0;
    if (md != 0.f) {
        int e0 = rowptr[node], e1 = rowptr[node + 1];
        int e = e0;
        for (; e + 3 < e1; e += 4) {
            int s0 = srcC[e], s1 = srcC[e + 1], s2 = srcC[e + 2], s3 = srcC[e + 3];
            float c0 = mask[s0] * norm[s0];
            float c1 = mask[s1] * norm[s1];
            float c2 = mask[s2] * norm[s2];
            float c3 = mask[s3] * norm[s3];
            float4 v0 = xw4[(size_t)s0 * 32 + t];
            float4 v1 = xw4[(size_t)s1 * 32 + t];
            float4 v2 = xw4[(size_t)s2 * 32 + t];
            float4 v3 = xw4[(size_t)s3 * 32 + t];
            a0.x = fmaf(v0.x, c0, a0.x); a0.y = fmaf(v0.y, c0, a0.y);
            a0.z = fmaf(v0.z, c0, a0.z); a0.w = fmaf(v0.w, c0, a0.w);
            a1.x = fmaf(v1.x, c1, a1.x); a1.y = fmaf(v1.y, c1, a1.y);
            a1.z = fmaf(v1.z, c1, a1.z); a1.w = fmaf(v1.w, c1, a1.w);
            a2.x = fmaf(v2.x, c2, a2.x); a2.y = fmaf(v2.y, c2, a2.y);
            a2.z = fmaf(v2.z, c2, a2.z); a2.w = fmaf(v2.w, c2, a2.w);
            a3.x = fmaf(v3.x, c3, a3.x); a3.y = fmaf(v3.y, c3, a3.y);
            a3.z = fmaf(v3.z, c3, a3.z); a3.w = fmaf(v3.w, c3, a3.w);
        }
        for (; e < e1; ++e) {
            int s = srcC[e];
            float c = mask[s] * norm[s];
            float4 v = xw4[(size_t)s * 32 + t];
            a0.x = fmaf(v.x, c, a0.x); a0.y = fmaf(v.y, c, a0.y);
            a0.z = fmaf(v.z, c, a0.z); a0.w = fmaf(v.w, c, a0.w);
        }
        float sc = md * nd;
        a0.x = (((a0.x + a1.x) + a2.x) + a3.x) * sc;
        a0.y = (((a0.y + a1.y) + a2.y) + a3.y) * sc;
        a0.z = (((a0.z + a1.z) + a2.z) + a3.z) * sc;
        a0.w = (((a0.w + a1.w) + a2.w) + a3.w) * sc;
    }
    float4 self = xw4[(size_t)node * 32 + t];
    float4 bb = ((const float4*)b)[t];
    float n2 = nd * nd;
    float4 v;
    v.x = fmaxf(fmaf(self.x, n2, a0.x) + bb.x, 0.f);
    v.y = fmaxf(fmaf(self.y, n2, a0.y) + bb.y, 0.f);
    v.z = fmaxf(fmaf(self.z, n2, a0.z) + bb.z, 0.f);
    v.w = fmaxf(fmaf(self.w, n2, a0.w) + bb.w, 0.f);
    ((float4*)hout)[(size_t)node * 32 + t] = v;
    // fused score projection: xws[node] = dot(hout_row, Ws)
    float4 w = ((const float4*)Ws)[t];
    float p = ((v.x * w.x + v.y * w.y) + v.z * w.z) + v.w * w.w;
#pragma unroll
    for (int o = 16; o > 0; o >>= 1) p += __shfl_down(p, o, 32);
    if (t == 0) xws[node] = p;
}

// ---------------- score gather (scalar conv) ----------------

__global__ void score_gather_kernel(const int* __restrict__ rowptr, const int* __restrict__ srcC,
        const float* __restrict__ xws, const float* __restrict__ mask,
        const float* __restrict__ norm, const float* __restrict__ bs,
        float* __restrict__ score, int n) {
    int d = blockIdx.x * 256 + threadIdx.x;
    if (d >= n) return;
    float md = mask[d];
    float nd = norm[d];
    float acc = 0.f;
    if (md != 0.f) {
        int e0 = rowptr[d], e1 = rowptr[d + 1];
        for (int e = e0; e < e1; ++e) {
            int s = srcC[e];
            acc = fmaf(xws[s] * mask[s], norm[s], acc);
        }
        acc *= md * nd;
    }
    score[d] = acc + xws[d] * nd * nd + bs[0];
}

// ---------------- top-k per graph (exact reference semantics) ----------------

__global__ __launch_bounds__(256) void topk_kernel(const float* __restrict__ score,
        const float* __restrict__ mask, const int* __restrict__ starts,
        const int* __restrict__ counts, float* __restrict__ nmask) {
    int g = blockIdx.x;
    int s0 = starts[g], cnt = counts[g];
    __shared__ float ssc[1024];
    __shared__ float red[256];
    bool useL = (cnt <= 1024);
    float la = 0.f;
    for (int i = threadIdx.x; i < cnt; i += 256) {
        float m = mask[s0 + i];
        float sc = (m > 0.f) ? score[s0 + i] : -INFINITY;
        if (useL) ssc[i] = sc;
        if (m > 0.f) la += 1.f;
    }
    red[threadIdx.x] = la;
    __syncthreads();
    for (int o = 128; o > 0; o >>= 1) {
        if (threadIdx.x < o) red[threadIdx.x] += red[threadIdx.x + o];
        __syncthreads();
    }
    int kk = (int)ceilf(0.5f * red[0]);
    for (int i = threadIdx.x; i < cnt; i += 256) {
        float sci = useL ? ssc[i] : ((mask[s0 + i] > 0.f) ? score[s0 + i] : -INFINITY);
        float nm = 0.f;
        if (sci != -INFINITY) {
            int rank = 0;
            for (int j = 0; j < cnt; ++j) {
                float scj = useL ? ssc[j] : ((mask[s0 + j] > 0.f) ? score[s0 + j] : -INFINITY);
                rank += (scj > sci || (scj == sci && j < i)) ? 1 : 0;
            }
            if (rank < kk) nm = mask[s0 + i];
        }
        nmask[s0 + i] = nm;
    }
}

// ---------------- gate factor: gfac = tanh(score) * nmask ----------------

__global__ void gfac_kernel(const float* __restrict__ score, const float* __restrict__ nmask,
                            float* __restrict__ gfac, int n) {
    int i = blockIdx.x * 256 + threadIdx.x;
    if (i < n) gfac[i] = tanhf(score[i]) * nmask[i];
}

// ---------------- readout (max || mean) on gated h, 4-way node-parallel ----------------

__global__ __launch_bounds__(512) void readout_kernel(const float* __restrict__ h,
        const float* __restrict__ mask, const float* __restrict__ gfac,
        const int* __restrict__ starts, const int* __restrict__ counts,
        float* __restrict__ r) {
    int g = blockIdx.x;
    int f = threadIdx.x & 127;
    int sub = threadIdx.x >> 7;
    int s0 = starts[g], cnt = counts[g];
    float s = 0.f, mx = -INFINITY, c = 0.f;
    for (int i = sub; i < cnt; i += 4) {
        float m = mask[s0 + i];
        if (m > 0.f) {
            float v = h[(size_t)(s0 + i) * H + f] * gfac[s0 + i];
            s += v; mx = fmaxf(mx, v); c += 1.f;
        }
    }
    __shared__ float ls[4][128];
    __shared__ float lm[4][128];
    __shared__ float lc[4];
    ls[sub][f] = s; lm[sub][f] = mx;
    if (f == 0) lc[sub] = c;
    __syncthreads();
    if (sub == 0) {
        float S = ((ls[0][f] + ls[1][f]) + ls[2][f]) + ls[3][f];
        float M = fmaxf(fmaxf(lm[0][f], lm[1][f]), fmaxf(lm[2][f], lm[3][f]));
        float C = ((lc[0] + lc[1]) + lc[2]) + lc[3];
        float mean = S / fmaxf(C, 1.f);
        if (C == 0.f) M = 0.f;
        r[(size_t)g * 2 * H + f] += M;
        r[(size_t)g * 2 * H + H + f] += mean;
    }
}

// ---------------- MLP head + log_softmax ----------------

__global__ __launch_bounds__(128) void mlp_kernel(const float* __restrict__ r,
        const float* __restrict__ Wl1, const float* __restrict__ bl1,
        const float* __restrict__ Wl2, const float* __restrict__ bl2,
        const float* __restrict__ Wl3, const float* __restrict__ bl3,
        float* __restrict__ out) {
    int g = blockIdx.x;
    int t = threadIdx.x;
    __shared__ float sz[256];
    __shared__ float sy1[128];
    __shared__ float sy2[64];
    __shared__ float sy3[10];
    __shared__ float sred[2];
    sz[t] = r[g * 256 + t];
    sz[t + 128] = r[g * 256 + 128 + t];
    __syncthreads();
    float a = bl1[t];
    for (int k = 0; k < 256; ++k) a = fmaf(sz[k], Wl1[k * 128 + t], a);
    sy1[t] = fmaxf(a, 0.f);
    __syncthreads();
    if (t < 64) {
        float a2 = bl2[t];
        for (int k = 0; k < 128; ++k) a2 = fmaf(sy1[k], Wl2[k * 64 + t], a2);
        sy2[t] = fmaxf(a2, 0.f);
    }
    __syncthreads();
    if (t < 10) {
        float a3 = bl3[t];
        for (int k = 0; k < 64; ++k) a3 = fmaf(sy2[k], Wl3[k * 10 + t], a3);
        sy3[t] = a3;
    }
    __syncthreads();
    if (t == 0) {
        float m = sy3[0];
        for (int c2 = 1; c2 < 10; ++c2) m = fmaxf(m, sy3[c2]);
        float se = 0.f;
        for (int c2 = 0; c2 < 10; ++c2) se += expf(sy3[c2] - m);
        sred[0] = m; sred[1] = logf(se);
    }
    __syncthreads();
    if (t < 10) out[g * 10 + t] = sy3[t] - sred[0] - sred[1];
}

// ---------------- launch ----------------

extern "C" void kernel_launch(void* const* d_in, const int* in_sizes, int n_in,
                              void* d_out, int out_size, void* d_ws, size_t ws_size,
                              hipStream_t stream) {
    const float* x     = (const float*)d_in[0];
    const int*   ei    = (const int*)d_in[1];
    const int*   batch = (const int*)d_in[2];
    const int* src  = ei;
    const int* dstp = ei + N_EDGES;
    const float* Wb[3]  = {(const float*)d_in[3], (const float*)d_in[7],  (const float*)d_in[11]};
    const float* bbv[3] = {(const float*)d_in[4], (const float*)d_in[8],  (const float*)d_in[12]};
    const float* Wsb[3] = {(const float*)d_in[5], (const float*)d_in[9],  (const float*)d_in[13]};
    const float* bsb[3] = {(const float*)d_in[6], (const float*)d_in[10], (const float*)d_in[14]};
    const float* Wl1 = (const float*)d_in[15];
    const float* bl1 = (const float*)d_in[16];
    const float* Wl2 = (const float*)d_in[17];
    const float* bl2 = (const float*)d_in[18];
    const float* Wl3 = (const float*)d_in[19];
    const float* bl3 = (const float*)d_in[20];
    float* out = (float*)d_out;

    // workspace carve (4B units)
    float* fws = (float*)d_ws;
    size_t off = 0;
    float* hA    = fws + off; off += (size_t)N_NODES * H;
    float* hB    = fws + off; off += (size_t)N_NODES * H;
    float* xw    = fws + off; off += (size_t)N_NODES * H;
    float* score = fws + off; off += N_NODES;
    float* xws   = fws + off; off += N_NODES;
    float* norm  = fws + off; off += N_NODES;
    float* mA    = fws + off; off += N_NODES;
    float* mB    = fws + off; off += N_NODES;
    float* gfac  = fws + off; off += N_NODES;
    float* rbuf  = fws + off; off += (size_t)G_GRAPHS * 2 * H;
    int* counts  = (int*)(fws + off); off += G_GRAPHS;
    int* starts  = (int*)(fws + off); off += G_GRAPHS;
    int* rowptr  = (int*)(fws + off); off += N_NODES + 1;
    int* indeg   = (int*)(fws + off); off += N_NODES;
    int* cursor  = (int*)(fws + off); off += N_NODES;
    int* srcC    = (int*)(fws + off); off += N_EDGES;

    int nblkN  = (N_NODES + 255) / 256;
    int nblkE  = (N_EDGES + 255) / 256;

    // graph segment structure (batch is sorted)
    hipMemsetAsync(counts, 0, G_GRAPHS * sizeof(int), stream);
    count_kernel<<<nblkN, 256, 0, stream>>>(batch, counts, N_NODES);
    scan_kernel<<<1, 64, 0, stream>>>(counts, starts);

    // CSR build (dst-grouped), deterministic via per-node sort
    hipMemsetAsync(indeg, 0, N_NODES * sizeof(int), stream);
    hipMemsetAsync(cursor, 0, N_NODES * sizeof(int), stream);
    indeg_kernel<<<nblkE, 256, 0, stream>>>(dstp, indeg, N_EDGES);
    scan_nodes_kernel<<<1, 1024, 0, stream>>>(indeg, rowptr);
    scatter_kernel<<<nblkE, 256, 0, stream>>>(src, dstp, rowptr, cursor, srcC, N_EDGES);
    sort_kernel<<<nblkN, 256, 0, stream>>>(rowptr, srcC, N_NODES);

    fill_kernel<<<nblkN, 256, 0, stream>>>(mA, 1.f, N_NODES);
    fill_kernel<<<nblkN, 256, 0, stream>>>(gfac, 1.f, N_NODES);
    hipMemsetAsync(rbuf, 0, G_GRAPHS * 2 * H * sizeof(float), stream);

    const float* hin = x;
    float* hout = hA;
    const float* mcur = mA;
    float* mnext = mB;

    for (int blk = 0; blk < 3; ++blk) {
        degnorm_kernel<<<nblkN, 256, 0, stream>>>(rowptr, srcC, mcur, norm, N_NODES);
        gemm128_kernel<<<(N_NODES + 63) / 64, 256, 0, stream>>>(hin, Wb[blk], gfac, xw, N_NODES);
        agg_fused_kernel<<<(N_NODES + 7) / 8, 256, 0, stream>>>(xw, rowptr, srcC, mcur, norm,
                                                                bbv[blk], Wsb[blk], hout, xws, N_NODES);
        score_gather_kernel<<<nblkN, 256, 0, stream>>>(rowptr, srcC, xws, mcur, norm,
                                                       bsb[blk], score, N_NODES);
        topk_kernel<<<G_GRAPHS, 256, 0, stream>>>(score, mcur, starts, counts, mnext);
        gfac_kernel<<<nblkN, 256, 0, stream>>>(score, mnext, gfac, N_NODES);
        readout_kernel<<<G_GRAPHS, 512, 0, stream>>>(hout, mnext, gfac, starts, counts, rbuf);
        hin = hout;
        hout = (hout == hA) ? hB : hA;
        const float* tm = mcur; mcur = mnext; mnext = (float*)tm;
    }

    mlp_kernel<<<G_GRAPHS, 128, 0, stream>>>(rbuf, Wl1, bl1, Wl2, bl2, Wl3, bl3, out);
}

// Round 9
// 944.891 us; speedup vs baseline: 1.6839x; 1.1651x over previous
//
#include <hip/hip_runtime.h>
#include <math.h>

#define N_NODES 50000
#define N_EDGES 600000
#define H 128
#define G_GRAPHS 100
#define C_CLS 10

// ---------------- graph segment structure (batch sorted -> boundary detect) ----------------

__global__ void fill_kernel(float* __restrict__ p, float v, int n) {
    int i = blockIdx.x * 256 + threadIdx.x;
    if (i < n) p[i] = v;
}

// starts[g] = first index i with batch[i] == g (or next segment start if empty)
__global__ void starts_kernel(const int* __restrict__ batch, int* __restrict__ starts, int n) {
    int i = blockIdx.x * 256 + threadIdx.x;
    if (i >= n) return;
    int b = batch[i];
    int prev = (i == 0) ? -1 : batch[i - 1];
    for (int g = prev + 1; g <= b; ++g) starts[g] = i;
    if (i == n - 1) {
        for (int g = b + 1; g < G_GRAPHS; ++g) starts[g] = n;
    }
}

__global__ void counts_kernel(const int* __restrict__ starts, int* __restrict__ counts) {
    int g = threadIdx.x;
    if (g < G_GRAPHS) {
        int e = (g == G_GRAPHS - 1) ? N_NODES : starts[g + 1];
        counts[g] = e - starts[g];
    }
}

// ---------------- CSR build (dst-grouped, deterministic) ----------------

__global__ void indeg_kernel(const int* __restrict__ dst, int* __restrict__ indeg, int ne) {
    int e = blockIdx.x * 256 + threadIdx.x;
    if (e < ne) atomicAdd(&indeg[dst[e]], 1);
}

__global__ __launch_bounds__(1024) void scan_nodes_kernel(const int* __restrict__ indeg,
                                                          int* __restrict__ rowptr) {
    __shared__ int part[1024];
    const int t = threadIdx.x;
    const int chunk = (N_NODES + 1023) / 1024;
    const int base = t * chunk;
    int s = 0;
    for (int i = 0; i < chunk; ++i) {
        int idx = base + i;
        if (idx < N_NODES) s += indeg[idx];
    }
    part[t] = s;
    __syncthreads();
    for (int off = 1; off < 1024; off <<= 1) {
        int v = 0;
        if (t >= off) v = part[t - off];
        __syncthreads();
        if (t >= off) part[t] += v;
        __syncthreads();
    }
    int run = (t == 0) ? 0 : part[t - 1];
    for (int i = 0; i < chunk; ++i) {
        int idx = base + i;
        if (idx < N_NODES) { rowptr[idx] = run; run += indeg[idx]; }
    }
    if (t == 1023) rowptr[N_NODES] = run;
}

__global__ void scatter_kernel(const int* __restrict__ src, const int* __restrict__ dst,
                               const int* __restrict__ rowptr, int* __restrict__ cursor,
                               int* __restrict__ srcC, int ne) {
    int e = blockIdx.x * 256 + threadIdx.x;
    if (e >= ne) return;
    int d = dst[e];
    int pos = rowptr[d] + atomicAdd(&cursor[d], 1);
    srcC[pos] = src[e];
}

// per-node insertion sort by src -> deterministic gather order
__global__ void sort_kernel(const int* __restrict__ rowptr, int* __restrict__ srcC, int n) {
    int d = blockIdx.x * 256 + threadIdx.x;
    if (d >= n) return;
    int e0 = rowptr[d], e1 = rowptr[d + 1];
    for (int i = e0 + 1; i < e1; ++i) {
        int key = srcC[i];
        int j = i - 1;
        while (j >= e0 && srcC[j] > key) { srcC[j + 1] = srcC[j]; --j; }
        srcC[j + 1] = key;
    }
}

// ---------------- degree / norm (gather) + premultiplied mask*norm ----------------
// mask in {0,1} => mnorm = mask*norm is exact (0 or norm); downstream uses are
// bit-identical to computing mask[s]*norm[s] per edge.

__global__ void degnorm_kernel(const int* __restrict__ rowptr, const int* __restrict__ srcC,
                               const float* __restrict__ mask, float* __restrict__ norm,
                               float* __restrict__ mnorm, int n) {
    int d = blockIdx.x * 256 + threadIdx.x;
    if (d >= n) return;
    float md = mask[d];
    float s = 0.f;
    if (md != 0.f) {
        int e0 = rowptr[d], e1 = rowptr[d + 1];
        for (int e = e0; e < e1; ++e) s += mask[srcC[e]];
    }
    float nd = rsqrtf(1.f + md * s);
    norm[d] = nd;
    mnorm[d] = md * nd;
}

// ---------------- GEMM: out[n][128] = (gfac[n] * A[n][128]) @ W[128][128] ----------------

__global__ __launch_bounds__(256) void gemm128_kernel(const float* __restrict__ A,
                                                      const float* __restrict__ W,
                                                      const float* __restrict__ gf,
                                                      float* __restrict__ out, int nrows) {
    __shared__ float sT[128][68];
    int row0 = blockIdx.x * 64;
    int tid = threadIdx.x;
    for (int i = tid; i < 2048; i += 256) {
        int r = i >> 5, c4 = i & 31;
        int row = row0 + r;
        float4 v = make_float4(0.f, 0.f, 0.f, 0.f);
        if (row < nrows) {
            float g = gf[row];
            v = ((const float4*)(A + (size_t)row * H))[c4];
            v.x *= g; v.y *= g; v.z *= g; v.w *= g;
        }
        sT[c4 * 4 + 0][r] = v.x; sT[c4 * 4 + 1][r] = v.y;
        sT[c4 * 4 + 2][r] = v.z; sT[c4 * 4 + 3][r] = v.w;
    }
    __syncthreads();
    int cg = tid & 31;
    int rg = tid >> 5;
    float acc[8][4];
#pragma unroll
    for (int i = 0; i < 8; ++i)
#pragma unroll
        for (int j = 0; j < 4; ++j) acc[i][j] = 0.f;

    for (int k = 0; k < 128; ++k) {
        float4 w4 = ((const float4*)(W + k * H))[cg];
        const float4* pa = (const float4*)(&sT[k][rg * 8]);
        float4 a0 = pa[0], a1 = pa[1];
        float av[8] = {a0.x, a0.y, a0.z, a0.w, a1.x, a1.y, a1.z, a1.w};
#pragma unroll
        for (int i = 0; i < 8; ++i) {
            acc[i][0] = fmaf(av[i], w4.x, acc[i][0]);
            acc[i][1] = fmaf(av[i], w4.y, acc[i][1]);
            acc[i][2] = fmaf(av[i], w4.z, acc[i][2]);
            acc[i][3] = fmaf(av[i], w4.w, acc[i][3]);
        }
    }
#pragma unroll
    for (int i = 0; i < 8; ++i) {
        int row = row0 + rg * 8 + i;
        if (row < nrows) {
            float4 o = make_float4(acc[i][0], acc[i][1], acc[i][2], acc[i][3]);
            ((float4*)(out + (size_t)row * H))[cg] = o;
        }
    }
}

// ---------------- fused gather agg + self + bias + relu + score-dot ----------------
// 8 nodes per 256-block, 32 threads/node, float4 per thread, 4-edge unroll (ILP).
// One scalar gather per edge (premultiplied mnorm).

__global__ __launch_bounds__(256) void agg_fused_kernel(const float* __restrict__ xw,
        const int* __restrict__ rowptr, const int* __restrict__ srcC,
        const float* __restrict__ mask, const float* __restrict__ norm,
        const float* __restrict__ mnorm,
        const float* __restrict__ b, const float* __restrict__ Ws,
        float* __restrict__ hout, float* __restrict__ xws, int n) {
    int node = blockIdx.x * 8 + (threadIdx.x >> 5);
    if (node >= n) return;
    int t = threadIdx.x & 31;
    const float4* xw4 = (const float4*)xw;
    float md = mask[node];
    float nd = norm[node];
    float4 a0 = make_float4(0.f, 0.f, 0.f, 0.f);
    float4 a1 = a0, a2 = a0, a3 = a0;
    if (md != 0.f) {
        int e0 = rowptr[node], e1 = rowptr[node + 1];
        int e = e0;
        for (; e + 3 < e1; e += 4) {
            int s0 = srcC[e], s1 = srcC[e + 1], s2 = srcC[e + 2], s3 = srcC[e + 3];
            float c0 = mnorm[s0];
            float c1 = mnorm[s1];
            float c2 = mnorm[s2];
            float c3 = mnorm[s3];
            float4 v0 = xw4[(size_t)s0 * 32 + t];
            float4 v1 = xw4[(size_t)s1 * 32 + t];
            float4 v2 = xw4[(size_t)s2 * 32 + t];
            float4 v3 = xw4[(size_t)s3 * 32 + t];
            a0.x = fmaf(v0.x, c0, a0.x); a0.y = fmaf(v0.y, c0, a0.y);
            a0.z = fmaf(v0.z, c0, a0.z); a0.w = fmaf(v0.w, c0, a0.w);
            a1.x = fmaf(v1.x, c1, a1.x); a1.y = fmaf(v1.y, c1, a1.y);
            a1.z = fmaf(v1.z, c1, a1.z); a1.w = fmaf(v1.w, c1, a1.w);
            a2.x = fmaf(v2.x, c2, a2.x); a2.y = fmaf(v2.y, c2, a2.y);
            a2.z = fmaf(v2.z, c2, a2.z); a2.w = fmaf(v2.w, c2, a2.w);
            a3.x = fmaf(v3.x, c3, a3.x); a3.y = fmaf(v3.y, c3, a3.y);
            a3.z = fmaf(v3.z, c3, a3.z); a3.w = fmaf(v3.w, c3, a3.w);
        }
        for (; e < e1; ++e) {
            int s = srcC[e];
            float c = mnorm[s];
            float4 v = xw4[(size_t)s * 32 + t];
            a0.x = fmaf(v.x, c, a0.x); a0.y = fmaf(v.y, c, a0.y);
            a0.z = fmaf(v.z, c, a0.z); a0.w = fmaf(v.w, c, a0.w);
        }
        float sc = md * nd;
        a0.x = (((a0.x + a1.x) + a2.x) + a3.x) * sc;
        a0.y = (((a0.y + a1.y) + a2.y) + a3.y) * sc;
        a0.z = (((a0.z + a1.z) + a2.z) + a3.z) * sc;
        a0.w = (((a0.w + a1.w) + a2.w) + a3.w) * sc;
    }
    float4 self = xw4[(size_t)node * 32 + t];
    float4 bb = ((const float4*)b)[t];
    float n2 = nd * nd;
    float4 v;
    v.x = fmaxf(fmaf(self.x, n2, a0.x) + bb.x, 0.f);
    v.y = fmaxf(fmaf(self.y, n2, a0.y) + bb.y, 0.f);
    v.z = fmaxf(fmaf(self.z, n2, a0.z) + bb.z, 0.f);
    v.w = fmaxf(fmaf(self.w, n2, a0.w) + bb.w, 0.f);
    ((float4*)hout)[(size_t)node * 32 + t] = v;
    // fused score projection: xws[node] = dot(hout_row, Ws)
    float4 w = ((const float4*)Ws)[t];
    float p = ((v.x * w.x + v.y * w.y) + v.z * w.z) + v.w * w.w;
#pragma unroll
    for (int o = 16; o > 0; o >>= 1) p += __shfl_down(p, o, 32);
    if (t == 0) xws[node] = p;
}

// ---------------- score gather (scalar conv) ----------------

__global__ void score_gather_kernel(const int* __restrict__ rowptr, const int* __restrict__ srcC,
        const float* __restrict__ xws, const float* __restrict__ mask,
        const float* __restrict__ norm, const float* __restrict__ mnorm,
        const float* __restrict__ bs, float* __restrict__ score, int n) {
    int d = blockIdx.x * 256 + threadIdx.x;
    if (d >= n) return;
    float md = mask[d];
    float nd = norm[d];
    float acc = 0.f;
    if (md != 0.f) {
        int e0 = rowptr[d], e1 = rowptr[d + 1];
        for (int e = e0; e < e1; ++e) {
            int s = srcC[e];
            acc = fmaf(xws[s], mnorm[s], acc);
        }
        acc *= md * nd;
    }
    score[d] = acc + xws[d] * nd * nd + bs[0];
}

// ---------------- top-k per graph (exact reference semantics) + fused gfac ----------------

__global__ __launch_bounds__(256) void topk_kernel(const float* __restrict__ score,
        const float* __restrict__ mask, const int* __restrict__ starts,
        const int* __restrict__ counts, float* __restrict__ nmask,
        float* __restrict__ gfac) {
    int g = blockIdx.x;
    int s0 = starts[g], cnt = counts[g];
    __shared__ float ssc[1024];
    __shared__ float red[256];
    bool useL = (cnt <= 1024);
    float la = 0.f;
    for (int i = threadIdx.x; i < cnt; i += 256) {
        float m = mask[s0 + i];
        float sc = (m > 0.f) ? score[s0 + i] : -INFINITY;
        if (useL) ssc[i] = sc;
        if (m > 0.f) la += 1.f;
    }
    red[threadIdx.x] = la;
    __syncthreads();
    for (int o = 128; o > 0; o >>= 1) {
        if (threadIdx.x < o) red[threadIdx.x] += red[threadIdx.x + o];
        __syncthreads();
    }
    int kk = (int)ceilf(0.5f * red[0]);
    for (int i = threadIdx.x; i < cnt; i += 256) {
        float sci = useL ? ssc[i] : ((mask[s0 + i] > 0.f) ? score[s0 + i] : -INFINITY);
        float nm = 0.f;
        if (sci != -INFINITY) {
            int rank = 0;
            for (int j = 0; j < cnt; ++j) {
                float scj = useL ? ssc[j] : ((mask[s0 + j] > 0.f) ? score[s0 + j] : -INFINITY);
                rank += (scj > sci || (scj == sci && j < i)) ? 1 : 0;
            }
            if (rank < kk) nm = mask[s0 + i];
        }
        nmask[s0 + i] = nm;
        gfac[s0 + i] = (nm > 0.f) ? tanhf(sci) * nm : 0.f;
    }
}

// ---------------- readout (max || mean) on gated h, 4-way node-parallel ----------------

__global__ __launch_bounds__(512) void readout_kernel(const float* __restrict__ h,
        const float* __restrict__ mask, const float* __restrict__ gfac,
        const int* __restrict__ starts, const int* __restrict__ counts,
        float* __restrict__ r) {
    int g = blockIdx.x;
    int f = threadIdx.x & 127;
    int sub = threadIdx.x >> 7;
    int s0 = starts[g], cnt = counts[g];
    float s = 0.f, mx = -INFINITY, c = 0.f;
    for (int i = sub; i < cnt; i += 4) {
        float m = mask[s0 + i];
        if (m > 0.f) {
            float v = h[(size_t)(s0 + i) * H + f] * gfac[s0 + i];
            s += v; mx = fmaxf(mx, v); c += 1.f;
        }
    }
    __shared__ float ls[4][128];
    __shared__ float lm[4][128];
    __shared__ float lc[4];
    ls[sub][f] = s; lm[sub][f] = mx;
    if (f == 0) lc[sub] = c;
    __syncthreads();
    if (sub == 0) {
        float S = ((ls[0][f] + ls[1][f]) + ls[2][f]) + ls[3][f];
        float M = fmaxf(fmaxf(lm[0][f], lm[1][f]), fmaxf(lm[2][f], lm[3][f]));
        float C = ((lc[0] + lc[1]) + lc[2]) + lc[3];
        float mean = S / fmaxf(C, 1.f);
        if (C == 0.f) M = 0.f;
        r[(size_t)g * 2 * H + f] += M;
        r[(size_t)g * 2 * H + H + f] += mean;
    }
}

// ---------------- MLP head + log_softmax ----------------

__global__ __launch_bounds__(128) void mlp_kernel(const float* __restrict__ r,
        const float* __restrict__ Wl1, const float* __restrict__ bl1,
        const float* __restrict__ Wl2, const float* __restrict__ bl2,
        const float* __restrict__ Wl3, const float* __restrict__ bl3,
        float* __restrict__ out) {
    int g = blockIdx.x;
    int t = threadIdx.x;
    __shared__ float sz[256];
    __shared__ float sy1[128];
    __shared__ float sy2[64];
    __shared__ float sy3[10];
    __shared__ float sred[2];
    sz[t] = r[g * 256 + t];
    sz[t + 128] = r[g * 256 + 128 + t];
    __syncthreads();
    float a = bl1[t];
    for (int k = 0; k < 256; ++k) a = fmaf(sz[k], Wl1[k * 128 + t], a);
    sy1[t] = fmaxf(a, 0.f);
    __syncthreads();
    if (t < 64) {
        float a2 = bl2[t];
        for (int k = 0; k < 128; ++k) a2 = fmaf(sy1[k], Wl2[k * 64 + t], a2);
        sy2[t] = fmaxf(a2, 0.f);
    }
    __syncthreads();
    if (t < 10) {
        float a3 = bl3[t];
        for (int k = 0; k < 64; ++k) a3 = fmaf(sy2[k], Wl3[k * 10 + t], a3);
        sy3[t] = a3;
    }
    __syncthreads();
    if (t == 0) {
        float m = sy3[0];
        for (int c2 = 1; c2 < 10; ++c2) m = fmaxf(m, sy3[c2]);
        float se = 0.f;
        for (int c2 = 0; c2 < 10; ++c2) se += expf(sy3[c2] - m);
        sred[0] = m; sred[1] = logf(se);
    }
    __syncthreads();
    if (t < 10) out[g * 10 + t] = sy3[t] - sred[0] - sred[1];
}

// ---------------- launch ----------------

extern "C" void kernel_launch(void* const* d_in, const int* in_sizes, int n_in,
                              void* d_out, int out_size, void* d_ws, size_t ws_size,
                              hipStream_t stream) {
    const float* x     = (const float*)d_in[0];
    const int*   ei    = (const int*)d_in[1];
    const int*   batch = (const int*)d_in[2];
    const int* src  = ei;
    const int* dstp = ei + N_EDGES;
    const float* Wb[3]  = {(const float*)d_in[3], (const float*)d_in[7],  (const float*)d_in[11]};
    const float* bbv[3] = {(const float*)d_in[4], (const float*)d_in[8],  (const float*)d_in[12]};
    const float* Wsb[3] = {(const float*)d_in[5], (const float*)d_in[9],  (const float*)d_in[13]};
    const float* bsb[3] = {(const float*)d_in[6], (const float*)d_in[10], (const float*)d_in[14]};
    const float* Wl1 = (const float*)d_in[15];
    const float* bl1 = (const float*)d_in[16];
    const float* Wl2 = (const float*)d_in[17];
    const float* bl2 = (const float*)d_in[18];
    const float* Wl3 = (const float*)d_in[19];
    const float* bl3 = (const float*)d_in[20];
    float* out = (float*)d_out;

    // workspace carve (4B units)
    float* fws = (float*)d_ws;
    size_t off = 0;
    float* hA    = fws + off; off += (size_t)N_NODES * H;
    float* hB    = fws + off; off += (size_t)N_NODES * H;
    float* xw    = fws + off; off += (size_t)N_NODES * H;
    float* score = fws + off; off += N_NODES;
    float* xws   = fws + off; off += N_NODES;
    float* norm  = fws + off; off += N_NODES;
    float* mnorm = fws + off; off += N_NODES;
    float* mA    = fws + off; off += N_NODES;
    float* mB    = fws + off; off += N_NODES;
    float* gfac  = fws + off; off += N_NODES;
    float* rbuf  = fws + off; off += (size_t)G_GRAPHS * 2 * H;
    int* counts  = (int*)(fws + off); off += G_GRAPHS;
    int* starts  = (int*)(fws + off); off += G_GRAPHS;
    int* rowptr  = (int*)(fws + off); off += N_NODES + 1;
    int* indeg   = (int*)(fws + off); off += N_NODES;
    int* cursor  = (int*)(fws + off); off += N_NODES;
    int* srcC    = (int*)(fws + off); off += N_EDGES;

    int nblkN  = (N_NODES + 255) / 256;
    int nblkE  = (N_EDGES + 255) / 256;

    // graph segment structure (batch is sorted -> boundary detect, no atomics)
    starts_kernel<<<nblkN, 256, 0, stream>>>(batch, starts, N_NODES);
    counts_kernel<<<1, 128, 0, stream>>>(starts, counts);

    // CSR build (dst-grouped), deterministic via per-node sort
    hipMemsetAsync(indeg, 0, N_NODES * sizeof(int), stream);
    hipMemsetAsync(cursor, 0, N_NODES * sizeof(int), stream);
    indeg_kernel<<<nblkE, 256, 0, stream>>>(dstp, indeg, N_EDGES);
    scan_nodes_kernel<<<1, 1024, 0, stream>>>(indeg, rowptr);
    scatter_kernel<<<nblkE, 256, 0, stream>>>(src, dstp, rowptr, cursor, srcC, N_EDGES);
    sort_kernel<<<nblkN, 256, 0, stream>>>(rowptr, srcC, N_NODES);

    fill_kernel<<<nblkN, 256, 0, stream>>>(mA, 1.f, N_NODES);
    fill_kernel<<<nblkN, 256, 0, stream>>>(gfac, 1.f, N_NODES);
    hipMemsetAsync(rbuf, 0, G_GRAPHS * 2 * H * sizeof(float), stream);

    const float* hin = x;
    float* hout = hA;
    const float* mcur = mA;
    float* mnext = mB;

    for (int blk = 0; blk < 3; ++blk) {
        degnorm_kernel<<<nblkN, 256, 0, stream>>>(rowptr, srcC, mcur, norm, mnorm, N_NODES);
        gemm128_kernel<<<(N_NODES + 63) / 64, 256, 0, stream>>>(hin, Wb[blk], gfac, xw, N_NODES);
        agg_fused_kernel<<<(N_NODES + 7) / 8, 256, 0, stream>>>(xw, rowptr, srcC, mcur, norm,
                                                                mnorm, bbv[blk], Wsb[blk],
                                                                hout, xws, N_NODES);
        score_gather_kernel<<<nblkN, 256, 0, stream>>>(rowptr, srcC, xws, mcur, norm, mnorm,
                                                       bsb[blk], score, N_NODES);
        topk_kernel<<<G_GRAPHS, 256, 0, stream>>>(score, mcur, starts, counts, mnext, gfac);
        readout_kernel<<<G_GRAPHS, 512, 0, stream>>>(hout, mnext, gfac, starts, counts, rbuf);
        hin = hout;
        hout = (hout == hA) ? hB : hA;
        const float* tm = mcur; mcur = mnext; mnext = (float*)tm;
    }

    mlp_kernel<<<G_GRAPHS, 128, 0, stream>>>(rbuf, Wl1, bl1, Wl2, bl2, Wl3, bl3, out);
}

// Round 10
// 685.408 us; speedup vs baseline: 2.3214x; 1.3786x over previous
//
#include <hip/hip_runtime.h>
#include <math.h>

#define N_NODES 50000
#define N_EDGES 600000
#define H 128
#define G_GRAPHS 100
#define C_CLS 10

// ---------------- graph segment structure (batch sorted -> boundary detect) ----------------

__global__ void fill_kernel(float* __restrict__ p, float v, int n) {
    int i = blockIdx.x * 256 + threadIdx.x;
    if (i < n) p[i] = v;
}

// starts[g] = first index i with batch[i] == g (or next segment start if empty)
__global__ void starts_kernel(const int* __restrict__ batch, int* __restrict__ starts, int n) {
    int i = blockIdx.x * 256 + threadIdx.x;
    if (i >= n) return;
    int b = batch[i];
    int prev = (i == 0) ? -1 : batch[i - 1];
    for (int g = prev + 1; g <= b; ++g) starts[g] = i;
    if (i == n - 1) {
        for (int g = b + 1; g < G_GRAPHS; ++g) starts[g] = n;
    }
}

__global__ void counts_kernel(const int* __restrict__ starts, int* __restrict__ counts) {
    int g = threadIdx.x;
    if (g < G_GRAPHS) {
        int e = (g == G_GRAPHS - 1) ? N_NODES : starts[g + 1];
        counts[g] = e - starts[g];
    }
}

// ---------------- CSR build (dst-grouped, deterministic) ----------------

__global__ void indeg_kernel(const int* __restrict__ dst, int* __restrict__ indeg, int ne) {
    int e = blockIdx.x * 256 + threadIdx.x;
    if (e < ne) atomicAdd(&indeg[dst[e]], 1);
}

__global__ __launch_bounds__(1024) void scan_nodes_kernel(const int* __restrict__ indeg,
                                                          int* __restrict__ rowptr) {
    __shared__ int part[1024];
    const int t = threadIdx.x;
    const int chunk = (N_NODES + 1023) / 1024;
    const int base = t * chunk;
    int s = 0;
    for (int i = 0; i < chunk; ++i) {
        int idx = base + i;
        if (idx < N_NODES) s += indeg[idx];
    }
    part[t] = s;
    __syncthreads();
    for (int off = 1; off < 1024; off <<= 1) {
        int v = 0;
        if (t >= off) v = part[t - off];
        __syncthreads();
        if (t >= off) part[t] += v;
        __syncthreads();
    }
    int run = (t == 0) ? 0 : part[t - 1];
    for (int i = 0; i < chunk; ++i) {
        int idx = base + i;
        if (idx < N_NODES) { rowptr[idx] = run; run += indeg[idx]; }
    }
    if (t == 1023) rowptr[N_NODES] = run;
}

__global__ void scatter_kernel(const int* __restrict__ src, const int* __restrict__ dst,
                               const int* __restrict__ rowptr, int* __restrict__ cursor,
                               int* __restrict__ srcC, int ne) {
    int e = blockIdx.x * 256 + threadIdx.x;
    if (e >= ne) return;
    int d = dst[e];
    int pos = rowptr[d] + atomicAdd(&cursor[d], 1);
    srcC[pos] = src[e];
}

// per-node insertion sort by src -> deterministic gather order
__global__ void sort_kernel(const int* __restrict__ rowptr, int* __restrict__ srcC, int n) {
    int d = blockIdx.x * 256 + threadIdx.x;
    if (d >= n) return;
    int e0 = rowptr[d], e1 = rowptr[d + 1];
    for (int i = e0 + 1; i < e1; ++i) {
        int key = srcC[i];
        int j = i - 1;
        while (j >= e0 && srcC[j] > key) { srcC[j + 1] = srcC[j]; --j; }
        srcC[j + 1] = key;
    }
}

// ---------------- degree / norm (gather) + premultiplied mask*norm ----------------

__global__ void degnorm_kernel(const int* __restrict__ rowptr, const int* __restrict__ srcC,
                               const float* __restrict__ mask, float* __restrict__ norm,
                               float* __restrict__ mnorm, int n) {
    int d = blockIdx.x * 256 + threadIdx.x;
    if (d >= n) return;
    float md = mask[d];
    float s = 0.f;
    if (md != 0.f) {
        int e0 = rowptr[d], e1 = rowptr[d + 1];
        for (int e = e0; e < e1; ++e) s += mask[srcC[e]];
    }
    float nd = rsqrtf(1.f + md * s);
    norm[d] = nd;
    mnorm[d] = md * nd;
}

// ---------------- GEMM: out[n][128] = (gfac[n] * A[n][128]) @ W[128][128] ----------------

__global__ __launch_bounds__(256) void gemm128_kernel(const float* __restrict__ A,
                                                      const float* __restrict__ W,
                                                      const float* __restrict__ gf,
                                                      float* __restrict__ out, int nrows) {
    __shared__ float sT[128][68];
    int row0 = blockIdx.x * 64;
    int tid = threadIdx.x;
    for (int i = tid; i < 2048; i += 256) {
        int r = i >> 5, c4 = i & 31;
        int row = row0 + r;
        float4 v = make_float4(0.f, 0.f, 0.f, 0.f);
        if (row < nrows) {
            float g = gf[row];
            v = ((const float4*)(A + (size_t)row * H))[c4];
            v.x *= g; v.y *= g; v.z *= g; v.w *= g;
        }
        sT[c4 * 4 + 0][r] = v.x; sT[c4 * 4 + 1][r] = v.y;
        sT[c4 * 4 + 2][r] = v.z; sT[c4 * 4 + 3][r] = v.w;
    }
    __syncthreads();
    int cg = tid & 31;
    int rg = tid >> 5;
    float acc[8][4];
#pragma unroll
    for (int i = 0; i < 8; ++i)
#pragma unroll
        for (int j = 0; j < 4; ++j) acc[i][j] = 0.f;

    for (int k = 0; k < 128; ++k) {
        float4 w4 = ((const float4*)(W + k * H))[cg];
        const float4* pa = (const float4*)(&sT[k][rg * 8]);
        float4 a0 = pa[0], a1 = pa[1];
        float av[8] = {a0.x, a0.y, a0.z, a0.w, a1.x, a1.y, a1.z, a1.w};
#pragma unroll
        for (int i = 0; i < 8; ++i) {
            acc[i][0] = fmaf(av[i], w4.x, acc[i][0]);
            acc[i][1] = fmaf(av[i], w4.y, acc[i][1]);
            acc[i][2] = fmaf(av[i], w4.z, acc[i][2]);
            acc[i][3] = fmaf(av[i], w4.w, acc[i][3]);
        }
    }
#pragma unroll
    for (int i = 0; i < 8; ++i) {
        int row = row0 + rg * 8 + i;
        if (row < nrows) {
            float4 o = make_float4(acc[i][0], acc[i][1], acc[i][2], acc[i][3]);
            ((float4*)(out + (size_t)row * H))[cg] = o;
        }
    }
}

// ---------------- fused gather agg + self + bias + relu + score-dot ----------------

__global__ __launch_bounds__(256) void agg_fused_kernel(const float* __restrict__ xw,
        const int* __restrict__ rowptr, const int* __restrict__ srcC,
        const float* __restrict__ mask, const float* __restrict__ norm,
        const float* __restrict__ mnorm,
        const float* __restrict__ b, const float* __restrict__ Ws,
        float* __restrict__ hout, float* __restrict__ xws, int n) {
    int node = blockIdx.x * 8 + (threadIdx.x >> 5);
    if (node >= n) return;
    int t = threadIdx.x & 31;
    const float4* xw4 = (const float4*)xw;
    float md = mask[node];
    float nd = norm[node];
    float4 a0 = make_float4(0.f, 0.f, 0.f, 0.f);
    float4 a1 = a0, a2 = a0, a3 = a0;
    if (md != 0.f) {
        int e0 = rowptr[node], e1 = rowptr[node + 1];
        int e = e0;
        for (; e + 3 < e1; e += 4) {
            int s0 = srcC[e], s1 = srcC[e + 1], s2 = srcC[e + 2], s3 = srcC[e + 3];
            float c0 = mnorm[s0];
            float c1 = mnorm[s1];
            float c2 = mnorm[s2];
            float c3 = mnorm[s3];
            float4 v0 = xw4[(size_t)s0 * 32 + t];
            float4 v1 = xw4[(size_t)s1 * 32 + t];
            float4 v2 = xw4[(size_t)s2 * 32 + t];
            float4 v3 = xw4[(size_t)s3 * 32 + t];
            a0.x = fmaf(v0.x, c0, a0.x); a0.y = fmaf(v0.y, c0, a0.y);
            a0.z = fmaf(v0.z, c0, a0.z); a0.w = fmaf(v0.w, c0, a0.w);
            a1.x = fmaf(v1.x, c1, a1.x); a1.y = fmaf(v1.y, c1, a1.y);
            a1.z = fmaf(v1.z, c1, a1.z); a1.w = fmaf(v1.w, c1, a1.w);
            a2.x = fmaf(v2.x, c2, a2.x); a2.y = fmaf(v2.y, c2, a2.y);
            a2.z = fmaf(v2.z, c2, a2.z); a2.w = fmaf(v2.w, c2, a2.w);
            a3.x = fmaf(v3.x, c3, a3.x); a3.y = fmaf(v3.y, c3, a3.y);
            a3.z = fmaf(v3.z, c3, a3.z); a3.w = fmaf(v3.w, c3, a3.w);
        }
        for (; e < e1; ++e) {
            int s = srcC[e];
            float c = mnorm[s];
            float4 v = xw4[(size_t)s * 32 + t];
            a0.x = fmaf(v.x, c, a0.x); a0.y = fmaf(v.y, c, a0.y);
            a0.z = fmaf(v.z, c, a0.z); a0.w = fmaf(v.w, c, a0.w);
        }
        float sc = md * nd;
        a0.x = (((a0.x + a1.x) + a2.x) + a3.x) * sc;
        a0.y = (((a0.y + a1.y) + a2.y) + a3.y) * sc;
        a0.z = (((a0.z + a1.z) + a2.z) + a3.z) * sc;
        a0.w = (((a0.w + a1.w) + a2.w) + a3.w) * sc;
    }
    float4 self = xw4[(size_t)node * 32 + t];
    float4 bb = ((const float4*)b)[t];
    float n2 = nd * nd;
    float4 v;
    v.x = fmaxf(fmaf(self.x, n2, a0.x) + bb.x, 0.f);
    v.y = fmaxf(fmaf(self.y, n2, a0.y) + bb.y, 0.f);
    v.z = fmaxf(fmaf(self.z, n2, a0.z) + bb.z, 0.f);
    v.w = fmaxf(fmaf(self.w, n2, a0.w) + bb.w, 0.f);
    ((float4*)hout)[(size_t)node * 32 + t] = v;
    // fused score projection: xws[node] = dot(hout_row, Ws)
    float4 w = ((const float4*)Ws)[t];
    float p = ((v.x * w.x + v.y * w.y) + v.z * w.z) + v.w * w.w;
#pragma unroll
    for (int o = 16; o > 0; o >>= 1) p += __shfl_down(p, o, 32);
    if (t == 0) xws[node] = p;
}

// ---------------- score gather -> masked score (scorem = active ? score : -inf) ----------------

__global__ void score_gather_kernel(const int* __restrict__ rowptr, const int* __restrict__ srcC,
        const float* __restrict__ xws, const float* __restrict__ mask,
        const float* __restrict__ norm, const float* __restrict__ mnorm,
        const float* __restrict__ bs, float* __restrict__ scorem, int n) {
    int d = blockIdx.x * 256 + threadIdx.x;
    if (d >= n) return;
    float md = mask[d];
    float nd = norm[d];
    float out;
    if (md != 0.f) {
        float acc = 0.f;
        int e0 = rowptr[d], e1 = rowptr[d + 1];
        for (int e = e0; e < e1; ++e) {
            int s = srcC[e];
            acc = fmaf(xws[s], mnorm[s], acc);
        }
        acc *= md * nd;
        out = acc + xws[d] * nd * nd + bs[0];
    } else {
        out = -INFINITY;
    }
    scorem[d] = out;
}

// ---------------- per-graph k (ceil(0.5 * active)) ----------------

__global__ __launch_bounds__(256) void kk_kernel(const float* __restrict__ scorem,
        const int* __restrict__ starts, const int* __restrict__ counts,
        int* __restrict__ kkarr) {
    int g = blockIdx.x;
    int s0 = starts[g], cnt = counts[g];
    __shared__ int red[256];
    int c = 0;
    for (int i = threadIdx.x; i < cnt; i += 256)
        if (scorem[s0 + i] != -INFINITY) ++c;
    red[threadIdx.x] = c;
    __syncthreads();
    for (int o = 128; o > 0; o >>= 1) {
        if (threadIdx.x < o) red[threadIdx.x] += red[threadIdx.x + o];
        __syncthreads();
    }
    if (threadIdx.x == 0) kkarr[g] = (int)ceilf(0.5f * (float)red[0]);
}

// ---------------- rank-based top-k: one 64-lane wave per node ----------------
// keep i iff active and #{j active: s_j > s_i or (s_j == s_i and j < i)} < kk[g].
// Identical tie-break to stable argsort (global index order). Deterministic.

__global__ __launch_bounds__(256) void rank_kernel(const float* __restrict__ scorem,
        const float* __restrict__ mask, const int* __restrict__ batch,
        const int* __restrict__ starts, const int* __restrict__ counts,
        const int* __restrict__ kkarr,
        float* __restrict__ nmask, float* __restrict__ gfac, int n) {
    int i = blockIdx.x * 4 + (threadIdx.x >> 6);
    if (i >= n) return;
    int lane = threadIdx.x & 63;
    float sci = scorem[i];
    if (sci == -INFINITY) {
        if (lane == 0) { nmask[i] = 0.f; gfac[i] = 0.f; }
        return;
    }
    int g = batch[i];
    int s0 = starts[g], cnt = counts[g];
    int r = 0;
    for (int j = lane; j < cnt; j += 64) {
        float sj = scorem[s0 + j];
        if (sj > sci || (sj == sci && (s0 + j) < i)) ++r;
    }
#pragma unroll
    for (int o = 32; o > 0; o >>= 1) r += __shfl_down(r, o);
    if (lane == 0) {
        bool keep = (r < kkarr[g]);
        float m = mask[i];
        nmask[i] = keep ? m : 0.f;
        gfac[i] = keep ? tanhf(sci) * m : 0.f;
    }
}

// ---------------- readout (max || mean) on gated h, 4-way node-parallel ----------------

__global__ __launch_bounds__(512) void readout_kernel(const float* __restrict__ h,
        const float* __restrict__ mask, const float* __restrict__ gfac,
        const int* __restrict__ starts, const int* __restrict__ counts,
        float* __restrict__ r) {
    int g = blockIdx.x;
    int f = threadIdx.x & 127;
    int sub = threadIdx.x >> 7;
    int s0 = starts[g], cnt = counts[g];
    float s = 0.f, mx = -INFINITY, c = 0.f;
    for (int i = sub; i < cnt; i += 4) {
        float m = mask[s0 + i];
        if (m > 0.f) {
            float v = h[(size_t)(s0 + i) * H + f] * gfac[s0 + i];
            s += v; mx = fmaxf(mx, v); c += 1.f;
        }
    }
    __shared__ float ls[4][128];
    __shared__ float lm[4][128];
    __shared__ float lc[4];
    ls[sub][f] = s; lm[sub][f] = mx;
    if (f == 0) lc[sub] = c;
    __syncthreads();
    if (sub == 0) {
        float S = ((ls[0][f] + ls[1][f]) + ls[2][f]) + ls[3][f];
        float M = fmaxf(fmaxf(lm[0][f], lm[1][f]), fmaxf(lm[2][f], lm[3][f]));
        float C = ((lc[0] + lc[1]) + lc[2]) + lc[3];
        float mean = S / fmaxf(C, 1.f);
        if (C == 0.f) M = 0.f;
        r[(size_t)g * 2 * H + f] += M;
        r[(size_t)g * 2 * H + H + f] += mean;
    }
}

// ---------------- MLP head + log_softmax ----------------

__global__ __launch_bounds__(128) void mlp_kernel(const float* __restrict__ r,
        const float* __restrict__ Wl1, const float* __restrict__ bl1,
        const float* __restrict__ Wl2, const float* __restrict__ bl2,
        const float* __restrict__ Wl3, const float* __restrict__ bl3,
        float* __restrict__ out) {
    int g = blockIdx.x;
    int t = threadIdx.x;
    __shared__ float sz[256];
    __shared__ float sy1[128];
    __shared__ float sy2[64];
    __shared__ float sy3[10];
    __shared__ float sred[2];
    sz[t] = r[g * 256 + t];
    sz[t + 128] = r[g * 256 + 128 + t];
    __syncthreads();
    float a = bl1[t];
    for (int k = 0; k < 256; ++k) a = fmaf(sz[k], Wl1[k * 128 + t], a);
    sy1[t] = fmaxf(a, 0.f);
    __syncthreads();
    if (t < 64) {
        float a2 = bl2[t];
        for (int k = 0; k < 128; ++k) a2 = fmaf(sy1[k], Wl2[k * 64 + t], a2);
        sy2[t] = fmaxf(a2, 0.f);
    }
    __syncthreads();
    if (t < 10) {
        float a3 = bl3[t];
        for (int k = 0; k < 64; ++k) a3 = fmaf(sy2[k], Wl3[k * 10 + t], a3);
        sy3[t] = a3;
    }
    __syncthreads();
    if (t == 0) {
        float m = sy3[0];
        for (int c2 = 1; c2 < 10; ++c2) m = fmaxf(m, sy3[c2]);
        float se = 0.f;
        for (int c2 = 0; c2 < 10; ++c2) se += expf(sy3[c2] - m);
        sred[0] = m; sred[1] = logf(se);
    }
    __syncthreads();
    if (t < 10) out[g * 10 + t] = sy3[t] - sred[0] - sred[1];
}

// ---------------- launch ----------------

extern "C" void kernel_launch(void* const* d_in, const int* in_sizes, int n_in,
                              void* d_out, int out_size, void* d_ws, size_t ws_size,
                              hipStream_t stream) {
    const float* x     = (const float*)d_in[0];
    const int*   ei    = (const int*)d_in[1];
    const int*   batch = (const int*)d_in[2];
    const int* src  = ei;
    const int* dstp = ei + N_EDGES;
    const float* Wb[3]  = {(const float*)d_in[3], (const float*)d_in[7],  (const float*)d_in[11]};
    const float* bbv[3] = {(const float*)d_in[4], (const float*)d_in[8],  (const float*)d_in[12]};
    const float* Wsb[3] = {(const float*)d_in[5], (const float*)d_in[9],  (const float*)d_in[13]};
    const float* bsb[3] = {(const float*)d_in[6], (const float*)d_in[10], (const float*)d_in[14]};
    const float* Wl1 = (const float*)d_in[15];
    const float* bl1 = (const float*)d_in[16];
    const float* Wl2 = (const float*)d_in[17];
    const float* bl2 = (const float*)d_in[18];
    const float* Wl3 = (const float*)d_in[19];
    const float* bl3 = (const float*)d_in[20];
    float* out = (float*)d_out;

    // workspace carve (4B units)
    float* fws = (float*)d_ws;
    size_t off = 0;
    float* hA     = fws + off; off += (size_t)N_NODES * H;
    float* hB     = fws + off; off += (size_t)N_NODES * H;
    float* xw     = fws + off; off += (size_t)N_NODES * H;
    float* scorem = fws + off; off += N_NODES;
    float* xws    = fws + off; off += N_NODES;
    float* norm   = fws + off; off += N_NODES;
    float* mnorm  = fws + off; off += N_NODES;
    float* mA     = fws + off; off += N_NODES;
    float* mB     = fws + off; off += N_NODES;
    float* gfac   = fws + off; off += N_NODES;
    float* rbuf   = fws + off; off += (size_t)G_GRAPHS * 2 * H;
    int* counts   = (int*)(fws + off); off += G_GRAPHS;
    int* starts   = (int*)(fws + off); off += G_GRAPHS;
    int* kkarr    = (int*)(fws + off); off += G_GRAPHS;
    int* rowptr   = (int*)(fws + off); off += N_NODES + 1;
    int* indeg    = (int*)(fws + off); off += N_NODES;
    int* cursor   = (int*)(fws + off); off += N_NODES;
    int* srcC     = (int*)(fws + off); off += N_EDGES;

    int nblkN  = (N_NODES + 255) / 256;
    int nblkE  = (N_EDGES + 255) / 256;

    // graph segment structure (batch is sorted -> boundary detect, no atomics)
    starts_kernel<<<nblkN, 256, 0, stream>>>(batch, starts, N_NODES);
    counts_kernel<<<1, 128, 0, stream>>>(starts, counts);

    // CSR build (dst-grouped), deterministic via per-node sort
    hipMemsetAsync(indeg, 0, N_NODES * sizeof(int), stream);
    hipMemsetAsync(cursor, 0, N_NODES * sizeof(int), stream);
    indeg_kernel<<<nblkE, 256, 0, stream>>>(dstp, indeg, N_EDGES);
    scan_nodes_kernel<<<1, 1024, 0, stream>>>(indeg, rowptr);
    scatter_kernel<<<nblkE, 256, 0, stream>>>(src, dstp, rowptr, cursor, srcC, N_EDGES);
    sort_kernel<<<nblkN, 256, 0, stream>>>(rowptr, srcC, N_NODES);

    fill_kernel<<<nblkN, 256, 0, stream>>>(mA, 1.f, N_NODES);
    fill_kernel<<<nblkN, 256, 0, stream>>>(gfac, 1.f, N_NODES);
    hipMemsetAsync(rbuf, 0, G_GRAPHS * 2 * H * sizeof(float), stream);

    const float* hin = x;
    float* hout = hA;
    const float* mcur = mA;
    float* mnext = mB;

    for (int blk = 0; blk < 3; ++blk) {
        degnorm_kernel<<<nblkN, 256, 0, stream>>>(rowptr, srcC, mcur, norm, mnorm, N_NODES);
        gemm128_kernel<<<(N_NODES + 63) / 64, 256, 0, stream>>>(hin, Wb[blk], gfac, xw, N_NODES);
        agg_fused_kernel<<<(N_NODES + 7) / 8, 256, 0, stream>>>(xw, rowptr, srcC, mcur, norm,
                                                                mnorm, bbv[blk], Wsb[blk],
                                                                hout, xws, N_NODES);
        score_gather_kernel<<<nblkN, 256, 0, stream>>>(rowptr, srcC, xws, mcur, norm, mnorm,
                                                       bsb[blk], scorem, N_NODES);
        kk_kernel<<<G_GRAPHS, 256, 0, stream>>>(scorem, starts, counts, kkarr);
        rank_kernel<<<(N_NODES + 3) / 4, 256, 0, stream>>>(scorem, mcur, batch, starts, counts,
                                                           kkarr, mnext, gfac, N_NODES);
        readout_kernel<<<G_GRAPHS, 512, 0, stream>>>(hout, mnext, gfac, starts, counts, rbuf);
        hin = hout;
        hout = (hout == hA) ? hB : hA;
        const float* tm = mcur; mcur = mnext; mnext = (float*)tm;
    }

    mlp_kernel<<<G_GRAPHS, 128, 0, stream>>>(rbuf, Wl1, bl1, Wl2, bl2, Wl3, bl3, out);
}

// Round 13
// 599.966 us; speedup vs baseline: 2.6520x; 1.1424x over previous
//
#include <hip/hip_runtime.h>
#include <math.h>

#define N_NODES 50000
#define N_EDGES 600000
#define H 128
#define G_GRAPHS 100
#define C_CLS 10
#define NBLK_SCAN ((N_NODES + 255) / 256)

// ---------------- graph segment structure (batch sorted -> boundary detect) ----------------

__global__ void fill_kernel(float* __restrict__ p, float v, int n) {
    int i = blockIdx.x * 256 + threadIdx.x;
    if (i < n) p[i] = v;
}

// starts[g] = first index i with batch[i] == g (or next segment start if empty)
__global__ void starts_kernel(const int* __restrict__ batch, int* __restrict__ starts, int n) {
    int i = blockIdx.x * 256 + threadIdx.x;
    if (i >= n) return;
    int b = batch[i];
    int prev = (i == 0) ? -1 : batch[i - 1];
    for (int g = prev + 1; g <= b; ++g) starts[g] = i;
    if (i == n - 1) {
        for (int g = b + 1; g < G_GRAPHS; ++g) starts[g] = n;
    }
}

__global__ void counts_kernel(const int* __restrict__ starts, int* __restrict__ counts) {
    int g = threadIdx.x;
    if (g < G_GRAPHS) {
        int e = (g == G_GRAPHS - 1) ? N_NODES : starts[g + 1];
        counts[g] = e - starts[g];
    }
}

// ---------------- CSR build (dst-grouped, deterministic) ----------------

__global__ void indeg_kernel(const int* __restrict__ dst, int* __restrict__ indeg, int ne) {
    int e = blockIdx.x * 256 + threadIdx.x;
    if (e < ne) atomicAdd(&indeg[dst[e]], 1);
}

// ---- 3-phase multi-block exclusive scan of indeg -> rowptr ----

__global__ void bsum_kernel(const int* __restrict__ indeg, int* __restrict__ bsum, int n) {
    __shared__ int red[256];
    int i = blockIdx.x * 256 + threadIdx.x;
    red[threadIdx.x] = (i < n) ? indeg[i] : 0;
    __syncthreads();
    for (int o = 128; o > 0; o >>= 1) {
        if (threadIdx.x < o) red[threadIdx.x] += red[threadIdx.x + o];
        __syncthreads();
    }
    if (threadIdx.x == 0) bsum[blockIdx.x] = red[0];
}

__global__ void bscan_kernel(const int* __restrict__ bsum, int* __restrict__ boff, int nb) {
    __shared__ int s[256];
    int t = threadIdx.x;
    s[t] = (t < nb) ? bsum[t] : 0;
    __syncthreads();
    for (int o = 1; o < 256; o <<= 1) {
        int v = (t >= o) ? s[t - o] : 0;
        __syncthreads();
        s[t] += v;
        __syncthreads();
    }
    if (t < nb) boff[t] = (t == 0) ? 0 : s[t - 1];
}

__global__ void rowptr_kernel(const int* __restrict__ indeg, const int* __restrict__ boff,
                              int* __restrict__ rowptr, int n) {
    __shared__ int s[256];
    int i = blockIdx.x * 256 + threadIdx.x;
    int t = threadIdx.x;
    int v = (i < n) ? indeg[i] : 0;
    s[t] = v;
    __syncthreads();
    for (int o = 1; o < 256; o <<= 1) {
        int u = (t >= o) ? s[t - o] : 0;
        __syncthreads();
        s[t] += u;
        __syncthreads();
    }
    int incl = s[t];
    int excl = incl - v;
    if (i < n) rowptr[i] = boff[blockIdx.x] + excl;
    if (i == n - 1) rowptr[n] = boff[blockIdx.x] + incl;
}

__global__ void scatter_kernel(const int* __restrict__ src, const int* __restrict__ dst,
                               const int* __restrict__ rowptr, int* __restrict__ cursor,
                               int* __restrict__ srcC, int ne) {
    int e = blockIdx.x * 256 + threadIdx.x;
    if (e >= ne) return;
    int d = dst[e];
    int pos = rowptr[d] + atomicAdd(&cursor[d], 1);
    srcC[pos] = src[e];
}

// per-node insertion sort by src -> deterministic gather order
__global__ void sort_kernel(const int* __restrict__ rowptr, int* __restrict__ srcC, int n) {
    int d = blockIdx.x * 256 + threadIdx.x;
    if (d >= n) return;
    int e0 = rowptr[d], e1 = rowptr[d + 1];
    for (int i = e0 + 1; i < e1; ++i) {
        int key = srcC[i];
        int j = i - 1;
        while (j >= e0 && srcC[j] > key) { srcC[j + 1] = srcC[j]; --j; }
        srcC[j + 1] = key;
    }
}

// ---------------- degree / norm (gather) + premultiplied mask*norm ----------------

__global__ void degnorm_kernel(const int* __restrict__ rowptr, const int* __restrict__ srcC,
                               const float* __restrict__ mask, float* __restrict__ norm,
                               float* __restrict__ mnorm, int n) {
    int d = blockIdx.x * 256 + threadIdx.x;
    if (d >= n) return;
    float md = mask[d];
    float s = 0.f;
    if (md != 0.f) {
        int e0 = rowptr[d], e1 = rowptr[d + 1];
        for (int e = e0; e < e1; ++e) s += mask[srcC[e]];
    }
    float nd = rsqrtf(1.f + md * s);
    norm[d] = nd;
    mnorm[d] = md * nd;
}

// ---------------- GEMM: out[n][128] = (gfac[n] * A[n][128]) @ W[128][128] ----------------

__global__ __launch_bounds__(256) void gemm128_kernel(const float* __restrict__ A,
                                                      const float* __restrict__ W,
                                                      const float* __restrict__ gf,
                                                      float* __restrict__ out, int nrows) {
    __shared__ float sT[128][68];
    int row0 = blockIdx.x * 64;
    int tid = threadIdx.x;
    for (int i = tid; i < 2048; i += 256) {
        int r = i >> 5, c4 = i & 31;
        int row = row0 + r;
        float4 v = make_float4(0.f, 0.f, 0.f, 0.f);
        if (row < nrows) {
            float g = gf[row];
            v = ((const float4*)(A + (size_t)row * H))[c4];
            v.x *= g; v.y *= g; v.z *= g; v.w *= g;
        }
        sT[c4 * 4 + 0][r] = v.x; sT[c4 * 4 + 1][r] = v.y;
        sT[c4 * 4 + 2][r] = v.z; sT[c4 * 4 + 3][r] = v.w;
    }
    __syncthreads();
    int cg = tid & 31;
    int rg = tid >> 5;
    float acc[8][4];
#pragma unroll
    for (int i = 0; i < 8; ++i)
#pragma unroll
        for (int j = 0; j < 4; ++j) acc[i][j] = 0.f;

    for (int k = 0; k < 128; ++k) {
        float4 w4 = ((const float4*)(W + k * H))[cg];
        const float4* pa = (const float4*)(&sT[k][rg * 8]);
        float4 a0 = pa[0], a1 = pa[1];
        float av[8] = {a0.x, a0.y, a0.z, a0.w, a1.x, a1.y, a1.z, a1.w};
#pragma unroll
        for (int i = 0; i < 8; ++i) {
            acc[i][0] = fmaf(av[i], w4.x, acc[i][0]);
            acc[i][1] = fmaf(av[i], w4.y, acc[i][1]);
            acc[i][2] = fmaf(av[i], w4.z, acc[i][2]);
            acc[i][3] = fmaf(av[i], w4.w, acc[i][3]);
        }
    }
#pragma unroll
    for (int i = 0; i < 8; ++i) {
        int row = row0 + rg * 8 + i;
        if (row < nrows) {
            float4 o = make_float4(acc[i][0], acc[i][1], acc[i][2], acc[i][3]);
            ((float4*)(out + (size_t)row * H))[cg] = o;
        }
    }
}

// ---------------- fused gather agg + self + bias + relu + score-dot ----------------

__global__ __launch_bounds__(256) void agg_fused_kernel(const float* __restrict__ xw,
        const int* __restrict__ rowptr, const int* __restrict__ srcC,
        const float* __restrict__ mask, const float* __restrict__ norm,
        const float* __restrict__ mnorm,
        const float* __restrict__ b, const float* __restrict__ Ws,
        float* __restrict__ hout, float* __restrict__ xws, int n) {
    int node = blockIdx.x * 8 + (threadIdx.x >> 5);
    if (node >= n) return;
    int t = threadIdx.x & 31;
    const float4* xw4 = (const float4*)xw;
    float md = mask[node];
    float nd = norm[node];
    float4 a0 = make_float4(0.f, 0.f, 0.f, 0.f);
    float4 a1 = a0, a2 = a0, a3 = a0;
    if (md != 0.f) {
        int e0 = rowptr[node], e1 = rowptr[node + 1];
        int e = e0;
        for (; e + 3 < e1; e += 4) {
            int s0 = srcC[e], s1 = srcC[e + 1], s2 = srcC[e + 2], s3 = srcC[e + 3];
            float c0 = mnorm[s0];
            float c1 = mnorm[s1];
            float c2 = mnorm[s2];
            float c3 = mnorm[s3];
            float4 v0 = xw4[(size_t)s0 * 32 + t];
            float4 v1 = xw4[(size_t)s1 * 32 + t];
            float4 v2 = xw4[(size_t)s2 * 32 + t];
            float4 v3 = xw4[(size_t)s3 * 32 + t];
            a0.x = fmaf(v0.x, c0, a0.x); a0.y = fmaf(v0.y, c0, a0.y);
            a0.z = fmaf(v0.z, c0, a0.z); a0.w = fmaf(v0.w, c0, a0.w);
            a1.x = fmaf(v1.x, c1, a1.x); a1.y = fmaf(v1.y, c1, a1.y);
            a1.z = fmaf(v1.z, c1, a1.z); a1.w = fmaf(v1.w, c1, a1.w);
            a2.x = fmaf(v2.x, c2, a2.x); a2.y = fmaf(v2.y, c2, a2.y);
            a2.z = fmaf(v2.z, c2, a2.z); a2.w = fmaf(v2.w, c2, a2.w);
            a3.x = fmaf(v3.x, c3, a3.x); a3.y = fmaf(v3.y, c3, a3.y);
            a3.z = fmaf(v3.z, c3, a3.z); a3.w = fmaf(v3.w, c3, a3.w);
        }
        for (; e < e1; ++e) {
            int s = srcC[e];
            float c = mnorm[s];
            float4 v = xw4[(size_t)s * 32 + t];
            a0.x = fmaf(v.x, c, a0.x); a0.y = fmaf(v.y, c, a0.y);
            a0.z = fmaf(v.z, c, a0.z); a0.w = fmaf(v.w, c, a0.w);
        }
        float sc = md * nd;
        a0.x = (((a0.x + a1.x) + a2.x) + a3.x) * sc;
        a0.y = (((a0.y + a1.y) + a2.y) + a3.y) * sc;
        a0.z = (((a0.z + a1.z) + a2.z) + a3.z) * sc;
        a0.w = (((a0.w + a1.w) + a2.w) + a3.w) * sc;
    }
    float4 self = xw4[(size_t)node * 32 + t];
    float4 bb = ((const float4*)b)[t];
    float n2 = nd * nd;
    float4 v;
    v.x = fmaxf(fmaf(self.x, n2, a0.x) + bb.x, 0.f);
    v.y = fmaxf(fmaf(self.y, n2, a0.y) + bb.y, 0.f);
    v.z = fmaxf(fmaf(self.z, n2, a0.z) + bb.z, 0.f);
    v.w = fmaxf(fmaf(self.w, n2, a0.w) + bb.w, 0.f);
    ((float4*)hout)[(size_t)node * 32 + t] = v;
    // fused score projection: xws[node] = dot(hout_row, Ws)
    float4 w = ((const float4*)Ws)[t];
    float p = ((v.x * w.x + v.y * w.y) + v.z * w.z) + v.w * w.w;
#pragma unroll
    for (int o = 16; o > 0; o >>= 1) p += __shfl_down(p, o, 32);
    if (t == 0) xws[node] = p;
}

// ---------------- score gather -> masked score (scorem = active ? score : -inf) ----------------

__global__ void score_gather_kernel(const int* __restrict__ rowptr, const int* __restrict__ srcC,
        const float* __restrict__ xws, const float* __restrict__ mask,
        const float* __restrict__ norm, const float* __restrict__ mnorm,
        const float* __restrict__ bs, float* __restrict__ scorem, int n) {
    int d = blockIdx.x * 256 + threadIdx.x;
    if (d >= n) return;
    float md = mask[d];
    float nd = norm[d];
    float out;
    if (md != 0.f) {
        float acc = 0.f;
        int e0 = rowptr[d], e1 = rowptr[d + 1];
        for (int e = e0; e < e1; ++e) {
            int s = srcC[e];
            acc = fmaf(xws[s], mnorm[s], acc);
        }
        acc *= md * nd;
        out = acc + xws[d] * nd * nd + bs[0];
    } else {
        out = -INFINITY;
    }
    scorem[d] = out;
}

// ---------------- per-graph k (ceil(0.5 * active)) ----------------

__global__ __launch_bounds__(256) void kk_kernel(const float* __restrict__ scorem,
        const int* __restrict__ starts, const int* __restrict__ counts,
        int* __restrict__ kkarr) {
    int g = blockIdx.x;
    int s0 = starts[g], cnt = counts[g];
    __shared__ int red[256];
    int c = 0;
    for (int i = threadIdx.x; i < cnt; i += 256)
        if (scorem[s0 + i] != -INFINITY) ++c;
    red[threadIdx.x] = c;
    __syncthreads();
    for (int o = 128; o > 0; o >>= 1) {
        if (threadIdx.x < o) red[threadIdx.x] += red[threadIdx.x + o];
        __syncthreads();
    }
    if (threadIdx.x == 0) kkarr[g] = (int)ceilf(0.5f * (float)red[0]);
}

// ---------------- rank-based top-k: one 64-lane wave per node ----------------

__global__ __launch_bounds__(256) void rank_kernel(const float* __restrict__ scorem,
        const float* __restrict__ mask, const int* __restrict__ batch,
        const int* __restrict__ starts, const int* __restrict__ counts,
        const int* __restrict__ kkarr,
        float* __restrict__ nmask, float* __restrict__ gfac, int n) {
    int i = blockIdx.x * 4 + (threadIdx.x >> 6);
    if (i >= n) return;
    int lane = threadIdx.x & 63;
    float sci = scorem[i];
    if (sci == -INFINITY) {
        if (lane == 0) { nmask[i] = 0.f; gfac[i] = 0.f; }
        return;
    }
    int g = batch[i];
    int s0 = starts[g], cnt = counts[g];
    int r = 0;
    for (int j = lane; j < cnt; j += 64) {
        float sj = scorem[s0 + j];
        if (sj > sci || (sj == sci && (s0 + j) < i)) ++r;
    }
#pragma unroll
    for (int o = 32; o > 0; o >>= 1) r += __shfl_down(r, o);
    if (lane == 0) {
        bool keep = (r < kkarr[g]);
        float m = mask[i];
        nmask[i] = keep ? m : 0.f;
        gfac[i] = keep ? tanhf(sci) * m : 0.f;
    }
}

// ---------------- readout (max || mean) on gated h, 4-way node-parallel ----------------

__global__ __launch_bounds__(512) void readout_kernel(const float* __restrict__ h,
        const float* __restrict__ mask, const float* __restrict__ gfac,
        const int* __restrict__ starts, const int* __restrict__ counts,
        float* __restrict__ r) {
    int g = blockIdx.x;
    int f = threadIdx.x & 127;
    int sub = threadIdx.x >> 7;
    int s0 = starts[g], cnt = counts[g];
    float s = 0.f, mx = -INFINITY, c = 0.f;
    for (int i = sub; i < cnt; i += 4) {
        float m = mask[s0 + i];
        if (m > 0.f) {
            float v = h[(size_t)(s0 + i) * H + f] * gfac[s0 + i];
            s += v; mx = fmaxf(mx, v); c += 1.f;
        }
    }
    __shared__ float ls[4][128];
    __shared__ float lm[4][128];
    __shared__ float lc[4];
    ls[sub][f] = s; lm[sub][f] = mx;
    if (f == 0) lc[sub] = c;
    __syncthreads();
    if (sub == 0) {
        float S = ((ls[0][f] + ls[1][f]) + ls[2][f]) + ls[3][f];
        float M = fmaxf(fmaxf(lm[0][f], lm[1][f]), fmaxf(lm[2][f], lm[3][f]));
        float C = ((lc[0] + lc[1]) + lc[2]) + lc[3];
        float mean = S / fmaxf(C, 1.f);
        if (C == 0.f) M = 0.f;
        r[(size_t)g * 2 * H + f] += M;
        r[(size_t)g * 2 * H + H + f] += mean;
    }
}

// ---------------- MLP head + log_softmax ----------------

__global__ __launch_bounds__(128) void mlp_kernel(const float* __restrict__ r,
        const float* __restrict__ Wl1, const float* __restrict__ bl1,
        const float* __restrict__ Wl2, const float* __restrict__ bl2,
        const float* __restrict__ Wl3, const float* __restrict__ bl3,
        float* __restrict__ out) {
    int g = blockIdx.x;
    int t = threadIdx.x;
    __shared__ float sz[256];
    __shared__ float sy1[128];
    __shared__ float sy2[64];
    __shared__ float sy3[10];
    __shared__ float sred[2];
    sz[t] = r[g * 256 + t];
    sz[t + 128] = r[g * 256 + 128 + t];
    __syncthreads();
    float a = bl1[t];
    for (int k = 0; k < 256; ++k) a = fmaf(sz[k], Wl1[k * 128 + t], a);
    sy1[t] = fmaxf(a, 0.f);
    __syncthreads();
    if (t < 64) {
        float a2 = bl2[t];
        for (int k = 0; k < 128; ++k) a2 = fmaf(sy1[k], Wl2[k * 64 + t], a2);
        sy2[t] = fmaxf(a2, 0.f);
    }
    __syncthreads();
    if (t < 10) {
        float a3 = bl3[t];
        for (int k = 0; k < 64; ++k) a3 = fmaf(sy2[k], Wl3[k * 10 + t], a3);
        sy3[t] = a3;
    }
    __syncthreads();
    if (t == 0) {
        float m = sy3[0];
        for (int c2 = 1; c2 < 10; ++c2) m = fmaxf(m, sy3[c2]);
        float se = 0.f;
        for (int c2 = 0; c2 < 10; ++c2) se += expf(sy3[c2] - m);
        sred[0] = m; sred[1] = logf(se);
    }
    __syncthreads();
    if (t < 10) out[g * 10 + t] = sy3[t] - sred[0] - sred[1];
}

// ---------------- launch ----------------

extern "C" void kernel_launch(void* const* d_in, const int* in_sizes, int n_in,
                              void* d_out, int out_size, void* d_ws, size_t ws_size,
                              hipStream_t stream) {
    const float* x     = (const float*)d_in[0];
    const int*   ei    = (const int*)d_in[1];
    const int*   batch = (const int*)d_in[2];
    const int* src  = ei;
    const int* dstp = ei + N_EDGES;
    const float* Wb[3]  = {(const float*)d_in[3], (const float*)d_in[7],  (const float*)d_in[11]};
    const float* bbv[3] = {(const float*)d_in[4], (const float*)d_in[8],  (const float*)d_in[12]};
    const float* Wsb[3] = {(const float*)d_in[5], (const float*)d_in[9],  (const float*)d_in[13]};
    const float* bsb[3] = {(const float*)d_in[6], (const float*)d_in[10], (const float*)d_in[14]};
    const float* Wl1 = (const float*)d_in[15];
    const float* bl1 = (const float*)d_in[16];
    const float* Wl2 = (const float*)d_in[17];
    const float* bl2 = (const float*)d_in[18];
    const float* Wl3 = (const float*)d_in[19];
    const float* bl3 = (const float*)d_in[20];
    float* out = (float*)d_out;

    // workspace carve (4B units)
    float* fws = (float*)d_ws;
    size_t off = 0;
    float* hA     = fws + off; off += (size_t)N_NODES * H;
    float* hB     = fws + off; off += (size_t)N_NODES * H;
    float* xw     = fws + off; off += (size_t)N_NODES * H;
    float* scorem = fws + off; off += N_NODES;
    float* xws    = fws + off; off += N_NODES;
    float* norm   = fws + off; off += N_NODES;
    float* mnorm  = fws + off; off += N_NODES;
    float* mA     = fws + off; off += N_NODES;
    float* mB     = fws + off; off += N_NODES;
    float* gfac   = fws + off; off += N_NODES;
    float* rbuf   = fws + off; off += (size_t)G_GRAPHS * 2 * H;
    int* counts   = (int*)(fws + off); off += G_GRAPHS;
    int* starts   = (int*)(fws + off); off += G_GRAPHS;
    int* kkarr    = (int*)(fws + off); off += G_GRAPHS;
    int* rowptr   = (int*)(fws + off); off += N_NODES + 1;
    int* indeg    = (int*)(fws + off); off += N_NODES;
    int* cursor   = (int*)(fws + off); off += N_NODES;
    int* bsum     = (int*)(fws + off); off += NBLK_SCAN;
    int* boff     = (int*)(fws + off); off += NBLK_SCAN;
    int* srcC     = (int*)(fws + off); off += N_EDGES;

    int nblkN  = (N_NODES + 255) / 256;
    int nblkE  = (N_EDGES + 255) / 256;

    // graph segment structure (batch is sorted -> boundary detect, no atomics)
    starts_kernel<<<nblkN, 256, 0, stream>>>(batch, starts, N_NODES);
    counts_kernel<<<1, 128, 0, stream>>>(starts, counts);

    // CSR build (dst-grouped), deterministic via per-node sort
    hipMemsetAsync(indeg, 0, N_NODES * sizeof(int), stream);
    hipMemsetAsync(cursor, 0, N_NODES * sizeof(int), stream);
    indeg_kernel<<<nblkE, 256, 0, stream>>>(dstp, indeg, N_EDGES);
    bsum_kernel<<<NBLK_SCAN, 256, 0, stream>>>(indeg, bsum, N_NODES);
    bscan_kernel<<<1, 256, 0, stream>>>(bsum, boff, NBLK_SCAN);
    rowptr_kernel<<<NBLK_SCAN, 256, 0, stream>>>(indeg, boff, rowptr, N_NODES);
    scatter_kernel<<<nblkE, 256, 0, stream>>>(src, dstp, rowptr, cursor, srcC, N_EDGES);
    sort_kernel<<<nblkN, 256, 0, stream>>>(rowptr, srcC, N_NODES);

    fill_kernel<<<nblkN, 256, 0, stream>>>(mA, 1.f, N_NODES);
    fill_kernel<<<nblkN, 256, 0, stream>>>(gfac, 1.f, N_NODES);
    hipMemsetAsync(rbuf, 0, G_GRAPHS * 2 * H * sizeof(float), stream);

    const float* hin = x;
    float* hout = hA;
    const float* mcur = mA;
    float* mnext = mB;

    for (int blk = 0; blk < 3; ++blk) {
        degnorm_kernel<<<nblkN, 256, 0, stream>>>(rowptr, srcC, mcur, norm, mnorm, N_NODES);
        gemm128_kernel<<<(N_NODES + 63) / 64, 256, 0, stream>>>(hin, Wb[blk], gfac, xw, N_NODES);
        agg_fused_kernel<<<(N_NODES + 7) / 8, 256, 0, stream>>>(xw, rowptr, srcC, mcur, norm,
                                                                mnorm, bbv[blk], Wsb[blk],
                                                                hout, xws, N_NODES);
        score_gather_kernel<<<nblkN, 256, 0, stream>>>(rowptr, srcC, xws, mcur, norm, mnorm,
                                                       bsb[blk], scorem, N_NODES);
        kk_kernel<<<G_GRAPHS, 256, 0, stream>>>(scorem, starts, counts, kkarr);
        rank_kernel<<<(N_NODES + 3) / 4, 256, 0, stream>>>(scorem, mcur, batch, starts, counts,
                                                           kkarr, mnext, gfac, N_NODES);
        readout_kernel<<<G_GRAPHS, 512, 0, stream>>>(hout, mnext, gfac, starts, counts, rbuf);
        hin = hout;
        hout = (hout == hA) ? hB : hA;
        const float* tm = mcur; mcur = mnext; mnext = (float*)tm;
    }

    mlp_kernel<<<G_GRAPHS, 128, 0, stream>>>(rbuf, Wl1, bl1, Wl2, bl2, Wl3, bl3, out);
}

// Round 14
// 509.881 us; speedup vs baseline: 3.1205x; 1.1767x over previous
//
#include <hip/hip_runtime.h>
#include <math.h>

#define N_NODES 50000
#define N_EDGES 600000
#define H 128
#define G_GRAPHS 100
#define C_CLS 10
#define NBLK_SCAN ((N_NODES + 255) / 256)
#define RSUB 16

// ---------------- graph segment structure (batch sorted -> boundary detect) ----------------

__global__ void fill_kernel(float* __restrict__ p, float v, int n) {
    int i = blockIdx.x * 256 + threadIdx.x;
    if (i < n) p[i] = v;
}

// starts[g] = first index i with batch[i] == g (or next segment start if empty)
__global__ void starts_kernel(const int* __restrict__ batch, int* __restrict__ starts, int n) {
    int i = blockIdx.x * 256 + threadIdx.x;
    if (i >= n) return;
    int b = batch[i];
    int prev = (i == 0) ? -1 : batch[i - 1];
    for (int g = prev + 1; g <= b; ++g) starts[g] = i;
    if (i == n - 1) {
        for (int g = b + 1; g < G_GRAPHS; ++g) starts[g] = n;
    }
}

__global__ void counts_kernel(const int* __restrict__ starts, int* __restrict__ counts) {
    int g = threadIdx.x;
    if (g < G_GRAPHS) {
        int e = (g == G_GRAPHS - 1) ? N_NODES : starts[g + 1];
        counts[g] = e - starts[g];
    }
}

// ---------------- CSR build (dst-grouped, deterministic) ----------------

__global__ void indeg_kernel(const int* __restrict__ dst, int* __restrict__ indeg, int ne) {
    int e = blockIdx.x * 256 + threadIdx.x;
    if (e < ne) atomicAdd(&indeg[dst[e]], 1);
}

// ---- 3-phase multi-block exclusive scan of indeg -> rowptr ----

__global__ void bsum_kernel(const int* __restrict__ indeg, int* __restrict__ bsum, int n) {
    __shared__ int red[256];
    int i = blockIdx.x * 256 + threadIdx.x;
    red[threadIdx.x] = (i < n) ? indeg[i] : 0;
    __syncthreads();
    for (int o = 128; o > 0; o >>= 1) {
        if (threadIdx.x < o) red[threadIdx.x] += red[threadIdx.x + o];
        __syncthreads();
    }
    if (threadIdx.x == 0) bsum[blockIdx.x] = red[0];
}

__global__ void bscan_kernel(const int* __restrict__ bsum, int* __restrict__ boff, int nb) {
    __shared__ int s[256];
    int t = threadIdx.x;
    s[t] = (t < nb) ? bsum[t] : 0;
    __syncthreads();
    for (int o = 1; o < 256; o <<= 1) {
        int v = (t >= o) ? s[t - o] : 0;
        __syncthreads();
        s[t] += v;
        __syncthreads();
    }
    if (t < nb) boff[t] = (t == 0) ? 0 : s[t - 1];
}

__global__ void rowptr_kernel(const int* __restrict__ indeg, const int* __restrict__ boff,
                              int* __restrict__ rowptr, int n) {
    __shared__ int s[256];
    int i = blockIdx.x * 256 + threadIdx.x;
    int t = threadIdx.x;
    int v = (i < n) ? indeg[i] : 0;
    s[t] = v;
    __syncthreads();
    for (int o = 1; o < 256; o <<= 1) {
        int u = (t >= o) ? s[t - o] : 0;
        __syncthreads();
        s[t] += u;
        __syncthreads();
    }
    int incl = s[t];
    int excl = incl - v;
    if (i < n) rowptr[i] = boff[blockIdx.x] + excl;
    if (i == n - 1) rowptr[n] = boff[blockIdx.x] + incl;
}

__global__ void scatter_kernel(const int* __restrict__ src, const int* __restrict__ dst,
                               const int* __restrict__ rowptr, int* __restrict__ cursor,
                               int* __restrict__ srcC, int ne) {
    int e = blockIdx.x * 256 + threadIdx.x;
    if (e >= ne) return;
    int d = dst[e];
    int pos = rowptr[d] + atomicAdd(&cursor[d], 1);
    srcC[pos] = src[e];
}

// per-node insertion sort by src -> deterministic gather order
__global__ void sort_kernel(const int* __restrict__ rowptr, int* __restrict__ srcC, int n) {
    int d = blockIdx.x * 256 + threadIdx.x;
    if (d >= n) return;
    int e0 = rowptr[d], e1 = rowptr[d + 1];
    for (int i = e0 + 1; i < e1; ++i) {
        int key = srcC[i];
        int j = i - 1;
        while (j >= e0 && srcC[j] > key) { srcC[j + 1] = srcC[j]; --j; }
        srcC[j + 1] = key;
    }
}

// ---------------- degree / norm (gather) + premultiplied mask*norm ----------------

__global__ void degnorm_kernel(const int* __restrict__ rowptr, const int* __restrict__ srcC,
                               const float* __restrict__ mask, float* __restrict__ norm,
                               float* __restrict__ mnorm, int n) {
    int d = blockIdx.x * 256 + threadIdx.x;
    if (d >= n) return;
    float md = mask[d];
    float s = 0.f;
    if (md != 0.f) {
        int e0 = rowptr[d], e1 = rowptr[d + 1];
        for (int e = e0; e < e1; ++e) s += mask[srcC[e]];
    }
    float nd = rsqrtf(1.f + md * s);
    norm[d] = nd;
    mnorm[d] = md * nd;
}

// ---------------- GEMM: out[n][128] = (gfac[n] * A[n][128]) @ W[128][128] ----------------

__global__ __launch_bounds__(256) void gemm128_kernel(const float* __restrict__ A,
                                                      const float* __restrict__ W,
                                                      const float* __restrict__ gf,
                                                      float* __restrict__ out, int nrows) {
    __shared__ float sT[128][68];
    int row0 = blockIdx.x * 64;
    int tid = threadIdx.x;
    for (int i = tid; i < 2048; i += 256) {
        int r = i >> 5, c4 = i & 31;
        int row = row0 + r;
        float4 v = make_float4(0.f, 0.f, 0.f, 0.f);
        if (row < nrows) {
            float g = gf[row];
            v = ((const float4*)(A + (size_t)row * H))[c4];
            v.x *= g; v.y *= g; v.z *= g; v.w *= g;
        }
        sT[c4 * 4 + 0][r] = v.x; sT[c4 * 4 + 1][r] = v.y;
        sT[c4 * 4 + 2][r] = v.z; sT[c4 * 4 + 3][r] = v.w;
    }
    __syncthreads();
    int cg = tid & 31;
    int rg = tid >> 5;
    float acc[8][4];
#pragma unroll
    for (int i = 0; i < 8; ++i)
#pragma unroll
        for (int j = 0; j < 4; ++j) acc[i][j] = 0.f;

    for (int k = 0; k < 128; ++k) {
        float4 w4 = ((const float4*)(W + k * H))[cg];
        const float4* pa = (const float4*)(&sT[k][rg * 8]);
        float4 a0 = pa[0], a1 = pa[1];
        float av[8] = {a0.x, a0.y, a0.z, a0.w, a1.x, a1.y, a1.z, a1.w};
#pragma unroll
        for (int i = 0; i < 8; ++i) {
            acc[i][0] = fmaf(av[i], w4.x, acc[i][0]);
            acc[i][1] = fmaf(av[i], w4.y, acc[i][1]);
            acc[i][2] = fmaf(av[i], w4.z, acc[i][2]);
            acc[i][3] = fmaf(av[i], w4.w, acc[i][3]);
        }
    }
#pragma unroll
    for (int i = 0; i < 8; ++i) {
        int row = row0 + rg * 8 + i;
        if (row < nrows) {
            float4 o = make_float4(acc[i][0], acc[i][1], acc[i][2], acc[i][3]);
            ((float4*)(out + (size_t)row * H))[cg] = o;
        }
    }
}

// ---------------- fused gather agg + self + bias + relu + score-dot ----------------

__global__ __launch_bounds__(256) void agg_fused_kernel(const float* __restrict__ xw,
        const int* __restrict__ rowptr, const int* __restrict__ srcC,
        const float* __restrict__ mask, const float* __restrict__ norm,
        const float* __restrict__ mnorm,
        const float* __restrict__ b, const float* __restrict__ Ws,
        float* __restrict__ hout, float* __restrict__ xws, int n) {
    int node = blockIdx.x * 8 + (threadIdx.x >> 5);
    if (node >= n) return;
    int t = threadIdx.x & 31;
    const float4* xw4 = (const float4*)xw;
    float md = mask[node];
    float nd = norm[node];
    float4 a0 = make_float4(0.f, 0.f, 0.f, 0.f);
    float4 a1 = a0, a2 = a0, a3 = a0;
    if (md != 0.f) {
        int e0 = rowptr[node], e1 = rowptr[node + 1];
        int e = e0;
        for (; e + 3 < e1; e += 4) {
            int s0 = srcC[e], s1 = srcC[e + 1], s2 = srcC[e + 2], s3 = srcC[e + 3];
            float c0 = mnorm[s0];
            float c1 = mnorm[s1];
            float c2 = mnorm[s2];
            float c3 = mnorm[s3];
            float4 v0 = xw4[(size_t)s0 * 32 + t];
            float4 v1 = xw4[(size_t)s1 * 32 + t];
            float4 v2 = xw4[(size_t)s2 * 32 + t];
            float4 v3 = xw4[(size_t)s3 * 32 + t];
            a0.x = fmaf(v0.x, c0, a0.x); a0.y = fmaf(v0.y, c0, a0.y);
            a0.z = fmaf(v0.z, c0, a0.z); a0.w = fmaf(v0.w, c0, a0.w);
            a1.x = fmaf(v1.x, c1, a1.x); a1.y = fmaf(v1.y, c1, a1.y);
            a1.z = fmaf(v1.z, c1, a1.z); a1.w = fmaf(v1.w, c1, a1.w);
            a2.x = fmaf(v2.x, c2, a2.x); a2.y = fmaf(v2.y, c2, a2.y);
            a2.z = fmaf(v2.z, c2, a2.z); a2.w = fmaf(v2.w, c2, a2.w);
            a3.x = fmaf(v3.x, c3, a3.x); a3.y = fmaf(v3.y, c3, a3.y);
            a3.z = fmaf(v3.z, c3, a3.z); a3.w = fmaf(v3.w, c3, a3.w);
        }
        for (; e < e1; ++e) {
            int s = srcC[e];
            float c = mnorm[s];
            float4 v = xw4[(size_t)s * 32 + t];
            a0.x = fmaf(v.x, c, a0.x); a0.y = fmaf(v.y, c, a0.y);
            a0.z = fmaf(v.z, c, a0.z); a0.w = fmaf(v.w, c, a0.w);
        }
        float sc = md * nd;
        a0.x = (((a0.x + a1.x) + a2.x) + a3.x) * sc;
        a0.y = (((a0.y + a1.y) + a2.y) + a3.y) * sc;
        a0.z = (((a0.z + a1.z) + a2.z) + a3.z) * sc;
        a0.w = (((a0.w + a1.w) + a2.w) + a3.w) * sc;
    }
    float4 self = xw4[(size_t)node * 32 + t];
    float4 bb = ((const float4*)b)[t];
    float n2 = nd * nd;
    float4 v;
    v.x = fmaxf(fmaf(self.x, n2, a0.x) + bb.x, 0.f);
    v.y = fmaxf(fmaf(self.y, n2, a0.y) + bb.y, 0.f);
    v.z = fmaxf(fmaf(self.z, n2, a0.z) + bb.z, 0.f);
    v.w = fmaxf(fmaf(self.w, n2, a0.w) + bb.w, 0.f);
    ((float4*)hout)[(size_t)node * 32 + t] = v;
    // fused score projection: xws[node] = dot(hout_row, Ws)
    float4 w = ((const float4*)Ws)[t];
    float p = ((v.x * w.x + v.y * w.y) + v.z * w.z) + v.w * w.w;
#pragma unroll
    for (int o = 16; o > 0; o >>= 1) p += __shfl_down(p, o, 32);
    if (t == 0) xws[node] = p;
}

// ---------------- score gather -> masked score (scorem = active ? score : -inf) ----------------

__global__ void score_gather_kernel(const int* __restrict__ rowptr, const int* __restrict__ srcC,
        const float* __restrict__ xws, const float* __restrict__ mask,
        const float* __restrict__ norm, const float* __restrict__ mnorm,
        const float* __restrict__ bs, float* __restrict__ scorem, int n) {
    int d = blockIdx.x * 256 + threadIdx.x;
    if (d >= n) return;
    float md = mask[d];
    float nd = norm[d];
    float out;
    if (md != 0.f) {
        float acc = 0.f;
        int e0 = rowptr[d], e1 = rowptr[d + 1];
        for (int e = e0; e < e1; ++e) {
            int s = srcC[e];
            acc = fmaf(xws[s], mnorm[s], acc);
        }
        acc *= md * nd;
        out = acc + xws[d] * nd * nd + bs[0];
    } else {
        out = -INFINITY;
    }
    scorem[d] = out;
}

// ---------------- per-graph k (ceil(0.5 * active)) ----------------

__global__ __launch_bounds__(256) void kk_kernel(const float* __restrict__ scorem,
        const int* __restrict__ starts, const int* __restrict__ counts,
        int* __restrict__ kkarr) {
    int g = blockIdx.x;
    int s0 = starts[g], cnt = counts[g];
    __shared__ int red[256];
    int c = 0;
    for (int i = threadIdx.x; i < cnt; i += 256)
        if (scorem[s0 + i] != -INFINITY) ++c;
    red[threadIdx.x] = c;
    __syncthreads();
    for (int o = 128; o > 0; o >>= 1) {
        if (threadIdx.x < o) red[threadIdx.x] += red[threadIdx.x + o];
        __syncthreads();
    }
    if (threadIdx.x == 0) kkarr[g] = (int)ceilf(0.5f * (float)red[0]);
}

// ---------------- rank-based top-k: one 64-lane wave per node ----------------

__global__ __launch_bounds__(256) void rank_kernel(const float* __restrict__ scorem,
        const float* __restrict__ mask, const int* __restrict__ batch,
        const int* __restrict__ starts, const int* __restrict__ counts,
        const int* __restrict__ kkarr,
        float* __restrict__ nmask, float* __restrict__ gfac, int n) {
    int i = blockIdx.x * 4 + (threadIdx.x >> 6);
    if (i >= n) return;
    int lane = threadIdx.x & 63;
    float sci = scorem[i];
    if (sci == -INFINITY) {
        if (lane == 0) { nmask[i] = 0.f; gfac[i] = 0.f; }
        return;
    }
    int g = batch[i];
    int s0 = starts[g], cnt = counts[g];
    int r = 0;
    for (int j = lane; j < cnt; j += 64) {
        float sj = scorem[s0 + j];
        if (sj > sci || (sj == sci && (s0 + j) < i)) ++r;
    }
#pragma unroll
    for (int o = 32; o > 0; o >>= 1) r += __shfl_down(r, o);
    if (lane == 0) {
        bool keep = (r < kkarr[g]);
        float m = mask[i];
        nmask[i] = keep ? m : 0.f;
        gfac[i] = keep ? tanhf(sci) * m : 0.f;
    }
}

// ---------------- readout phase 1: per-(graph, sub-slice) partials ----------------
// 1600 blocks (100 graphs x 16 slices), 128 threads; deterministic fixed-stride order.

__global__ __launch_bounds__(128) void readout_part_kernel(const float* __restrict__ h,
        const float* __restrict__ mask, const float* __restrict__ gfac,
        const int* __restrict__ starts, const int* __restrict__ counts,
        float* __restrict__ partS, float* __restrict__ partM, float* __restrict__ partC) {
    int g = blockIdx.x >> 4;
    int sub = blockIdx.x & (RSUB - 1);
    int f = threadIdx.x;
    int s0 = starts[g], cnt = counts[g];
    float s = 0.f, mx = -INFINITY, c = 0.f;
    for (int i = sub; i < cnt; i += RSUB) {
        float m = mask[s0 + i];
        if (m > 0.f) {
            float v = h[(size_t)(s0 + i) * H + f] * gfac[s0 + i];
            s += v; mx = fmaxf(mx, v); c += 1.f;
        }
    }
    size_t pidx = (size_t)blockIdx.x * H + f;
    partS[pidx] = s;
    partM[pidx] = mx;
    if (f == 0) partC[blockIdx.x] = c;
}

// ---------------- readout phase 2: combine partials in fixed order -> rbuf ----------------

__global__ __launch_bounds__(128) void readout_comb_kernel(const float* __restrict__ partS,
        const float* __restrict__ partM, const float* __restrict__ partC,
        float* __restrict__ r) {
    int g = blockIdx.x;
    int f = threadIdx.x;
    float S = 0.f, M = -INFINITY, C = 0.f;
    for (int sub = 0; sub < RSUB; ++sub) {
        size_t pidx = (size_t)(g * RSUB + sub) * H + f;
        S += partS[pidx];
        M = fmaxf(M, partM[pidx]);
        C += partC[g * RSUB + sub];
    }
    float mean = S / fmaxf(C, 1.f);
    if (C == 0.f) M = 0.f;
    r[(size_t)g * 2 * H + f] += M;
    r[(size_t)g * 2 * H + H + f] += mean;
}

// ---------------- MLP head + log_softmax ----------------

__global__ __launch_bounds__(128) void mlp_kernel(const float* __restrict__ r,
        const float* __restrict__ Wl1, const float* __restrict__ bl1,
        const float* __restrict__ Wl2, const float* __restrict__ bl2,
        const float* __restrict__ Wl3, const float* __restrict__ bl3,
        float* __restrict__ out) {
    int g = blockIdx.x;
    int t = threadIdx.x;
    __shared__ float sz[256];
    __shared__ float sy1[128];
    __shared__ float sy2[64];
    __shared__ float sy3[10];
    __shared__ float sred[2];
    sz[t] = r[g * 256 + t];
    sz[t + 128] = r[g * 256 + 128 + t];
    __syncthreads();
    float a = bl1[t];
    for (int k = 0; k < 256; ++k) a = fmaf(sz[k], Wl1[k * 128 + t], a);
    sy1[t] = fmaxf(a, 0.f);
    __syncthreads();
    if (t < 64) {
        float a2 = bl2[t];
        for (int k = 0; k < 128; ++k) a2 = fmaf(sy1[k], Wl2[k * 64 + t], a2);
        sy2[t] = fmaxf(a2, 0.f);
    }
    __syncthreads();
    if (t < 10) {
        float a3 = bl3[t];
        for (int k = 0; k < 64; ++k) a3 = fmaf(sy2[k], Wl3[k * 10 + t], a3);
        sy3[t] = a3;
    }
    __syncthreads();
    if (t == 0) {
        float m = sy3[0];
        for (int c2 = 1; c2 < 10; ++c2) m = fmaxf(m, sy3[c2]);
        float se = 0.f;
        for (int c2 = 0; c2 < 10; ++c2) se += expf(sy3[c2] - m);
        sred[0] = m; sred[1] = logf(se);
    }
    __syncthreads();
    if (t < 10) out[g * 10 + t] = sy3[t] - sred[0] - sred[1];
}

// ---------------- launch ----------------

extern "C" void kernel_launch(void* const* d_in, const int* in_sizes, int n_in,
                              void* d_out, int out_size, void* d_ws, size_t ws_size,
                              hipStream_t stream) {
    const float* x     = (const float*)d_in[0];
    const int*   ei    = (const int*)d_in[1];
    const int*   batch = (const int*)d_in[2];
    const int* src  = ei;
    const int* dstp = ei + N_EDGES;
    const float* Wb[3]  = {(const float*)d_in[3], (const float*)d_in[7],  (const float*)d_in[11]};
    const float* bbv[3] = {(const float*)d_in[4], (const float*)d_in[8],  (const float*)d_in[12]};
    const float* Wsb[3] = {(const float*)d_in[5], (const float*)d_in[9],  (const float*)d_in[13]};
    const float* bsb[3] = {(const float*)d_in[6], (const float*)d_in[10], (const float*)d_in[14]};
    const float* Wl1 = (const float*)d_in[15];
    const float* bl1 = (const float*)d_in[16];
    const float* Wl2 = (const float*)d_in[17];
    const float* bl2 = (const float*)d_in[18];
    const float* Wl3 = (const float*)d_in[19];
    const float* bl3 = (const float*)d_in[20];
    float* out = (float*)d_out;

    // workspace carve (4B units)
    float* fws = (float*)d_ws;
    size_t off = 0;
    float* hA     = fws + off; off += (size_t)N_NODES * H;
    float* hB     = fws + off; off += (size_t)N_NODES * H;
    float* xw     = fws + off; off += (size_t)N_NODES * H;
    float* scorem = fws + off; off += N_NODES;
    float* xws    = fws + off; off += N_NODES;
    float* norm   = fws + off; off += N_NODES;
    float* mnorm  = fws + off; off += N_NODES;
    float* mA     = fws + off; off += N_NODES;
    float* mB     = fws + off; off += N_NODES;
    float* gfac   = fws + off; off += N_NODES;
    float* rbuf   = fws + off; off += (size_t)G_GRAPHS * 2 * H;
    float* partS  = fws + off; off += (size_t)G_GRAPHS * RSUB * H;
    float* partM  = fws + off; off += (size_t)G_GRAPHS * RSUB * H;
    float* partC  = fws + off; off += (size_t)G_GRAPHS * RSUB;
    int* counts   = (int*)(fws + off); off += G_GRAPHS;
    int* starts   = (int*)(fws + off); off += G_GRAPHS;
    int* kkarr    = (int*)(fws + off); off += G_GRAPHS;
    int* rowptr   = (int*)(fws + off); off += N_NODES + 1;
    int* indeg    = (int*)(fws + off); off += N_NODES;
    int* cursor   = (int*)(fws + off); off += N_NODES;
    int* bsum     = (int*)(fws + off); off += NBLK_SCAN;
    int* boff     = (int*)(fws + off); off += NBLK_SCAN;
    int* srcC     = (int*)(fws + off); off += N_EDGES;

    int nblkN  = (N_NODES + 255) / 256;
    int nblkE  = (N_EDGES + 255) / 256;

    // graph segment structure (batch is sorted -> boundary detect, no atomics)
    starts_kernel<<<nblkN, 256, 0, stream>>>(batch, starts, N_NODES);
    counts_kernel<<<1, 128, 0, stream>>>(starts, counts);

    // CSR build (dst-grouped), deterministic via per-node sort
    hipMemsetAsync(indeg, 0, N_NODES * sizeof(int), stream);
    hipMemsetAsync(cursor, 0, N_NODES * sizeof(int), stream);
    indeg_kernel<<<nblkE, 256, 0, stream>>>(dstp, indeg, N_EDGES);
    bsum_kernel<<<NBLK_SCAN, 256, 0, stream>>>(indeg, bsum, N_NODES);
    bscan_kernel<<<1, 256, 0, stream>>>(bsum, boff, NBLK_SCAN);
    rowptr_kernel<<<NBLK_SCAN, 256, 0, stream>>>(indeg, boff, rowptr, N_NODES);
    scatter_kernel<<<nblkE, 256, 0, stream>>>(src, dstp, rowptr, cursor, srcC, N_EDGES);
    sort_kernel<<<nblkN, 256, 0, stream>>>(rowptr, srcC, N_NODES);

    fill_kernel<<<nblkN, 256, 0, stream>>>(mA, 1.f, N_NODES);
    fill_kernel<<<nblkN, 256, 0, stream>>>(gfac, 1.f, N_NODES);
    hipMemsetAsync(rbuf, 0, G_GRAPHS * 2 * H * sizeof(float), stream);

    const float* hin = x;
    float* hout = hA;
    const float* mcur = mA;
    float* mnext = mB;

    for (int blk = 0; blk < 3; ++blk) {
        degnorm_kernel<<<nblkN, 256, 0, stream>>>(rowptr, srcC, mcur, norm, mnorm, N_NODES);
        gemm128_kernel<<<(N_NODES + 63) / 64, 256, 0, stream>>>(hin, Wb[blk], gfac, xw, N_NODES);
        agg_fused_kernel<<<(N_NODES + 7) / 8, 256, 0, stream>>>(xw, rowptr, srcC, mcur, norm,
                                                                mnorm, bbv[blk], Wsb[blk],
                                                                hout, xws, N_NODES);
        score_gather_kernel<<<nblkN, 256, 0, stream>>>(rowptr, srcC, xws, mcur, norm, mnorm,
                                                       bsb[blk], scorem, N_NODES);
        kk_kernel<<<G_GRAPHS, 256, 0, stream>>>(scorem, starts, counts, kkarr);
        rank_kernel<<<(N_NODES + 3) / 4, 256, 0, stream>>>(scorem, mcur, batch, starts, counts,
                                                           kkarr, mnext, gfac, N_NODES);
        readout_part_kernel<<<G_GRAPHS * RSUB, 128, 0, stream>>>(hout, mnext, gfac, starts,
                                                                 counts, partS, partM, partC);
        readout_comb_kernel<<<G_GRAPHS, 128, 0, stream>>>(partS, partM, partC, rbuf);
        hin = hout;
        hout = (hout == hA) ? hB : hA;
        const float* tm = mcur; mcur = mnext; mnext = (float*)tm;
    }

    mlp_kernel<<<G_GRAPHS, 128, 0, stream>>>(rbuf, Wl1, bl1, Wl2, bl2, Wl3, bl3, out);
}

// Round 15
// 478.370 us; speedup vs baseline: 3.3261x; 1.0659x over previous
//
#include <hip/hip_runtime.h>
#include <math.h>

#define N_NODES 50000
#define N_EDGES 600000
#define H 128
#define G_GRAPHS 100
#define C_CLS 10
#define NBLK_SCAN ((N_NODES + 255) / 256)
#define RSUB 16

// ---------------- graph segment structure (batch sorted -> boundary detect) ----------------

__global__ void fill_kernel(float* __restrict__ p, float v, int n) {
    int i = blockIdx.x * 256 + threadIdx.x;
    if (i < n) p[i] = v;
}

// starts[g] = first index i with batch[i] == g (or next segment start if empty)
__global__ void starts_kernel(const int* __restrict__ batch, int* __restrict__ starts, int n) {
    int i = blockIdx.x * 256 + threadIdx.x;
    if (i >= n) return;
    int b = batch[i];
    int prev = (i == 0) ? -1 : batch[i - 1];
    for (int g = prev + 1; g <= b; ++g) starts[g] = i;
    if (i == n - 1) {
        for (int g = b + 1; g < G_GRAPHS; ++g) starts[g] = n;
    }
}

__global__ void counts_kernel(const int* __restrict__ starts, int* __restrict__ counts) {
    int g = threadIdx.x;
    if (g < G_GRAPHS) {
        int e = (g == G_GRAPHS - 1) ? N_NODES : starts[g + 1];
        counts[g] = e - starts[g];
    }
}

// ---------------- CSR build (dst-grouped, deterministic) ----------------

__global__ void indeg_kernel(const int* __restrict__ dst, int* __restrict__ indeg, int ne) {
    int e = blockIdx.x * 256 + threadIdx.x;
    if (e < ne) atomicAdd(&indeg[dst[e]], 1);
}

// ---- 3-phase multi-block exclusive scan of indeg -> rowptr ----

__global__ void bsum_kernel(const int* __restrict__ indeg, int* __restrict__ bsum, int n) {
    __shared__ int red[256];
    int i = blockIdx.x * 256 + threadIdx.x;
    red[threadIdx.x] = (i < n) ? indeg[i] : 0;
    __syncthreads();
    for (int o = 128; o > 0; o >>= 1) {
        if (threadIdx.x < o) red[threadIdx.x] += red[threadIdx.x + o];
        __syncthreads();
    }
    if (threadIdx.x == 0) bsum[blockIdx.x] = red[0];
}

__global__ void bscan_kernel(const int* __restrict__ bsum, int* __restrict__ boff, int nb) {
    __shared__ int s[256];
    int t = threadIdx.x;
    s[t] = (t < nb) ? bsum[t] : 0;
    __syncthreads();
    for (int o = 1; o < 256; o <<= 1) {
        int v = (t >= o) ? s[t - o] : 0;
        __syncthreads();
        s[t] += v;
        __syncthreads();
    }
    if (t < nb) boff[t] = (t == 0) ? 0 : s[t - 1];
}

__global__ void rowptr_kernel(const int* __restrict__ indeg, const int* __restrict__ boff,
                              int* __restrict__ rowptr, int n) {
    __shared__ int s[256];
    int i = blockIdx.x * 256 + threadIdx.x;
    int t = threadIdx.x;
    int v = (i < n) ? indeg[i] : 0;
    s[t] = v;
    __syncthreads();
    for (int o = 1; o < 256; o <<= 1) {
        int u = (t >= o) ? s[t - o] : 0;
        __syncthreads();
        s[t] += u;
        __syncthreads();
    }
    int incl = s[t];
    int excl = incl - v;
    if (i < n) rowptr[i] = boff[blockIdx.x] + excl;
    if (i == n - 1) rowptr[n] = boff[blockIdx.x] + incl;
}

__global__ void scatter_kernel(const int* __restrict__ src, const int* __restrict__ dst,
                               const int* __restrict__ rowptr, int* __restrict__ cursor,
                               int* __restrict__ srcC, int ne) {
    int e = blockIdx.x * 256 + threadIdx.x;
    if (e >= ne) return;
    int d = dst[e];
    int pos = rowptr[d] + atomicAdd(&cursor[d], 1);
    srcC[pos] = src[e];
}

// ---------------- wave-per-node odd-even sort (canonical ascending; deterministic) ----------
// lane l holds element l of the node's segment; len phases of shfl neighbor exchange.
// Ties are equal values -> canonical content identical to any stable/unstable sort.

__global__ __launch_bounds__(256) void wsort_kernel(const int* __restrict__ rowptr,
                                                    int* __restrict__ srcC, int n) {
    int node = blockIdx.x * 4 + (threadIdx.x >> 6);
    if (node >= n) return;
    int lane = threadIdx.x & 63;
    int e0 = rowptr[node], e1 = rowptr[node + 1];
    int len = e1 - e0;
    if (len <= 1) return;
    if (len <= 64) {
        int key = (lane < len) ? srcC[e0 + lane] : 0x7fffffff;
        for (int p = 0; p < len; ++p) {
            int partner = ((lane ^ p) & 1) ? lane - 1 : lane + 1;
            int pv = __shfl(key, partner & 63, 64);
            if (partner >= 0 && partner < 64) {
                key = (partner > lane) ? min(key, pv) : max(key, pv);
            }
        }
        if (lane < len) srcC[e0 + lane] = key;
    } else {
        // never expected (Poisson(12) indegree); correctness fallback
        if (lane == 0) {
            for (int i = e0 + 1; i < e1; ++i) {
                int k = srcC[i];
                int j = i - 1;
                while (j >= e0 && srcC[j] > k) { srcC[j + 1] = srcC[j]; --j; }
                srcC[j + 1] = k;
            }
        }
    }
}

// ---------------- degree / norm (gather) + premultiplied mask*norm ----------------

__global__ void degnorm_kernel(const int* __restrict__ rowptr, const int* __restrict__ srcC,
                               const float* __restrict__ mask, float* __restrict__ norm,
                               float* __restrict__ mnorm, int n) {
    int d = blockIdx.x * 256 + threadIdx.x;
    if (d >= n) return;
    float md = mask[d];
    float s = 0.f;
    if (md != 0.f) {
        int e0 = rowptr[d], e1 = rowptr[d + 1];
        for (int e = e0; e < e1; ++e) s += mask[srcC[e]];
    }
    float nd = rsqrtf(1.f + md * s);
    norm[d] = nd;
    mnorm[d] = md * nd;
}

// ---------------- GEMM: out[n][128] = (gfac[n] * A[n][128]) @ W[128][128] ----------------

__global__ __launch_bounds__(256) void gemm128_kernel(const float* __restrict__ A,
                                                      const float* __restrict__ W,
                                                      const float* __restrict__ gf,
                                                      float* __restrict__ out, int nrows) {
    __shared__ float sT[128][68];
    int row0 = blockIdx.x * 64;
    int tid = threadIdx.x;
    for (int i = tid; i < 2048; i += 256) {
        int r = i >> 5, c4 = i & 31;
        int row = row0 + r;
        float4 v = make_float4(0.f, 0.f, 0.f, 0.f);
        if (row < nrows) {
            float g = gf[row];
            v = ((const float4*)(A + (size_t)row * H))[c4];
            v.x *= g; v.y *= g; v.z *= g; v.w *= g;
        }
        sT[c4 * 4 + 0][r] = v.x; sT[c4 * 4 + 1][r] = v.y;
        sT[c4 * 4 + 2][r] = v.z; sT[c4 * 4 + 3][r] = v.w;
    }
    __syncthreads();
    int cg = tid & 31;
    int rg = tid >> 5;
    float acc[8][4];
#pragma unroll
    for (int i = 0; i < 8; ++i)
#pragma unroll
        for (int j = 0; j < 4; ++j) acc[i][j] = 0.f;

    for (int k = 0; k < 128; ++k) {
        float4 w4 = ((const float4*)(W + k * H))[cg];
        const float4* pa = (const float4*)(&sT[k][rg * 8]);
        float4 a0 = pa[0], a1 = pa[1];
        float av[8] = {a0.x, a0.y, a0.z, a0.w, a1.x, a1.y, a1.z, a1.w};
#pragma unroll
        for (int i = 0; i < 8; ++i) {
            acc[i][0] = fmaf(av[i], w4.x, acc[i][0]);
            acc[i][1] = fmaf(av[i], w4.y, acc[i][1]);
            acc[i][2] = fmaf(av[i], w4.z, acc[i][2]);
            acc[i][3] = fmaf(av[i], w4.w, acc[i][3]);
        }
    }
#pragma unroll
    for (int i = 0; i < 8; ++i) {
        int row = row0 + rg * 8 + i;
        if (row < nrows) {
            float4 o = make_float4(acc[i][0], acc[i][1], acc[i][2], acc[i][3]);
            ((float4*)(out + (size_t)row * H))[cg] = o;
        }
    }
}

// ---------------- fused gather agg + self + bias + relu + score-dot ----------------

__global__ __launch_bounds__(256) void agg_fused_kernel(const float* __restrict__ xw,
        const int* __restrict__ rowptr, const int* __restrict__ srcC,
        const float* __restrict__ mask, const float* __restrict__ norm,
        const float* __restrict__ mnorm,
        const float* __restrict__ b, const float* __restrict__ Ws,
        float* __restrict__ hout, float* __restrict__ xws, int n) {
    int node = blockIdx.x * 8 + (threadIdx.x >> 5);
    if (node >= n) return;
    int t = threadIdx.x & 31;
    const float4* xw4 = (const float4*)xw;
    float md = mask[node];
    float nd = norm[node];
    float4 a0 = make_float4(0.f, 0.f, 0.f, 0.f);
    float4 a1 = a0, a2 = a0, a3 = a0;
    if (md != 0.f) {
        int e0 = rowptr[node], e1 = rowptr[node + 1];
        int e = e0;
        for (; e + 3 < e1; e += 4) {
            int s0 = srcC[e], s1 = srcC[e + 1], s2 = srcC[e + 2], s3 = srcC[e + 3];
            float c0 = mnorm[s0];
            float c1 = mnorm[s1];
            float c2 = mnorm[s2];
            float c3 = mnorm[s3];
            float4 v0 = xw4[(size_t)s0 * 32 + t];
            float4 v1 = xw4[(size_t)s1 * 32 + t];
            float4 v2 = xw4[(size_t)s2 * 32 + t];
            float4 v3 = xw4[(size_t)s3 * 32 + t];
            a0.x = fmaf(v0.x, c0, a0.x); a0.y = fmaf(v0.y, c0, a0.y);
            a0.z = fmaf(v0.z, c0, a0.z); a0.w = fmaf(v0.w, c0, a0.w);
            a1.x = fmaf(v1.x, c1, a1.x); a1.y = fmaf(v1.y, c1, a1.y);
            a1.z = fmaf(v1.z, c1, a1.z); a1.w = fmaf(v1.w, c1, a1.w);
            a2.x = fmaf(v2.x, c2, a2.x); a2.y = fmaf(v2.y, c2, a2.y);
            a2.z = fmaf(v2.z, c2, a2.z); a2.w = fmaf(v2.w, c2, a2.w);
            a3.x = fmaf(v3.x, c3, a3.x); a3.y = fmaf(v3.y, c3, a3.y);
            a3.z = fmaf(v3.z, c3, a3.z); a3.w = fmaf(v3.w, c3, a3.w);
        }
        for (; e < e1; ++e) {
            int s = srcC[e];
            float c = mnorm[s];
            float4 v = xw4[(size_t)s * 32 + t];
            a0.x = fmaf(v.x, c, a0.x); a0.y = fmaf(v.y, c, a0.y);
            a0.z = fmaf(v.z, c, a0.z); a0.w = fmaf(v.w, c, a0.w);
        }
        float sc = md * nd;
        a0.x = (((a0.x + a1.x) + a2.x) + a3.x) * sc;
        a0.y = (((a0.y + a1.y) + a2.y) + a3.y) * sc;
        a0.z = (((a0.z + a1.z) + a2.z) + a3.z) * sc;
        a0.w = (((a0.w + a1.w) + a2.w) + a3.w) * sc;
    }
    float4 self = xw4[(size_t)node * 32 + t];
    float4 bb = ((const float4*)b)[t];
    float n2 = nd * nd;
    float4 v;
    v.x = fmaxf(fmaf(self.x, n2, a0.x) + bb.x, 0.f);
    v.y = fmaxf(fmaf(self.y, n2, a0.y) + bb.y, 0.f);
    v.z = fmaxf(fmaf(self.z, n2, a0.z) + bb.z, 0.f);
    v.w = fmaxf(fmaf(self.w, n2, a0.w) + bb.w, 0.f);
    ((float4*)hout)[(size_t)node * 32 + t] = v;
    // fused score projection: xws[node] = dot(hout_row, Ws)
    float4 w = ((const float4*)Ws)[t];
    float p = ((v.x * w.x + v.y * w.y) + v.z * w.z) + v.w * w.w;
#pragma unroll
    for (int o = 16; o > 0; o >>= 1) p += __shfl_down(p, o, 32);
    if (t == 0) xws[node] = p;
}

// ---------------- score gather -> masked score (scorem = active ? score : -inf) ----------------

__global__ void score_gather_kernel(const int* __restrict__ rowptr, const int* __restrict__ srcC,
        const float* __restrict__ xws, const float* __restrict__ mask,
        const float* __restrict__ norm, const float* __restrict__ mnorm,
        const float* __restrict__ bs, float* __restrict__ scorem, int n) {
    int d = blockIdx.x * 256 + threadIdx.x;
    if (d >= n) return;
    float md = mask[d];
    float nd = norm[d];
    float out;
    if (md != 0.f) {
        float acc = 0.f;
        int e0 = rowptr[d], e1 = rowptr[d + 1];
        for (int e = e0; e < e1; ++e) {
            int s = srcC[e];
            acc = fmaf(xws[s], mnorm[s], acc);
        }
        acc *= md * nd;
        out = acc + xws[d] * nd * nd + bs[0];
    } else {
        out = -INFINITY;
    }
    scorem[d] = out;
}

// ---------------- per-graph k (ceil(0.5 * active)) ----------------

__global__ __launch_bounds__(256) void kk_kernel(const float* __restrict__ scorem,
        const int* __restrict__ starts, const int* __restrict__ counts,
        int* __restrict__ kkarr) {
    int g = blockIdx.x;
    int s0 = starts[g], cnt = counts[g];
    __shared__ int red[256];
    int c = 0;
    for (int i = threadIdx.x; i < cnt; i += 256)
        if (scorem[s0 + i] != -INFINITY) ++c;
    red[threadIdx.x] = c;
    __syncthreads();
    for (int o = 128; o > 0; o >>= 1) {
        if (threadIdx.x < o) red[threadIdx.x] += red[threadIdx.x + o];
        __syncthreads();
    }
    if (threadIdx.x == 0) kkarr[g] = (int)ceilf(0.5f * (float)red[0]);
}

// ---------------- rank-based top-k: one 64-lane wave per node ----------------

__global__ __launch_bounds__(256) void rank_kernel(const float* __restrict__ scorem,
        const float* __restrict__ mask, const int* __restrict__ batch,
        const int* __restrict__ starts, const int* __restrict__ counts,
        const int* __restrict__ kkarr,
        float* __restrict__ nmask, float* __restrict__ gfac, int n) {
    int i = blockIdx.x * 4 + (threadIdx.x >> 6);
    if (i >= n) return;
    int lane = threadIdx.x & 63;
    float sci = scorem[i];
    if (sci == -INFINITY) {
        if (lane == 0) { nmask[i] = 0.f; gfac[i] = 0.f; }
        return;
    }
    int g = batch[i];
    int s0 = starts[g], cnt = counts[g];
    int r = 0;
    for (int j = lane; j < cnt; j += 64) {
        float sj = scorem[s0 + j];
        if (sj > sci || (sj == sci && (s0 + j) < i)) ++r;
    }
#pragma unroll
    for (int o = 32; o > 0; o >>= 1) r += __shfl_down(r, o);
    if (lane == 0) {
        bool keep = (r < kkarr[g]);
        float m = mask[i];
        nmask[i] = keep ? m : 0.f;
        gfac[i] = keep ? tanhf(sci) * m : 0.f;
    }
}

// ---------------- readout phase 1: per-(graph, sub-slice) partials ----------------

__global__ __launch_bounds__(128) void readout_part_kernel(const float* __restrict__ h,
        const float* __restrict__ mask, const float* __restrict__ gfac,
        const int* __restrict__ starts, const int* __restrict__ counts,
        float* __restrict__ partS, float* __restrict__ partM, float* __restrict__ partC) {
    int g = blockIdx.x >> 4;
    int sub = blockIdx.x & (RSUB - 1);
    int f = threadIdx.x;
    int s0 = starts[g], cnt = counts[g];
    float s = 0.f, mx = -INFINITY, c = 0.f;
    for (int i = sub; i < cnt; i += RSUB) {
        float m = mask[s0 + i];
        if (m > 0.f) {
            float v = h[(size_t)(s0 + i) * H + f] * gfac[s0 + i];
            s += v; mx = fmaxf(mx, v); c += 1.f;
        }
    }
    size_t pidx = (size_t)blockIdx.x * H + f;
    partS[pidx] = s;
    partM[pidx] = mx;
    if (f == 0) partC[blockIdx.x] = c;
}

// ---------------- readout phase 2: combine partials in fixed order -> rbuf ----------------

__global__ __launch_bounds__(128) void readout_comb_kernel(const float* __restrict__ partS,
        const float* __restrict__ partM, const float* __restrict__ partC,
        float* __restrict__ r) {
    int g = blockIdx.x;
    int f = threadIdx.x;
    float S = 0.f, M = -INFINITY, C = 0.f;
    for (int sub = 0; sub < RSUB; ++sub) {
        size_t pidx = (size_t)(g * RSUB + sub) * H + f;
        S += partS[pidx];
        M = fmaxf(M, partM[pidx]);
        C += partC[g * RSUB + sub];
    }
    float mean = S / fmaxf(C, 1.f);
    if (C == 0.f) M = 0.f;
    r[(size_t)g * 2 * H + f] += M;
    r[(size_t)g * 2 * H + H + f] += mean;
}

// ---------------- MLP head + log_softmax ----------------

__global__ __launch_bounds__(128) void mlp_kernel(const float* __restrict__ r,
        const float* __restrict__ Wl1, const float* __restrict__ bl1,
        const float* __restrict__ Wl2, const float* __restrict__ bl2,
        const float* __restrict__ Wl3, const float* __restrict__ bl3,
        float* __restrict__ out) {
    int g = blockIdx.x;
    int t = threadIdx.x;
    __shared__ float sz[256];
    __shared__ float sy1[128];
    __shared__ float sy2[64];
    __shared__ float sy3[10];
    __shared__ float sred[2];
    sz[t] = r[g * 256 + t];
    sz[t + 128] = r[g * 256 + 128 + t];
    __syncthreads();
    float a = bl1[t];
    for (int k = 0; k < 256; ++k) a = fmaf(sz[k], Wl1[k * 128 + t], a);
    sy1[t] = fmaxf(a, 0.f);
    __syncthreads();
    if (t < 64) {
        float a2 = bl2[t];
        for (int k = 0; k < 128; ++k) a2 = fmaf(sy1[k], Wl2[k * 64 + t], a2);
        sy2[t] = fmaxf(a2, 0.f);
    }
    __syncthreads();
    if (t < 10) {
        float a3 = bl3[t];
        for (int k = 0; k < 64; ++k) a3 = fmaf(sy2[k], Wl3[k * 10 + t], a3);
        sy3[t] = a3;
    }
    __syncthreads();
    if (t == 0) {
        float m = sy3[0];
        for (int c2 = 1; c2 < 10; ++c2) m = fmaxf(m, sy3[c2]);
        float se = 0.f;
        for (int c2 = 0; c2 < 10; ++c2) se += expf(sy3[c2] - m);
        sred[0] = m; sred[1] = logf(se);
    }
    __syncthreads();
    if (t < 10) out[g * 10 + t] = sy3[t] - sred[0] - sred[1];
}

// ---------------- launch ----------------

extern "C" void kernel_launch(void* const* d_in, const int* in_sizes, int n_in,
                              void* d_out, int out_size, void* d_ws, size_t ws_size,
                              hipStream_t stream) {
    const float* x     = (const float*)d_in[0];
    const int*   ei    = (const int*)d_in[1];
    const int*   batch = (const int*)d_in[2];
    const int* src  = ei;
    const int* dstp = ei + N_EDGES;
    const float* Wb[3]  = {(const float*)d_in[3], (const float*)d_in[7],  (const float*)d_in[11]};
    const float* bbv[3] = {(const float*)d_in[4], (const float*)d_in[8],  (const float*)d_in[12]};
    const float* Wsb[3] = {(const float*)d_in[5], (const float*)d_in[9],  (const float*)d_in[13]};
    const float* bsb[3] = {(const float*)d_in[6], (const float*)d_in[10], (const float*)d_in[14]};
    const float* Wl1 = (const float*)d_in[15];
    const float* bl1 = (const float*)d_in[16];
    const float* Wl2 = (const float*)d_in[17];
    const float* bl2 = (const float*)d_in[18];
    const float* Wl3 = (const float*)d_in[19];
    const float* bl3 = (const float*)d_in[20];
    float* out = (float*)d_out;

    // workspace carve (4B units)
    float* fws = (float*)d_ws;
    size_t off = 0;
    float* hA     = fws + off; off += (size_t)N_NODES * H;
    float* hB     = fws + off; off += (size_t)N_NODES * H;
    float* xw     = fws + off; off += (size_t)N_NODES * H;
    float* scorem = fws + off; off += N_NODES;
    float* xws    = fws + off; off += N_NODES;
    float* norm   = fws + off; off += N_NODES;
    float* mnorm  = fws + off; off += N_NODES;
    float* mA     = fws + off; off += N_NODES;
    float* mB     = fws + off; off += N_NODES;
    float* gfac   = fws + off; off += N_NODES;
    float* rbuf   = fws + off; off += (size_t)G_GRAPHS * 2 * H;
    float* partS  = fws + off; off += (size_t)G_GRAPHS * RSUB * H;
    float* partM  = fws + off; off += (size_t)G_GRAPHS * RSUB * H;
    float* partC  = fws + off; off += (size_t)G_GRAPHS * RSUB;
    int* counts   = (int*)(fws + off); off += G_GRAPHS;
    int* starts   = (int*)(fws + off); off += G_GRAPHS;
    int* kkarr    = (int*)(fws + off); off += G_GRAPHS;
    int* rowptr   = (int*)(fws + off); off += N_NODES + 1;
    int* indeg    = (int*)(fws + off); off += N_NODES;
    int* cursor   = (int*)(fws + off); off += N_NODES;
    int* bsum     = (int*)(fws + off); off += NBLK_SCAN;
    int* boff     = (int*)(fws + off); off += NBLK_SCAN;
    int* srcC     = (int*)(fws + off); off += N_EDGES;

    int nblkN  = (N_NODES + 255) / 256;
    int nblkE  = (N_EDGES + 255) / 256;

    // graph segment structure (batch is sorted -> boundary detect, no atomics)
    starts_kernel<<<nblkN, 256, 0, stream>>>(batch, starts, N_NODES);
    counts_kernel<<<1, 128, 0, stream>>>(starts, counts);

    // CSR build (dst-grouped), deterministic via per-node wave sort
    hipMemsetAsync(indeg, 0, N_NODES * sizeof(int), stream);
    hipMemsetAsync(cursor, 0, N_NODES * sizeof(int), stream);
    indeg_kernel<<<nblkE, 256, 0, stream>>>(dstp, indeg, N_EDGES);
    bsum_kernel<<<NBLK_SCAN, 256, 0, stream>>>(indeg, bsum, N_NODES);
    bscan_kernel<<<1, 256, 0, stream>>>(bsum, boff, NBLK_SCAN);
    rowptr_kernel<<<NBLK_SCAN, 256, 0, stream>>>(indeg, boff, rowptr, N_NODES);
    scatter_kernel<<<nblkE, 256, 0, stream>>>(src, dstp, rowptr, cursor, srcC, N_EDGES);
    wsort_kernel<<<(N_NODES + 3) / 4, 256, 0, stream>>>(rowptr, srcC, N_NODES);

    fill_kernel<<<nblkN, 256, 0, stream>>>(mA, 1.f, N_NODES);
    fill_kernel<<<nblkN, 256, 0, stream>>>(gfac, 1.f, N_NODES);
    hipMemsetAsync(rbuf, 0, G_GRAPHS * 2 * H * sizeof(float), stream);

    const float* hin = x;
    float* hout = hA;
    const float* mcur = mA;
    float* mnext = mB;

    for (int blk = 0; blk < 3; ++blk) {
        degnorm_kernel<<<nblkN, 256, 0, stream>>>(rowptr, srcC, mcur, norm, mnorm, N_NODES);
        gemm128_kernel<<<(N_NODES + 63) / 64, 256, 0, stream>>>(hin, Wb[blk], gfac, xw, N_NODES);
        agg_fused_kernel<<<(N_NODES + 7) / 8, 256, 0, stream>>>(xw, rowptr, srcC, mcur, norm,
                                                                mnorm, bbv[blk], Wsb[blk],
                                                                hout, xws, N_NODES);
        score_gather_kernel<<<nblkN, 256, 0, stream>>>(rowptr, srcC, xws, mcur, norm, mnorm,
                                                       bsb[blk], scorem, N_NODES);
        kk_kernel<<<G_GRAPHS, 256, 0, stream>>>(scorem, starts, counts, kkarr);
        rank_kernel<<<(N_NODES + 3) / 4, 256, 0, stream>>>(scorem, mcur, batch, starts, counts,
                                                           kkarr, mnext, gfac, N_NODES);
        readout_part_kernel<<<G_GRAPHS * RSUB, 128, 0, stream>>>(hout, mnext, gfac, starts,
                                                                 counts, partS, partM, partC);
        readout_comb_kernel<<<G_GRAPHS, 128, 0, stream>>>(partS, partM, partC, rbuf);
        hin = hout;
        hout = (hout == hA) ? hB : hA;
        const float* tm = mcur; mcur = mnext; mnext = (float*)tm;
    }

    mlp_kernel<<<G_GRAPHS, 128, 0, stream>>>(rbuf, Wl1, bl1, Wl2, bl2, Wl3, bl3, out);
}

// Round 16
// 476.344 us; speedup vs baseline: 3.3402x; 1.0043x over previous
//
#include <hip/hip_runtime.h>
#include <math.h>

#define N_NODES 50000
#define N_EDGES 600000
#define H 128
#define G_GRAPHS 100
#define C_CLS 10
#define NBLK_SCAN ((N_NODES + 255) / 256)
#define RSUB 16

// ---------------- graph segment structure (batch sorted -> boundary detect) ----------------

__global__ void fill_kernel(float* __restrict__ p, float v, int n) {
    int i = blockIdx.x * 256 + threadIdx.x;
    if (i < n) p[i] = v;
}

// starts[g] = first index i with batch[i] == g (or next segment start if empty)
__global__ void starts_kernel(const int* __restrict__ batch, int* __restrict__ starts, int n) {
    int i = blockIdx.x * 256 + threadIdx.x;
    if (i >= n) return;
    int b = batch[i];
    int prev = (i == 0) ? -1 : batch[i - 1];
    for (int g = prev + 1; g <= b; ++g) starts[g] = i;
    if (i == n - 1) {
        for (int g = b + 1; g < G_GRAPHS; ++g) starts[g] = n;
    }
}

__global__ void counts_kernel(const int* __restrict__ starts, int* __restrict__ counts) {
    int g = threadIdx.x;
    if (g < G_GRAPHS) {
        int e = (g == G_GRAPHS - 1) ? N_NODES : starts[g + 1];
        counts[g] = e - starts[g];
    }
}

// ---------------- CSR build (dst-grouped, deterministic) ----------------

__global__ void indeg_kernel(const int* __restrict__ dst, int* __restrict__ indeg, int ne) {
    int e = blockIdx.x * 256 + threadIdx.x;
    if (e < ne) atomicAdd(&indeg[dst[e]], 1);
}

// ---- 3-phase multi-block exclusive scan of indeg -> rowptr ----

__global__ void bsum_kernel(const int* __restrict__ indeg, int* __restrict__ bsum, int n) {
    __shared__ int red[256];
    int i = blockIdx.x * 256 + threadIdx.x;
    red[threadIdx.x] = (i < n) ? indeg[i] : 0;
    __syncthreads();
    for (int o = 128; o > 0; o >>= 1) {
        if (threadIdx.x < o) red[threadIdx.x] += red[threadIdx.x + o];
        __syncthreads();
    }
    if (threadIdx.x == 0) bsum[blockIdx.x] = red[0];
}

__global__ void bscan_kernel(const int* __restrict__ bsum, int* __restrict__ boff, int nb) {
    __shared__ int s[256];
    int t = threadIdx.x;
    s[t] = (t < nb) ? bsum[t] : 0;
    __syncthreads();
    for (int o = 1; o < 256; o <<= 1) {
        int v = (t >= o) ? s[t - o] : 0;
        __syncthreads();
        s[t] += v;
        __syncthreads();
    }
    if (t < nb) boff[t] = (t == 0) ? 0 : s[t - 1];
}

__global__ void rowptr_kernel(const int* __restrict__ indeg, const int* __restrict__ boff,
                              int* __restrict__ rowptr, int n) {
    __shared__ int s[256];
    int i = blockIdx.x * 256 + threadIdx.x;
    int t = threadIdx.x;
    int v = (i < n) ? indeg[i] : 0;
    s[t] = v;
    __syncthreads();
    for (int o = 1; o < 256; o <<= 1) {
        int u = (t >= o) ? s[t - o] : 0;
        __syncthreads();
        s[t] += u;
        __syncthreads();
    }
    int incl = s[t];
    int excl = incl - v;
    if (i < n) rowptr[i] = boff[blockIdx.x] + excl;
    if (i == n - 1) rowptr[n] = boff[blockIdx.x] + incl;
}

__global__ void scatter_kernel(const int* __restrict__ src, const int* __restrict__ dst,
                               const int* __restrict__ rowptr, int* __restrict__ cursor,
                               int* __restrict__ srcC, int ne) {
    int e = blockIdx.x * 256 + threadIdx.x;
    if (e >= ne) return;
    int d = dst[e];
    int pos = rowptr[d] + atomicAdd(&cursor[d], 1);
    srcC[pos] = src[e];
}

// ---------------- wave-per-node odd-even sort (canonical ascending; deterministic) ----------

__global__ __launch_bounds__(256) void wsort_kernel(const int* __restrict__ rowptr,
                                                    int* __restrict__ srcC, int n) {
    int node = blockIdx.x * 4 + (threadIdx.x >> 6);
    if (node >= n) return;
    int lane = threadIdx.x & 63;
    int e0 = rowptr[node], e1 = rowptr[node + 1];
    int len = e1 - e0;
    if (len <= 1) return;
    if (len <= 64) {
        int key = (lane < len) ? srcC[e0 + lane] : 0x7fffffff;
        for (int p = 0; p < len; ++p) {
            int partner = ((lane ^ p) & 1) ? lane - 1 : lane + 1;
            int pv = __shfl(key, partner & 63, 64);
            if (partner >= 0 && partner < 64) {
                key = (partner > lane) ? min(key, pv) : max(key, pv);
            }
        }
        if (lane < len) srcC[e0 + lane] = key;
    } else {
        if (lane == 0) {
            for (int i = e0 + 1; i < e1; ++i) {
                int k = srcC[i];
                int j = i - 1;
                while (j >= e0 && srcC[j] > k) { srcC[j + 1] = srcC[j]; --j; }
                srcC[j + 1] = k;
            }
        }
    }
}

// ---------------- degree / norm (gather) + premultiplied mask*norm ----------------

__global__ void degnorm_kernel(const int* __restrict__ rowptr, const int* __restrict__ srcC,
                               const float* __restrict__ mask, float* __restrict__ norm,
                               float* __restrict__ mnorm, int n) {
    int d = blockIdx.x * 256 + threadIdx.x;
    if (d >= n) return;
    float md = mask[d];
    float s = 0.f;
    if (md != 0.f) {
        int e0 = rowptr[d], e1 = rowptr[d + 1];
        for (int e = e0; e < e1; ++e) s += mask[srcC[e]];
    }
    float nd = rsqrtf(1.f + md * s);
    norm[d] = nd;
    mnorm[d] = md * nd;
}

// ---------------- GEMM: out[n][128] = (gfac[n] * A[n][128]) @ W[128][128] ----------------

__global__ __launch_bounds__(256) void gemm128_kernel(const float* __restrict__ A,
                                                      const float* __restrict__ W,
                                                      const float* __restrict__ gf,
                                                      float* __restrict__ out, int nrows) {
    __shared__ float sT[128][68];
    int row0 = blockIdx.x * 64;
    int tid = threadIdx.x;
    for (int i = tid; i < 2048; i += 256) {
        int r = i >> 5, c4 = i & 31;
        int row = row0 + r;
        float4 v = make_float4(0.f, 0.f, 0.f, 0.f);
        if (row < nrows) {
            float g = gf[row];
            v = ((const float4*)(A + (size_t)row * H))[c4];
            v.x *= g; v.y *= g; v.z *= g; v.w *= g;
        }
        sT[c4 * 4 + 0][r] = v.x; sT[c4 * 4 + 1][r] = v.y;
        sT[c4 * 4 + 2][r] = v.z; sT[c4 * 4 + 3][r] = v.w;
    }
    __syncthreads();
    int cg = tid & 31;
    int rg = tid >> 5;
    float acc[8][4];
#pragma unroll
    for (int i = 0; i < 8; ++i)
#pragma unroll
        for (int j = 0; j < 4; ++j) acc[i][j] = 0.f;

    for (int k = 0; k < 128; ++k) {
        float4 w4 = ((const float4*)(W + k * H))[cg];
        const float4* pa = (const float4*)(&sT[k][rg * 8]);
        float4 a0 = pa[0], a1 = pa[1];
        float av[8] = {a0.x, a0.y, a0.z, a0.w, a1.x, a1.y, a1.z, a1.w};
#pragma unroll
        for (int i = 0; i < 8; ++i) {
            acc[i][0] = fmaf(av[i], w4.x, acc[i][0]);
            acc[i][1] = fmaf(av[i], w4.y, acc[i][1]);
            acc[i][2] = fmaf(av[i], w4.z, acc[i][2]);
            acc[i][3] = fmaf(av[i], w4.w, acc[i][3]);
        }
    }
#pragma unroll
    for (int i = 0; i < 8; ++i) {
        int row = row0 + rg * 8 + i;
        if (row < nrows) {
            float4 o = make_float4(acc[i][0], acc[i][1], acc[i][2], acc[i][3]);
            ((float4*)(out + (size_t)row * H))[cg] = o;
        }
    }
}

// ---------------- fused gather agg + self + bias + relu + score-dot ----------------
// XCD-aware bijective block swizzle: XCD k gets a contiguous chunk of nodes so
// its private L2 caches that chunk's xw rows (gathers are intra-graph-local).

__global__ __launch_bounds__(256) void agg_fused_kernel(const float* __restrict__ xw,
        const int* __restrict__ rowptr, const int* __restrict__ srcC,
        const float* __restrict__ mask, const float* __restrict__ norm,
        const float* __restrict__ mnorm,
        const float* __restrict__ b, const float* __restrict__ Ws,
        float* __restrict__ hout, float* __restrict__ xws, int n) {
    // bijective XCD swizzle (m204): orig bid -> contiguous chunk per XCD
    int bid = blockIdx.x;
    int nwg = gridDim.x;
    int xcd = bid & 7;
    int q = nwg >> 3, rr = nwg & 7;
    int swz = (xcd < rr ? xcd * (q + 1) : rr * (q + 1) + (xcd - rr) * q) + (bid >> 3);
    int node = swz * 8 + (threadIdx.x >> 5);
    if (node >= n) return;
    int t = threadIdx.x & 31;
    const float4* xw4 = (const float4*)xw;
    float md = mask[node];
    float nd = norm[node];
    float4 a0 = make_float4(0.f, 0.f, 0.f, 0.f);
    float4 a1 = a0, a2 = a0, a3 = a0;
    if (md != 0.f) {
        int e0 = rowptr[node], e1 = rowptr[node + 1];
        int e = e0;
        for (; e + 3 < e1; e += 4) {
            int s0 = srcC[e], s1 = srcC[e + 1], s2 = srcC[e + 2], s3 = srcC[e + 3];
            float c0 = mnorm[s0];
            float c1 = mnorm[s1];
            float c2 = mnorm[s2];
            float c3 = mnorm[s3];
            float4 v0 = xw4[(size_t)s0 * 32 + t];
            float4 v1 = xw4[(size_t)s1 * 32 + t];
            float4 v2 = xw4[(size_t)s2 * 32 + t];
            float4 v3 = xw4[(size_t)s3 * 32 + t];
            a0.x = fmaf(v0.x, c0, a0.x); a0.y = fmaf(v0.y, c0, a0.y);
            a0.z = fmaf(v0.z, c0, a0.z); a0.w = fmaf(v0.w, c0, a0.w);
            a1.x = fmaf(v1.x, c1, a1.x); a1.y = fmaf(v1.y, c1, a1.y);
            a1.z = fmaf(v1.z, c1, a1.z); a1.w = fmaf(v1.w, c1, a1.w);
            a2.x = fmaf(v2.x, c2, a2.x); a2.y = fmaf(v2.y, c2, a2.y);
            a2.z = fmaf(v2.z, c2, a2.z); a2.w = fmaf(v2.w, c2, a2.w);
            a3.x = fmaf(v3.x, c3, a3.x); a3.y = fmaf(v3.y, c3, a3.y);
            a3.z = fmaf(v3.z, c3, a3.z); a3.w = fmaf(v3.w, c3, a3.w);
        }
        for (; e < e1; ++e) {
            int s = srcC[e];
            float c = mnorm[s];
            float4 v = xw4[(size_t)s * 32 + t];
            a0.x = fmaf(v.x, c, a0.x); a0.y = fmaf(v.y, c, a0.y);
            a0.z = fmaf(v.z, c, a0.z); a0.w = fmaf(v.w, c, a0.w);
        }
        float sc = md * nd;
        a0.x = (((a0.x + a1.x) + a2.x) + a3.x) * sc;
        a0.y = (((a0.y + a1.y) + a2.y) + a3.y) * sc;
        a0.z = (((a0.z + a1.z) + a2.z) + a3.z) * sc;
        a0.w = (((a0.w + a1.w) + a2.w) + a3.w) * sc;
    }
    float4 self = xw4[(size_t)node * 32 + t];
    float4 bb = ((const float4*)b)[t];
    float n2 = nd * nd;
    float4 v;
    v.x = fmaxf(fmaf(self.x, n2, a0.x) + bb.x, 0.f);
    v.y = fmaxf(fmaf(self.y, n2, a0.y) + bb.y, 0.f);
    v.z = fmaxf(fmaf(self.z, n2, a0.z) + bb.z, 0.f);
    v.w = fmaxf(fmaf(self.w, n2, a0.w) + bb.w, 0.f);
    ((float4*)hout)[(size_t)node * 32 + t] = v;
    // fused score projection: xws[node] = dot(hout_row, Ws)
    float4 w = ((const float4*)Ws)[t];
    float p = ((v.x * w.x + v.y * w.y) + v.z * w.z) + v.w * w.w;
#pragma unroll
    for (int o = 16; o > 0; o >>= 1) p += __shfl_down(p, o, 32);
    if (t == 0) xws[node] = p;
}

// ---------------- score gather -> masked score (scorem = active ? score : -inf) ----------------

__global__ void score_gather_kernel(const int* __restrict__ rowptr, const int* __restrict__ srcC,
        const float* __restrict__ xws, const float* __restrict__ mask,
        const float* __restrict__ norm, const float* __restrict__ mnorm,
        const float* __restrict__ bs, float* __restrict__ scorem, int n) {
    int d = blockIdx.x * 256 + threadIdx.x;
    if (d >= n) return;
    float md = mask[d];
    float nd = norm[d];
    float out;
    if (md != 0.f) {
        float acc = 0.f;
        int e0 = rowptr[d], e1 = rowptr[d + 1];
        for (int e = e0; e < e1; ++e) {
            int s = srcC[e];
            acc = fmaf(xws[s], mnorm[s], acc);
        }
        acc *= md * nd;
        out = acc + xws[d] * nd * nd + bs[0];
    } else {
        out = -INFINITY;
    }
    scorem[d] = out;
}

// ---------------- per-graph k (ceil(0.5 * active)) ----------------

__global__ __launch_bounds__(256) void kk_kernel(const float* __restrict__ scorem,
        const int* __restrict__ starts, const int* __restrict__ counts,
        int* __restrict__ kkarr) {
    int g = blockIdx.x;
    int s0 = starts[g], cnt = counts[g];
    __shared__ int red[256];
    int c = 0;
    for (int i = threadIdx.x; i < cnt; i += 256)
        if (scorem[s0 + i] != -INFINITY) ++c;
    red[threadIdx.x] = c;
    __syncthreads();
    for (int o = 128; o > 0; o >>= 1) {
        if (threadIdx.x < o) red[threadIdx.x] += red[threadIdx.x + o];
        __syncthreads();
    }
    if (threadIdx.x == 0) kkarr[g] = (int)ceilf(0.5f * (float)red[0]);
}

// ---------------- rank-based top-k: one 64-lane wave per node ----------------

__global__ __launch_bounds__(256) void rank_kernel(const float* __restrict__ scorem,
        const float* __restrict__ mask, const int* __restrict__ batch,
        const int* __restrict__ starts, const int* __restrict__ counts,
        const int* __restrict__ kkarr,
        float* __restrict__ nmask, float* __restrict__ gfac, int n) {
    int i = blockIdx.x * 4 + (threadIdx.x >> 6);
    if (i >= n) return;
    int lane = threadIdx.x & 63;
    float sci = scorem[i];
    if (sci == -INFINITY) {
        if (lane == 0) { nmask[i] = 0.f; gfac[i] = 0.f; }
        return;
    }
    int g = batch[i];
    int s0 = starts[g], cnt = counts[g];
    int r = 0;
    for (int j = lane; j < cnt; j += 64) {
        float sj = scorem[s0 + j];
        if (sj > sci || (sj == sci && (s0 + j) < i)) ++r;
    }
#pragma unroll
    for (int o = 32; o > 0; o >>= 1) r += __shfl_down(r, o);
    if (lane == 0) {
        bool keep = (r < kkarr[g]);
        float m = mask[i];
        nmask[i] = keep ? m : 0.f;
        gfac[i] = keep ? tanhf(sci) * m : 0.f;
    }
}

// ---------------- readout phase 1: per-(graph, sub-slice) partials ----------------

__global__ __launch_bounds__(128) void readout_part_kernel(const float* __restrict__ h,
        const float* __restrict__ mask, const float* __restrict__ gfac,
        const int* __restrict__ starts, const int* __restrict__ counts,
        float* __restrict__ partS, float* __restrict__ partM, float* __restrict__ partC) {
    int g = blockIdx.x >> 4;
    int sub = blockIdx.x & (RSUB - 1);
    int f = threadIdx.x;
    int s0 = starts[g], cnt = counts[g];
    float s = 0.f, mx = -INFINITY, c = 0.f;
    for (int i = sub; i < cnt; i += RSUB) {
        float m = mask[s0 + i];
        if (m > 0.f) {
            float v = h[(size_t)(s0 + i) * H + f] * gfac[s0 + i];
            s += v; mx = fmaxf(mx, v); c += 1.f;
        }
    }
    size_t pidx = (size_t)blockIdx.x * H + f;
    partS[pidx] = s;
    partM[pidx] = mx;
    if (f == 0) partC[blockIdx.x] = c;
}

// ---------------- readout phase 2: combine partials in fixed order -> rbuf ----------------

__global__ __launch_bounds__(128) void readout_comb_kernel(const float* __restrict__ partS,
        const float* __restrict__ partM, const float* __restrict__ partC,
        float* __restrict__ r) {
    int g = blockIdx.x;
    int f = threadIdx.x;
    float S = 0.f, M = -INFINITY, C = 0.f;
    for (int sub = 0; sub < RSUB; ++sub) {
        size_t pidx = (size_t)(g * RSUB + sub) * H + f;
        S += partS[pidx];
        M = fmaxf(M, partM[pidx]);
        C += partC[g * RSUB + sub];
    }
    float mean = S / fmaxf(C, 1.f);
    if (C == 0.f) M = 0.f;
    r[(size_t)g * 2 * H + f] += M;
    r[(size_t)g * 2 * H + H + f] += mean;
}

// ---------------- MLP head + log_softmax ----------------

__global__ __launch_bounds__(128) void mlp_kernel(const float* __restrict__ r,
        const float* __restrict__ Wl1, const float* __restrict__ bl1,
        const float* __restrict__ Wl2, const float* __restrict__ bl2,
        const float* __restrict__ Wl3, const float* __restrict__ bl3,
        float* __restrict__ out) {
    int g = blockIdx.x;
    int t = threadIdx.x;
    __shared__ float sz[256];
    __shared__ float sy1[128];
    __shared__ float sy2[64];
    __shared__ float sy3[10];
    __shared__ float sred[2];
    sz[t] = r[g * 256 + t];
    sz[t + 128] = r[g * 256 + 128 + t];
    __syncthreads();
    float a = bl1[t];
    for (int k = 0; k < 256; ++k) a = fmaf(sz[k], Wl1[k * 128 + t], a);
    sy1[t] = fmaxf(a, 0.f);
    __syncthreads();
    if (t < 64) {
        float a2 = bl2[t];
        for (int k = 0; k < 128; ++k) a2 = fmaf(sy1[k], Wl2[k * 64 + t], a2);
        sy2[t] = fmaxf(a2, 0.f);
    }
    __syncthreads();
    if (t < 10) {
        float a3 = bl3[t];
        for (int k = 0; k < 64; ++k) a3 = fmaf(sy2[k], Wl3[k * 10 + t], a3);
        sy3[t] = a3;
    }
    __syncthreads();
    if (t == 0) {
        float m = sy3[0];
        for (int c2 = 1; c2 < 10; ++c2) m = fmaxf(m, sy3[c2]);
        float se = 0.f;
        for (int c2 = 0; c2 < 10; ++c2) se += expf(sy3[c2] - m);
        sred[0] = m; sred[1] = logf(se);
    }
    __syncthreads();
    if (t < 10) out[g * 10 + t] = sy3[t] - sred[0] - sred[1];
}

// ---------------- launch ----------------

extern "C" void kernel_launch(void* const* d_in, const int* in_sizes, int n_in,
                              void* d_out, int out_size, void* d_ws, size_t ws_size,
                              hipStream_t stream) {
    const float* x     = (const float*)d_in[0];
    const int*   ei    = (const int*)d_in[1];
    const int*   batch = (const int*)d_in[2];
    const int* src  = ei;
    const int* dstp = ei + N_EDGES;
    const float* Wb[3]  = {(const float*)d_in[3], (const float*)d_in[7],  (const float*)d_in[11]};
    const float* bbv[3] = {(const float*)d_in[4], (const float*)d_in[8],  (const float*)d_in[12]};
    const float* Wsb[3] = {(const float*)d_in[5], (const float*)d_in[9],  (const float*)d_in[13]};
    const float* bsb[3] = {(const float*)d_in[6], (const float*)d_in[10], (const float*)d_in[14]};
    const float* Wl1 = (const float*)d_in[15];
    const float* bl1 = (const float*)d_in[16];
    const float* Wl2 = (const float*)d_in[17];
    const float* bl2 = (const float*)d_in[18];
    const float* Wl3 = (const float*)d_in[19];
    const float* bl3 = (const float*)d_in[20];
    float* out = (float*)d_out;

    // workspace carve (4B units)
    float* fws = (float*)d_ws;
    size_t off = 0;
    float* hA     = fws + off; off += (size_t)N_NODES * H;
    float* hB     = fws + off; off += (size_t)N_NODES * H;
    float* xw     = fws + off; off += (size_t)N_NODES * H;
    float* scorem = fws + off; off += N_NODES;
    float* xws    = fws + off; off += N_NODES;
    float* norm   = fws + off; off += N_NODES;
    float* mnorm  = fws + off; off += N_NODES;
    float* mA     = fws + off; off += N_NODES;
    float* mB     = fws + off; off += N_NODES;
    float* gfac   = fws + off; off += N_NODES;
    float* rbuf   = fws + off; off += (size_t)G_GRAPHS * 2 * H;
    float* partS  = fws + off; off += (size_t)G_GRAPHS * RSUB * H;
    float* partM  = fws + off; off += (size_t)G_GRAPHS * RSUB * H;
    float* partC  = fws + off; off += (size_t)G_GRAPHS * RSUB;
    int* counts   = (int*)(fws + off); off += G_GRAPHS;
    int* starts   = (int*)(fws + off); off += G_GRAPHS;
    int* kkarr    = (int*)(fws + off); off += G_GRAPHS;
    int* rowptr   = (int*)(fws + off); off += N_NODES + 1;
    int* indeg    = (int*)(fws + off); off += N_NODES;
    int* cursor   = (int*)(fws + off); off += N_NODES;
    int* bsum     = (int*)(fws + off); off += NBLK_SCAN;
    int* boff     = (int*)(fws + off); off += NBLK_SCAN;
    int* srcC     = (int*)(fws + off); off += N_EDGES;

    int nblkN  = (N_NODES + 255) / 256;
    int nblkE  = (N_EDGES + 255) / 256;

    // graph segment structure (batch is sorted -> boundary detect, no atomics)
    starts_kernel<<<nblkN, 256, 0, stream>>>(batch, starts, N_NODES);
    counts_kernel<<<1, 128, 0, stream>>>(starts, counts);

    // CSR build (dst-grouped), deterministic via per-node wave sort
    hipMemsetAsync(indeg, 0, N_NODES * sizeof(int), stream);
    hipMemsetAsync(cursor, 0, N_NODES * sizeof(int), stream);
    indeg_kernel<<<nblkE, 256, 0, stream>>>(dstp, indeg, N_EDGES);
    bsum_kernel<<<NBLK_SCAN, 256, 0, stream>>>(indeg, bsum, N_NODES);
    bscan_kernel<<<1, 256, 0, stream>>>(bsum, boff, NBLK_SCAN);
    rowptr_kernel<<<NBLK_SCAN, 256, 0, stream>>>(indeg, boff, rowptr, N_NODES);
    scatter_kernel<<<nblkE, 256, 0, stream>>>(src, dstp, rowptr, cursor, srcC, N_EDGES);
    wsort_kernel<<<(N_NODES + 3) / 4, 256, 0, stream>>>(rowptr, srcC, N_NODES);

    fill_kernel<<<nblkN, 256, 0, stream>>>(mA, 1.f, N_NODES);
    fill_kernel<<<nblkN, 256, 0, stream>>>(gfac, 1.f, N_NODES);
    hipMemsetAsync(rbuf, 0, G_GRAPHS * 2 * H * sizeof(float), stream);

    const float* hin = x;
    float* hout = hA;
    const float* mcur = mA;
    float* mnext = mB;

    for (int blk = 0; blk < 3; ++blk) {
        degnorm_kernel<<<nblkN, 256, 0, stream>>>(rowptr, srcC, mcur, norm, mnorm, N_NODES);
        gemm128_kernel<<<(N_NODES + 63) / 64, 256, 0, stream>>>(hin, Wb[blk], gfac, xw, N_NODES);
        agg_fused_kernel<<<(N_NODES + 7) / 8, 256, 0, stream>>>(xw, rowptr, srcC, mcur, norm,
                                                                mnorm, bbv[blk], Wsb[blk],
                                                                hout, xws, N_NODES);
        score_gather_kernel<<<nblkN, 256, 0, stream>>>(rowptr, srcC, xws, mcur, norm, mnorm,
                                                       bsb[blk], scorem, N_NODES);
        kk_kernel<<<G_GRAPHS, 256, 0, stream>>>(scorem, starts, counts, kkarr);
        rank_kernel<<<(N_NODES + 3) / 4, 256, 0, stream>>>(scorem, mcur, batch, starts, counts,
                                                           kkarr, mnext, gfac, N_NODES);
        readout_part_kernel<<<G_GRAPHS * RSUB, 128, 0, stream>>>(hout, mnext, gfac, starts,
                                                                 counts, partS, partM, partC);
        readout_comb_kernel<<<G_GRAPHS, 128, 0, stream>>>(partS, partM, partC, rbuf);
        hin = hout;
        hout = (hout == hA) ? hB : hA;
        const float* tm = mcur; mcur = mnext; mnext = (float*)tm;
    }

    mlp_kernel<<<G_GRAPHS, 128, 0, stream>>>(rbuf, Wl1, bl1, Wl2, bl2, Wl3, bl3, out);
}

// Round 17
// 474.138 us; speedup vs baseline: 3.3558x; 1.0047x over previous
//
#include <hip/hip_runtime.h>
#include <math.h>

#define N_NODES 50000
#define N_EDGES 600000
#define H 128
#define G_GRAPHS 100
#define C_CLS 10
#define NBLK_SCAN ((N_NODES + 255) / 256)
#define RSUB 16

// ---------------- graph segment structure (batch sorted -> boundary detect) ----------------

__global__ void fill_kernel(float* __restrict__ p, float v, int n) {
    int i = blockIdx.x * 256 + threadIdx.x;
    if (i < n) p[i] = v;
}

__global__ void starts_kernel(const int* __restrict__ batch, int* __restrict__ starts, int n) {
    int i = blockIdx.x * 256 + threadIdx.x;
    if (i >= n) return;
    int b = batch[i];
    int prev = (i == 0) ? -1 : batch[i - 1];
    for (int g = prev + 1; g <= b; ++g) starts[g] = i;
    if (i == n - 1) {
        for (int g = b + 1; g < G_GRAPHS; ++g) starts[g] = n;
    }
}

__global__ void counts_kernel(const int* __restrict__ starts, int* __restrict__ counts) {
    int g = threadIdx.x;
    if (g < G_GRAPHS) {
        int e = (g == G_GRAPHS - 1) ? N_NODES : starts[g + 1];
        counts[g] = e - starts[g];
    }
}

// ---------------- CSR build (dst-grouped, deterministic) ----------------

__global__ void indeg_kernel(const int* __restrict__ dst, int* __restrict__ indeg, int ne) {
    int e = blockIdx.x * 256 + threadIdx.x;
    if (e < ne) atomicAdd(&indeg[dst[e]], 1);
}

__global__ void bsum_kernel(const int* __restrict__ indeg, int* __restrict__ bsum, int n) {
    __shared__ int red[256];
    int i = blockIdx.x * 256 + threadIdx.x;
    red[threadIdx.x] = (i < n) ? indeg[i] : 0;
    __syncthreads();
    for (int o = 128; o > 0; o >>= 1) {
        if (threadIdx.x < o) red[threadIdx.x] += red[threadIdx.x + o];
        __syncthreads();
    }
    if (threadIdx.x == 0) bsum[blockIdx.x] = red[0];
}

__global__ void bscan_kernel(const int* __restrict__ bsum, int* __restrict__ boff, int nb) {
    __shared__ int s[256];
    int t = threadIdx.x;
    s[t] = (t < nb) ? bsum[t] : 0;
    __syncthreads();
    for (int o = 1; o < 256; o <<= 1) {
        int v = (t >= o) ? s[t - o] : 0;
        __syncthreads();
        s[t] += v;
        __syncthreads();
    }
    if (t < nb) boff[t] = (t == 0) ? 0 : s[t - 1];
}

__global__ void rowptr_kernel(const int* __restrict__ indeg, const int* __restrict__ boff,
                              int* __restrict__ rowptr, int n) {
    __shared__ int s[256];
    int i = blockIdx.x * 256 + threadIdx.x;
    int t = threadIdx.x;
    int v = (i < n) ? indeg[i] : 0;
    s[t] = v;
    __syncthreads();
    for (int o = 1; o < 256; o <<= 1) {
        int u = (t >= o) ? s[t - o] : 0;
        __syncthreads();
        s[t] += u;
        __syncthreads();
    }
    int incl = s[t];
    int excl = incl - v;
    if (i < n) rowptr[i] = boff[blockIdx.x] + excl;
    if (i == n - 1) rowptr[n] = boff[blockIdx.x] + incl;
}

__global__ void scatter_kernel(const int* __restrict__ src, const int* __restrict__ dst,
                               const int* __restrict__ rowptr, int* __restrict__ cursor,
                               int* __restrict__ srcC, int ne) {
    int e = blockIdx.x * 256 + threadIdx.x;
    if (e >= ne) return;
    int d = dst[e];
    int pos = rowptr[d] + atomicAdd(&cursor[d], 1);
    srcC[pos] = src[e];
}

// ---------------- wave-per-node odd-even sort (canonical ascending; deterministic) ----------

__global__ __launch_bounds__(256) void wsort_kernel(const int* __restrict__ rowptr,
                                                    int* __restrict__ srcC, int n) {
    int node = blockIdx.x * 4 + (threadIdx.x >> 6);
    if (node >= n) return;
    int lane = threadIdx.x & 63;
    int e0 = rowptr[node], e1 = rowptr[node + 1];
    int len = e1 - e0;
    if (len <= 1) return;
    if (len <= 64) {
        int key = (lane < len) ? srcC[e0 + lane] : 0x7fffffff;
        for (int p = 0; p < len; ++p) {
            int partner = ((lane ^ p) & 1) ? lane - 1 : lane + 1;
            int pv = __shfl(key, partner & 63, 64);
            if (partner >= 0 && partner < 64) {
                key = (partner > lane) ? min(key, pv) : max(key, pv);
            }
        }
        if (lane < len) srcC[e0 + lane] = key;
    } else {
        if (lane == 0) {
            for (int i = e0 + 1; i < e1; ++i) {
                int k = srcC[i];
                int j = i - 1;
                while (j >= e0 && srcC[j] > k) { srcC[j + 1] = srcC[j]; --j; }
                srcC[j + 1] = k;
            }
        }
    }
}

// ---------------- degree / norm: 8 lanes per node (parallel gather) ----------------

__global__ void degnorm_kernel(const int* __restrict__ rowptr, const int* __restrict__ srcC,
                               const float* __restrict__ mask, float* __restrict__ norm,
                               float* __restrict__ mnorm, int n) {
    int idx = blockIdx.x * 256 + threadIdx.x;
    int d = idx >> 3;
    if (d >= n) return;
    int l = idx & 7;
    float md = mask[d];
    float s = 0.f;
    if (md != 0.f) {
        int e0 = rowptr[d], e1 = rowptr[d + 1];
        for (int e = e0 + l; e < e1; e += 8) s += mask[srcC[e]];
    }
#pragma unroll
    for (int o = 4; o > 0; o >>= 1) s += __shfl_down(s, o, 8);
    if (l == 0) {
        float nd = rsqrtf(1.f + md * s);
        norm[d] = nd;
        mnorm[d] = md * nd;
    }
}

// ---------------- GEMM: out[n][128] = (gfac[n] * A[n][128]) @ W[128][128] ----------------

__global__ __launch_bounds__(256) void gemm128_kernel(const float* __restrict__ A,
                                                      const float* __restrict__ W,
                                                      const float* __restrict__ gf,
                                                      float* __restrict__ out, int nrows) {
    __shared__ float sT[128][68];
    int row0 = blockIdx.x * 64;
    int tid = threadIdx.x;
    for (int i = tid; i < 2048; i += 256) {
        int r = i >> 5, c4 = i & 31;
        int row = row0 + r;
        float4 v = make_float4(0.f, 0.f, 0.f, 0.f);
        if (row < nrows) {
            float g = gf[row];
            v = ((const float4*)(A + (size_t)row * H))[c4];
            v.x *= g; v.y *= g; v.z *= g; v.w *= g;
        }
        sT[c4 * 4 + 0][r] = v.x; sT[c4 * 4 + 1][r] = v.y;
        sT[c4 * 4 + 2][r] = v.z; sT[c4 * 4 + 3][r] = v.w;
    }
    __syncthreads();
    int cg = tid & 31;
    int rg = tid >> 5;
    float acc[8][4];
#pragma unroll
    for (int i = 0; i < 8; ++i)
#pragma unroll
        for (int j = 0; j < 4; ++j) acc[i][j] = 0.f;

#pragma unroll 4
    for (int k = 0; k < 128; ++k) {
        float4 w4 = ((const float4*)(W + k * H))[cg];
        const float4* pa = (const float4*)(&sT[k][rg * 8]);
        float4 a0 = pa[0], a1 = pa[1];
        float av[8] = {a0.x, a0.y, a0.z, a0.w, a1.x, a1.y, a1.z, a1.w};
#pragma unroll
        for (int i = 0; i < 8; ++i) {
            acc[i][0] = fmaf(av[i], w4.x, acc[i][0]);
            acc[i][1] = fmaf(av[i], w4.y, acc[i][1]);
            acc[i][2] = fmaf(av[i], w4.z, acc[i][2]);
            acc[i][3] = fmaf(av[i], w4.w, acc[i][3]);
        }
    }
#pragma unroll
    for (int i = 0; i < 8; ++i) {
        int row = row0 + rg * 8 + i;
        if (row < nrows) {
            float4 o = make_float4(acc[i][0], acc[i][1], acc[i][2], acc[i][3]);
            ((float4*)(out + (size_t)row * H))[cg] = o;
        }
    }
}

// ---------------- fused gather agg + self + bias + relu + score-dot ----------------
// 8 nodes per 256-block, 32 threads/node, float4/thread, 8-edge unroll (8 chains in flight).

__global__ __launch_bounds__(256) void agg_fused_kernel(const float* __restrict__ xw,
        const int* __restrict__ rowptr, const int* __restrict__ srcC,
        const float* __restrict__ mask, const float* __restrict__ norm,
        const float* __restrict__ mnorm,
        const float* __restrict__ b, const float* __restrict__ Ws,
        float* __restrict__ hout, float* __restrict__ xws, int n) {
    int node = blockIdx.x * 8 + (threadIdx.x >> 5);
    if (node >= n) return;
    int t = threadIdx.x & 31;
    const float4* xw4 = (const float4*)xw;
    float md = mask[node];
    float nd = norm[node];
    float4 a0 = make_float4(0.f, 0.f, 0.f, 0.f);
    float4 a1 = a0, a2 = a0, a3 = a0, a4 = a0, a5 = a0, a6 = a0, a7 = a0;
    if (md != 0.f) {
        int e0 = rowptr[node], e1 = rowptr[node + 1];
        int e = e0;
        for (; e + 7 < e1; e += 8) {
            int s0 = srcC[e], s1 = srcC[e + 1], s2 = srcC[e + 2], s3 = srcC[e + 3];
            int s4 = srcC[e + 4], s5 = srcC[e + 5], s6 = srcC[e + 6], s7 = srcC[e + 7];
            float c0 = mnorm[s0], c1 = mnorm[s1], c2 = mnorm[s2], c3 = mnorm[s3];
            float c4 = mnorm[s4], c5 = mnorm[s5], c6 = mnorm[s6], c7 = mnorm[s7];
            float4 v0 = xw4[(size_t)s0 * 32 + t];
            float4 v1 = xw4[(size_t)s1 * 32 + t];
            float4 v2 = xw4[(size_t)s2 * 32 + t];
            float4 v3 = xw4[(size_t)s3 * 32 + t];
            float4 v4 = xw4[(size_t)s4 * 32 + t];
            float4 v5 = xw4[(size_t)s5 * 32 + t];
            float4 v6 = xw4[(size_t)s6 * 32 + t];
            float4 v7 = xw4[(size_t)s7 * 32 + t];
            a0.x = fmaf(v0.x, c0, a0.x); a0.y = fmaf(v0.y, c0, a0.y);
            a0.z = fmaf(v0.z, c0, a0.z); a0.w = fmaf(v0.w, c0, a0.w);
            a1.x = fmaf(v1.x, c1, a1.x); a1.y = fmaf(v1.y, c1, a1.y);
            a1.z = fmaf(v1.z, c1, a1.z); a1.w = fmaf(v1.w, c1, a1.w);
            a2.x = fmaf(v2.x, c2, a2.x); a2.y = fmaf(v2.y, c2, a2.y);
            a2.z = fmaf(v2.z, c2, a2.z); a2.w = fmaf(v2.w, c2, a2.w);
            a3.x = fmaf(v3.x, c3, a3.x); a3.y = fmaf(v3.y, c3, a3.y);
            a3.z = fmaf(v3.z, c3, a3.z); a3.w = fmaf(v3.w, c3, a3.w);
            a4.x = fmaf(v4.x, c4, a4.x); a4.y = fmaf(v4.y, c4, a4.y);
            a4.z = fmaf(v4.z, c4, a4.z); a4.w = fmaf(v4.w, c4, a4.w);
            a5.x = fmaf(v5.x, c5, a5.x); a5.y = fmaf(v5.y, c5, a5.y);
            a5.z = fmaf(v5.z, c5, a5.z); a5.w = fmaf(v5.w, c5, a5.w);
            a6.x = fmaf(v6.x, c6, a6.x); a6.y = fmaf(v6.y, c6, a6.y);
            a6.z = fmaf(v6.z, c6, a6.z); a6.w = fmaf(v6.w, c6, a6.w);
            a7.x = fmaf(v7.x, c7, a7.x); a7.y = fmaf(v7.y, c7, a7.y);
            a7.z = fmaf(v7.z, c7, a7.z); a7.w = fmaf(v7.w, c7, a7.w);
        }
        for (; e < e1; ++e) {
            int s = srcC[e];
            float c = mnorm[s];
            float4 v = xw4[(size_t)s * 32 + t];
            a0.x = fmaf(v.x, c, a0.x); a0.y = fmaf(v.y, c, a0.y);
            a0.z = fmaf(v.z, c, a0.z); a0.w = fmaf(v.w, c, a0.w);
        }
        float sc = md * nd;
        a0.x = ((((a0.x + a1.x) + (a2.x + a3.x)) + ((a4.x + a5.x) + (a6.x + a7.x)))) * sc;
        a0.y = ((((a0.y + a1.y) + (a2.y + a3.y)) + ((a4.y + a5.y) + (a6.y + a7.y)))) * sc;
        a0.z = ((((a0.z + a1.z) + (a2.z + a3.z)) + ((a4.z + a5.z) + (a6.z + a7.z)))) * sc;
        a0.w = ((((a0.w + a1.w) + (a2.w + a3.w)) + ((a4.w + a5.w) + (a6.w + a7.w)))) * sc;
    }
    float4 self = xw4[(size_t)node * 32 + t];
    float4 bb = ((const float4*)b)[t];
    float n2 = nd * nd;
    float4 v;
    v.x = fmaxf(fmaf(self.x, n2, a0.x) + bb.x, 0.f);
    v.y = fmaxf(fmaf(self.y, n2, a0.y) + bb.y, 0.f);
    v.z = fmaxf(fmaf(self.z, n2, a0.z) + bb.z, 0.f);
    v.w = fmaxf(fmaf(self.w, n2, a0.w) + bb.w, 0.f);
    ((float4*)hout)[(size_t)node * 32 + t] = v;
    // fused score projection: xws[node] = dot(hout_row, Ws)
    float4 w = ((const float4*)Ws)[t];
    float p = ((v.x * w.x + v.y * w.y) + v.z * w.z) + v.w * w.w;
#pragma unroll
    for (int o = 16; o > 0; o >>= 1) p += __shfl_down(p, o, 32);
    if (t == 0) xws[node] = p;
}

// ---------------- score gather: 8 lanes per node -> masked score ----------------

__global__ void score_gather_kernel(const int* __restrict__ rowptr, const int* __restrict__ srcC,
        const float* __restrict__ xws, const float* __restrict__ mask,
        const float* __restrict__ norm, const float* __restrict__ mnorm,
        const float* __restrict__ bs, float* __restrict__ scorem, int n) {
    int idx = blockIdx.x * 256 + threadIdx.x;
    int d = idx >> 3;
    if (d >= n) return;
    int l = idx & 7;
    float md = mask[d];
    float nd = norm[d];
    float acc = 0.f;
    if (md != 0.f) {
        int e0 = rowptr[d], e1 = rowptr[d + 1];
        for (int e = e0 + l; e < e1; e += 8) {
            int s = srcC[e];
            acc = fmaf(xws[s], mnorm[s], acc);
        }
    }
#pragma unroll
    for (int o = 4; o > 0; o >>= 1) acc += __shfl_down(acc, o, 8);
    if (l == 0) {
        float out;
        if (md != 0.f) out = acc * (md * nd) + xws[d] * nd * nd + bs[0];
        else out = -INFINITY;
        scorem[d] = out;
    }
}

// ---------------- per-graph k (ceil(0.5 * active)) ----------------

__global__ __launch_bounds__(256) void kk_kernel(const float* __restrict__ scorem,
        const int* __restrict__ starts, const int* __restrict__ counts,
        int* __restrict__ kkarr) {
    int g = blockIdx.x;
    int s0 = starts[g], cnt = counts[g];
    __shared__ int red[256];
    int c = 0;
    for (int i = threadIdx.x; i < cnt; i += 256)
        if (scorem[s0 + i] != -INFINITY) ++c;
    red[threadIdx.x] = c;
    __syncthreads();
    for (int o = 128; o > 0; o >>= 1) {
        if (threadIdx.x < o) red[threadIdx.x] += red[threadIdx.x + o];
        __syncthreads();
    }
    if (threadIdx.x == 0) kkarr[g] = (int)ceilf(0.5f * (float)red[0]);
}

// ---------------- rank-based top-k: one 64-lane wave per node ----------------

__global__ __launch_bounds__(256) void rank_kernel(const float* __restrict__ scorem,
        const float* __restrict__ mask, const int* __restrict__ batch,
        const int* __restrict__ starts, const int* __restrict__ counts,
        const int* __restrict__ kkarr,
        float* __restrict__ nmask, float* __restrict__ gfac, int n) {
    int i = blockIdx.x * 4 + (threadIdx.x >> 6);
    if (i >= n) return;
    int lane = threadIdx.x & 63;
    float sci = scorem[i];
    if (sci == -INFINITY) {
        if (lane == 0) { nmask[i] = 0.f; gfac[i] = 0.f; }
        return;
    }
    int g = batch[i];
    int s0 = starts[g], cnt = counts[g];
    int r = 0;
    for (int j = lane; j < cnt; j += 64) {
        float sj = scorem[s0 + j];
        if (sj > sci || (sj == sci && (s0 + j) < i)) ++r;
    }
#pragma unroll
    for (int o = 32; o > 0; o >>= 1) r += __shfl_down(r, o);
    if (lane == 0) {
        bool keep = (r < kkarr[g]);
        float m = mask[i];
        nmask[i] = keep ? m : 0.f;
        gfac[i] = keep ? tanhf(sci) * m : 0.f;
    }
}

// ---------------- readout phase 1: per-(graph, sub-slice) partials ----------------

__global__ __launch_bounds__(128) void readout_part_kernel(const float* __restrict__ h,
        const float* __restrict__ mask, const float* __restrict__ gfac,
        const int* __restrict__ starts, const int* __restrict__ counts,
        float* __restrict__ partS, float* __restrict__ partM, float* __restrict__ partC) {
    int g = blockIdx.x >> 4;
    int sub = blockIdx.x & (RSUB - 1);
    int f = threadIdx.x;
    int s0 = starts[g], cnt = counts[g];
    float s = 0.f, mx = -INFINITY, c = 0.f;
    for (int i = sub; i < cnt; i += RSUB) {
        float m = mask[s0 + i];
        if (m > 0.f) {
            float v = h[(size_t)(s0 + i) * H + f] * gfac[s0 + i];
            s += v; mx = fmaxf(mx, v); c += 1.f;
        }
    }
    size_t pidx = (size_t)blockIdx.x * H + f;
    partS[pidx] = s;
    partM[pidx] = mx;
    if (f == 0) partC[blockIdx.x] = c;
}

// ---------------- readout phase 2: combine partials in fixed order -> rbuf ----------------

__global__ __launch_bounds__(128) void readout_comb_kernel(const float* __restrict__ partS,
        const float* __restrict__ partM, const float* __restrict__ partC,
        float* __restrict__ r) {
    int g = blockIdx.x;
    int f = threadIdx.x;
    float S = 0.f, M = -INFINITY, C = 0.f;
    for (int sub = 0; sub < RSUB; ++sub) {
        size_t pidx = (size_t)(g * RSUB + sub) * H + f;
        S += partS[pidx];
        M = fmaxf(M, partM[pidx]);
        C += partC[g * RSUB + sub];
    }
    float mean = S / fmaxf(C, 1.f);
    if (C == 0.f) M = 0.f;
    r[(size_t)g * 2 * H + f] += M;
    r[(size_t)g * 2 * H + H + f] += mean;
}

// ---------------- MLP head + log_softmax ----------------

__global__ __launch_bounds__(128) void mlp_kernel(const float* __restrict__ r,
        const float* __restrict__ Wl1, const float* __restrict__ bl1,
        const float* __restrict__ Wl2, const float* __restrict__ bl2,
        const float* __restrict__ Wl3, const float* __restrict__ bl3,
        float* __restrict__ out) {
    int g = blockIdx.x;
    int t = threadIdx.x;
    __shared__ float sz[256];
    __shared__ float sy1[128];
    __shared__ float sy2[64];
    __shared__ float sy3[10];
    __shared__ float sred[2];
    sz[t] = r[g * 256 + t];
    sz[t + 128] = r[g * 256 + 128 + t];
    __syncthreads();
    float a = bl1[t];
    for (int k = 0; k < 256; ++k) a = fmaf(sz[k], Wl1[k * 128 + t], a);
    sy1[t] = fmaxf(a, 0.f);
    __syncthreads();
    if (t < 64) {
        float a2 = bl2[t];
        for (int k = 0; k < 128; ++k) a2 = fmaf(sy1[k], Wl2[k * 64 + t], a2);
        sy2[t] = fmaxf(a2, 0.f);
    }
    __syncthreads();
    if (t < 10) {
        float a3 = bl3[t];
        for (int k = 0; k < 64; ++k) a3 = fmaf(sy2[k], Wl3[k * 10 + t], a3);
        sy3[t] = a3;
    }
    __syncthreads();
    if (t == 0) {
        float m = sy3[0];
        for (int c2 = 1; c2 < 10; ++c2) m = fmaxf(m, sy3[c2]);
        float se = 0.f;
        for (int c2 = 0; c2 < 10; ++c2) se += expf(sy3[c2] - m);
        sred[0] = m; sred[1] = logf(se);
    }
    __syncthreads();
    if (t < 10) out[g * 10 + t] = sy3[t] - sred[0] - sred[1];
}

// ---------------- launch ----------------

extern "C" void kernel_launch(void* const* d_in, const int* in_sizes, int n_in,
                              void* d_out, int out_size, void* d_ws, size_t ws_size,
                              hipStream_t stream) {
    const float* x     = (const float*)d_in[0];
    const int*   ei    = (const int*)d_in[1];
    const int*   batch = (const int*)d_in[2];
    const int* src  = ei;
    const int* dstp = ei + N_EDGES;
    const float* Wb[3]  = {(const float*)d_in[3], (const float*)d_in[7],  (const float*)d_in[11]};
    const float* bbv[3] = {(const float*)d_in[4], (const float*)d_in[8],  (const float*)d_in[12]};
    const float* Wsb[3] = {(const float*)d_in[5], (const float*)d_in[9],  (const float*)d_in[13]};
    const float* bsb[3] = {(const float*)d_in[6], (const float*)d_in[10], (const float*)d_in[14]};
    const float* Wl1 = (const float*)d_in[15];
    const float* bl1 = (const float*)d_in[16];
    const float* Wl2 = (const float*)d_in[17];
    const float* bl2 = (const float*)d_in[18];
    const float* Wl3 = (const float*)d_in[19];
    const float* bl3 = (const float*)d_in[20];
    float* out = (float*)d_out;

    // workspace carve (4B units)
    float* fws = (float*)d_ws;
    size_t off = 0;
    float* hA     = fws + off; off += (size_t)N_NODES * H;
    float* hB     = fws + off; off += (size_t)N_NODES * H;
    float* xw     = fws + off; off += (size_t)N_NODES * H;
    float* scorem = fws + off; off += N_NODES;
    float* xws    = fws + off; off += N_NODES;
    float* norm   = fws + off; off += N_NODES;
    float* mnorm  = fws + off; off += N_NODES;
    float* mA     = fws + off; off += N_NODES;
    float* mB     = fws + off; off += N_NODES;
    float* gfac   = fws + off; off += N_NODES;
    float* rbuf   = fws + off; off += (size_t)G_GRAPHS * 2 * H;
    float* partS  = fws + off; off += (size_t)G_GRAPHS * RSUB * H;
    float* partM  = fws + off; off += (size_t)G_GRAPHS * RSUB * H;
    float* partC  = fws + off; off += (size_t)G_GRAPHS * RSUB;
    int* counts   = (int*)(fws + off); off += G_GRAPHS;
    int* starts   = (int*)(fws + off); off += G_GRAPHS;
    int* kkarr    = (int*)(fws + off); off += G_GRAPHS;
    int* rowptr   = (int*)(fws + off); off += N_NODES + 1;
    int* indeg    = (int*)(fws + off); off += N_NODES;
    int* cursor   = (int*)(fws + off); off += N_NODES;
    int* bsum     = (int*)(fws + off); off += NBLK_SCAN;
    int* boff     = (int*)(fws + off); off += NBLK_SCAN;
    int* srcC     = (int*)(fws + off); off += N_EDGES;

    int nblkN  = (N_NODES + 255) / 256;
    int nblkN8 = (N_NODES * 8 + 255) / 256;
    int nblkE  = (N_EDGES + 255) / 256;

    // graph segment structure (batch is sorted -> boundary detect, no atomics)
    starts_kernel<<<nblkN, 256, 0, stream>>>(batch, starts, N_NODES);
    counts_kernel<<<1, 128, 0, stream>>>(starts, counts);

    // CSR build (dst-grouped), deterministic via per-node wave sort
    hipMemsetAsync(indeg, 0, N_NODES * sizeof(int), stream);
    hipMemsetAsync(cursor, 0, N_NODES * sizeof(int), stream);
    indeg_kernel<<<nblkE, 256, 0, stream>>>(dstp, indeg, N_EDGES);
    bsum_kernel<<<NBLK_SCAN, 256, 0, stream>>>(indeg, bsum, N_NODES);
    bscan_kernel<<<1, 256, 0, stream>>>(bsum, boff, NBLK_SCAN);
    rowptr_kernel<<<NBLK_SCAN, 256, 0, stream>>>(indeg, boff, rowptr, N_NODES);
    scatter_kernel<<<nblkE, 256, 0, stream>>>(src, dstp, rowptr, cursor, srcC, N_EDGES);
    wsort_kernel<<<(N_NODES + 3) / 4, 256, 0, stream>>>(rowptr, srcC, N_NODES);

    fill_kernel<<<nblkN, 256, 0, stream>>>(mA, 1.f, N_NODES);
    fill_kernel<<<nblkN, 256, 0, stream>>>(gfac, 1.f, N_NODES);
    hipMemsetAsync(rbuf, 0, G_GRAPHS * 2 * H * sizeof(float), stream);

    const float* hin = x;
    float* hout = hA;
    const float* mcur = mA;
    float* mnext = mB;

    for (int blk = 0; blk < 3; ++blk) {
        degnorm_kernel<<<nblkN8, 256, 0, stream>>>(rowptr, srcC, mcur, norm, mnorm, N_NODES);
        gemm128_kernel<<<(N_NODES + 63) / 64, 256, 0, stream>>>(hin, Wb[blk], gfac, xw, N_NODES);
        agg_fused_kernel<<<(N_NODES + 7) / 8, 256, 0, stream>>>(xw, rowptr, srcC, mcur, norm,
                                                                mnorm, bbv[blk], Wsb[blk],
                                                                hout, xws, N_NODES);
        score_gather_kernel<<<nblkN8, 256, 0, stream>>>(rowptr, srcC, xws, mcur, norm, mnorm,
                                                        bsb[blk], scorem, N_NODES);
        kk_kernel<<<G_GRAPHS, 256, 0, stream>>>(scorem, starts, counts, kkarr);
        rank_kernel<<<(N_NODES + 3) / 4, 256, 0, stream>>>(scorem, mcur, batch, starts, counts,
                                                           kkarr, mnext, gfac, N_NODES);
        readout_part_kernel<<<G_GRAPHS * RSUB, 128, 0, stream>>>(hout, mnext, gfac, starts,
                                                                 counts, partS, partM, partC);
        readout_comb_kernel<<<G_GRAPHS, 128, 0, stream>>>(partS, partM, partC, rbuf);
        hin = hout;
        hout = (hout == hA) ? hB : hA;
        const float* tm = mcur; mcur = mnext; mnext = (float*)tm;
    }

    mlp_kernel<<<G_GRAPHS, 128, 0, stream>>>(rbuf, Wl1, bl1, Wl2, bl2, Wl3, bl3, out);
}

// Round 19
// 458.750 us; speedup vs baseline: 3.4683x; 1.0335x over previous
//
#include <hip/hip_runtime.h>
#include <math.h>

#define N_NODES 50000
#define N_EDGES 600000
#define H 128
#define G_GRAPHS 100
#define C_CLS 10
#define NBLK_SCAN ((N_NODES + 255) / 256)
#define RSUB 16

// ---------------- graph segment structure (batch sorted -> boundary detect) ----------------

__global__ void fill_kernel(float* __restrict__ p, float v, int n) {
    int i = blockIdx.x * 256 + threadIdx.x;
    if (i < n) p[i] = v;
}

__global__ void starts_kernel(const int* __restrict__ batch, int* __restrict__ starts, int n) {
    int i = blockIdx.x * 256 + threadIdx.x;
    if (i >= n) return;
    int b = batch[i];
    int prev = (i == 0) ? -1 : batch[i - 1];
    for (int g = prev + 1; g <= b; ++g) starts[g] = i;
    if (i == n - 1) {
        for (int g = b + 1; g < G_GRAPHS; ++g) starts[g] = n;
    }
}

__global__ void counts_kernel(const int* __restrict__ starts, int* __restrict__ counts) {
    int g = threadIdx.x;
    if (g < G_GRAPHS) {
        int e = (g == G_GRAPHS - 1) ? N_NODES : starts[g + 1];
        counts[g] = e - starts[g];
    }
}

// ---------------- CSR build (dst-grouped, deterministic) ----------------

__global__ void indeg_kernel(const int* __restrict__ dst, int* __restrict__ indeg, int ne) {
    int e = blockIdx.x * 256 + threadIdx.x;
    if (e < ne) atomicAdd(&indeg[dst[e]], 1);
}

__global__ void bsum_kernel(const int* __restrict__ indeg, int* __restrict__ bsum, int n) {
    __shared__ int red[256];
    int i = blockIdx.x * 256 + threadIdx.x;
    red[threadIdx.x] = (i < n) ? indeg[i] : 0;
    __syncthreads();
    for (int o = 128; o > 0; o >>= 1) {
        if (threadIdx.x < o) red[threadIdx.x] += red[threadIdx.x + o];
        __syncthreads();
    }
    if (threadIdx.x == 0) bsum[blockIdx.x] = red[0];
}

__global__ void bscan_kernel(const int* __restrict__ bsum, int* __restrict__ boff, int nb) {
    __shared__ int s[256];
    int t = threadIdx.x;
    s[t] = (t < nb) ? bsum[t] : 0;
    __syncthreads();
    for (int o = 1; o < 256; o <<= 1) {
        int v = (t >= o) ? s[t - o] : 0;
        __syncthreads();
        s[t] += v;
        __syncthreads();
    }
    if (t < nb) boff[t] = (t == 0) ? 0 : s[t - 1];
}

__global__ void rowptr_kernel(const int* __restrict__ indeg, const int* __restrict__ boff,
                              int* __restrict__ rowptr, int n) {
    __shared__ int s[256];
    int i = blockIdx.x * 256 + threadIdx.x;
    int t = threadIdx.x;
    int v = (i < n) ? indeg[i] : 0;
    s[t] = v;
    __syncthreads();
    for (int o = 1; o < 256; o <<= 1) {
        int u = (t >= o) ? s[t - o] : 0;
        __syncthreads();
        s[t] += u;
        __syncthreads();
    }
    int incl = s[t];
    int excl = incl - v;
    if (i < n) rowptr[i] = boff[blockIdx.x] + excl;
    if (i == n - 1) rowptr[n] = boff[blockIdx.x] + incl;
}

__global__ void scatter_kernel(const int* __restrict__ src, const int* __restrict__ dst,
                               const int* __restrict__ rowptr, int* __restrict__ cursor,
                               int* __restrict__ srcC, int ne) {
    int e = blockIdx.x * 256 + threadIdx.x;
    if (e >= ne) return;
    int d = dst[e];
    int pos = rowptr[d] + atomicAdd(&cursor[d], 1);
    srcC[pos] = src[e];
}

// ---------------- wave-per-node odd-even sort (canonical ascending; deterministic) ----------

__global__ __launch_bounds__(256) void wsort_kernel(const int* __restrict__ rowptr,
                                                    int* __restrict__ srcC, int n) {
    int node = blockIdx.x * 4 + (threadIdx.x >> 6);
    if (node >= n) return;
    int lane = threadIdx.x & 63;
    int e0 = rowptr[node], e1 = rowptr[node + 1];
    int len = e1 - e0;
    if (len <= 1) return;
    if (len <= 64) {
        int key = (lane < len) ? srcC[e0 + lane] : 0x7fffffff;
        for (int p = 0; p < len; ++p) {
            int partner = ((lane ^ p) & 1) ? lane - 1 : lane + 1;
            int pv = __shfl(key, partner & 63, 64);
            if (partner >= 0 && partner < 64) {
                key = (partner > lane) ? min(key, pv) : max(key, pv);
            }
        }
        if (lane < len) srcC[e0 + lane] = key;
    } else {
        if (lane == 0) {
            for (int i = e0 + 1; i < e1; ++i) {
                int k = srcC[i];
                int j = i - 1;
                while (j >= e0 && srcC[j] > k) { srcC[j + 1] = srcC[j]; --j; }
                srcC[j + 1] = k;
            }
        }
    }
}

// ---------------- degree / norm: 8 lanes per node (parallel gather) ----------------

__global__ void degnorm_kernel(const int* __restrict__ rowptr, const int* __restrict__ srcC,
                               const float* __restrict__ mask, float* __restrict__ norm,
                               float* __restrict__ mnorm, int n) {
    int idx = blockIdx.x * 256 + threadIdx.x;
    int d = idx >> 3;
    if (d >= n) return;
    int l = idx & 7;
    float md = mask[d];
    float s = 0.f;
    if (md != 0.f) {
        int e0 = rowptr[d], e1 = rowptr[d + 1];
        for (int e = e0 + l; e < e1; e += 8) s += mask[srcC[e]];
    }
#pragma unroll
    for (int o = 4; o > 0; o >>= 1) s += __shfl_down(s, o, 8);
    if (l == 0) {
        float nd = rsqrtf(1.f + md * s);
        norm[d] = nd;
        mnorm[d] = md * nd;
    }
}

// ---------------- GEMM: out[n][128] = (gfac[n] * A[n][128]) @ W[128][128] ----------------

__global__ __launch_bounds__(256) void gemm128_kernel(const float* __restrict__ A,
                                                      const float* __restrict__ W,
                                                      const float* __restrict__ gf,
                                                      float* __restrict__ out, int nrows) {
    __shared__ float sT[128][68];
    int row0 = blockIdx.x * 64;
    int tid = threadIdx.x;
    for (int i = tid; i < 2048; i += 256) {
        int r = i >> 5, c4 = i & 31;
        int row = row0 + r;
        float4 v = make_float4(0.f, 0.f, 0.f, 0.f);
        if (row < nrows) {
            float g = gf[row];
            v = ((const float4*)(A + (size_t)row * H))[c4];
            v.x *= g; v.y *= g; v.z *= g; v.w *= g;
        }
        sT[c4 * 4 + 0][r] = v.x; sT[c4 * 4 + 1][r] = v.y;
        sT[c4 * 4 + 2][r] = v.z; sT[c4 * 4 + 3][r] = v.w;
    }
    __syncthreads();
    int cg = tid & 31;
    int rg = tid >> 5;
    float acc[8][4];
#pragma unroll
    for (int i = 0; i < 8; ++i)
#pragma unroll
        for (int j = 0; j < 4; ++j) acc[i][j] = 0.f;

#pragma unroll 4
    for (int k = 0; k < 128; ++k) {
        float4 w4 = ((const float4*)(W + k * H))[cg];
        const float4* pa = (const float4*)(&sT[k][rg * 8]);
        float4 a0 = pa[0], a1 = pa[1];
        float av[8] = {a0.x, a0.y, a0.z, a0.w, a1.x, a1.y, a1.z, a1.w};
#pragma unroll
        for (int i = 0; i < 8; ++i) {
            acc[i][0] = fmaf(av[i], w4.x, acc[i][0]);
            acc[i][1] = fmaf(av[i], w4.y, acc[i][1]);
            acc[i][2] = fmaf(av[i], w4.z, acc[i][2]);
            acc[i][3] = fmaf(av[i], w4.w, acc[i][3]);
        }
    }
#pragma unroll
    for (int i = 0; i < 8; ++i) {
        int row = row0 + rg * 8 + i;
        if (row < nrows) {
            float4 o = make_float4(acc[i][0], acc[i][1], acc[i][2], acc[i][3]);
            ((float4*)(out + (size_t)row * H))[cg] = o;
        }
    }
}

// ---------------- fused gather agg + self + bias + relu + score-dot ----------------
// 4 nodes per 256-block, 64 threads/node = 2 edge-slots x 32 feature-lanes.
// Per slot: 4 independent chains (stride-2 edges) -> half the serial depth of R15
// at the same VGPR budget; halves combined with one shfl_xor(32).

__global__ __launch_bounds__(256) void agg_fused_kernel(const float* __restrict__ xw,
        const int* __restrict__ rowptr, const int* __restrict__ srcC,
        const float* __restrict__ mask, const float* __restrict__ norm,
        const float* __restrict__ mnorm,
        const float* __restrict__ b, const float* __restrict__ Ws,
        float* __restrict__ hout, float* __restrict__ xws, int n) {
    int node = blockIdx.x * 4 + (threadIdx.x >> 6);
    if (node >= n) return;
    int t = threadIdx.x & 63;
    int fl = t & 31;        // feature float4 lane
    int es = t >> 5;        // edge slot (0 or 1)
    const float4* xw4 = (const float4*)xw;
    float md = mask[node];
    float nd = norm[node];
    float4 a0 = make_float4(0.f, 0.f, 0.f, 0.f);
    float4 a1 = a0, a2 = a0, a3 = a0;
    if (md != 0.f) {
        int e0 = rowptr[node], e1 = rowptr[node + 1];
        int e = e0 + es;
        // 4 chains per slot: edges e, e+2, e+4, e+6 (slot-interleaved)
        for (; e + 6 < e1; e += 8) {
            int s0 = srcC[e], s1 = srcC[e + 2], s2 = srcC[e + 4], s3 = srcC[e + 6];
            float c0 = mnorm[s0];
            float c1 = mnorm[s1];
            float c2 = mnorm[s2];
            float c3 = mnorm[s3];
            float4 v0 = xw4[(size_t)s0 * 32 + fl];
            float4 v1 = xw4[(size_t)s1 * 32 + fl];
            float4 v2 = xw4[(size_t)s2 * 32 + fl];
            float4 v3 = xw4[(size_t)s3 * 32 + fl];
            a0.x = fmaf(v0.x, c0, a0.x); a0.y = fmaf(v0.y, c0, a0.y);
            a0.z = fmaf(v0.z, c0, a0.z); a0.w = fmaf(v0.w, c0, a0.w);
            a1.x = fmaf(v1.x, c1, a1.x); a1.y = fmaf(v1.y, c1, a1.y);
            a1.z = fmaf(v1.z, c1, a1.z); a1.w = fmaf(v1.w, c1, a1.w);
            a2.x = fmaf(v2.x, c2, a2.x); a2.y = fmaf(v2.y, c2, a2.y);
            a2.z = fmaf(v2.z, c2, a2.z); a2.w = fmaf(v2.w, c2, a2.w);
            a3.x = fmaf(v3.x, c3, a3.x); a3.y = fmaf(v3.y, c3, a3.y);
            a3.z = fmaf(v3.z, c3, a3.z); a3.w = fmaf(v3.w, c3, a3.w);
        }
        for (; e < e1; e += 2) {
            int s = srcC[e];
            float c = mnorm[s];
            float4 v = xw4[(size_t)s * 32 + fl];
            a0.x = fmaf(v.x, c, a0.x); a0.y = fmaf(v.y, c, a0.y);
            a0.z = fmaf(v.z, c, a0.z); a0.w = fmaf(v.w, c, a0.w);
        }
        a0.x = ((a0.x + a1.x) + (a2.x + a3.x));
        a0.y = ((a0.y + a1.y) + (a2.y + a3.y));
        a0.z = ((a0.z + a1.z) + (a2.z + a3.z));
        a0.w = ((a0.w + a1.w) + (a2.w + a3.w));
        // combine the two edge slots (lane t <-> t^32 hold same feature slot)
        a0.x += __shfl_xor(a0.x, 32, 64);
        a0.y += __shfl_xor(a0.y, 32, 64);
        a0.z += __shfl_xor(a0.z, 32, 64);
        a0.w += __shfl_xor(a0.w, 32, 64);
        float sc = md * nd;
        a0.x *= sc; a0.y *= sc; a0.z *= sc; a0.w *= sc;
    }
    if (es != 0) return;   // lanes 32..63 done (their sums are merged into lanes 0..31)
    float4 self = xw4[(size_t)node * 32 + fl];
    float4 bb = ((const float4*)b)[fl];
    float n2 = nd * nd;
    float4 v;
    v.x = fmaxf(fmaf(self.x, n2, a0.x) + bb.x, 0.f);
    v.y = fmaxf(fmaf(self.y, n2, a0.y) + bb.y, 0.f);
    v.z = fmaxf(fmaf(self.z, n2, a0.z) + bb.z, 0.f);
    v.w = fmaxf(fmaf(self.w, n2, a0.w) + bb.w, 0.f);
    ((float4*)hout)[(size_t)node * 32 + fl] = v;
    // fused score projection: xws[node] = dot(hout_row, Ws)
    float4 w = ((const float4*)Ws)[fl];
    float p = ((v.x * w.x + v.y * w.y) + v.z * w.z) + v.w * w.w;
#pragma unroll
    for (int o = 16; o > 0; o >>= 1) p += __shfl_down(p, o, 32);
    if (fl == 0) xws[node] = p;
}

// ---------------- score gather: 8 lanes per node -> masked score ----------------

__global__ void score_gather_kernel(const int* __restrict__ rowptr, const int* __restrict__ srcC,
        const float* __restrict__ xws, const float* __restrict__ mask,
        const float* __restrict__ norm, const float* __restrict__ mnorm,
        const float* __restrict__ bs, float* __restrict__ scorem, int n) {
    int idx = blockIdx.x * 256 + threadIdx.x;
    int d = idx >> 3;
    if (d >= n) return;
    int l = idx & 7;
    float md = mask[d];
    float nd = norm[d];
    float acc = 0.f;
    if (md != 0.f) {
        int e0 = rowptr[d], e1 = rowptr[d + 1];
        for (int e = e0 + l; e < e1; e += 8) {
            int s = srcC[e];
            acc = fmaf(xws[s], mnorm[s], acc);
        }
    }
#pragma unroll
    for (int o = 4; o > 0; o >>= 1) acc += __shfl_down(acc, o, 8);
    if (l == 0) {
        float out;
        if (md != 0.f) out = acc * (md * nd) + xws[d] * nd * nd + bs[0];
        else out = -INFINITY;
        scorem[d] = out;
    }
}

// ---------------- per-graph k (ceil(0.5 * active)) ----------------

__global__ __launch_bounds__(256) void kk_kernel(const float* __restrict__ scorem,
        const int* __restrict__ starts, const int* __restrict__ counts,
        int* __restrict__ kkarr) {
    int g = blockIdx.x;
    int s0 = starts[g], cnt = counts[g];
    __shared__ int red[256];
    int c = 0;
    for (int i = threadIdx.x; i < cnt; i += 256)
        if (scorem[s0 + i] != -INFINITY) ++c;
    red[threadIdx.x] = c;
    __syncthreads();
    for (int o = 128; o > 0; o >>= 1) {
        if (threadIdx.x < o) red[threadIdx.x] += red[threadIdx.x + o];
        __syncthreads();
    }
    if (threadIdx.x == 0) kkarr[g] = (int)ceilf(0.5f * (float)red[0]);
}

// ---------------- rank-based top-k: one 64-lane wave per node ----------------

__global__ __launch_bounds__(256) void rank_kernel(const float* __restrict__ scorem,
        const float* __restrict__ mask, const int* __restrict__ batch,
        const int* __restrict__ starts, const int* __restrict__ counts,
        const int* __restrict__ kkarr,
        float* __restrict__ nmask, float* __restrict__ gfac, int n) {
    int i = blockIdx.x * 4 + (threadIdx.x >> 6);
    if (i >= n) return;
    int lane = threadIdx.x & 63;
    float sci = scorem[i];
    if (sci == -INFINITY) {
        if (lane == 0) { nmask[i] = 0.f; gfac[i] = 0.f; }
        return;
    }
    int g = batch[i];
    int s0 = starts[g], cnt = counts[g];
    int r = 0;
    for (int j = lane; j < cnt; j += 64) {
        float sj = scorem[s0 + j];
        if (sj > sci || (sj == sci && (s0 + j) < i)) ++r;
    }
#pragma unroll
    for (int o = 32; o > 0; o >>= 1) r += __shfl_down(r, o);
    if (lane == 0) {
        bool keep = (r < kkarr[g]);
        float m = mask[i];
        nmask[i] = keep ? m : 0.f;
        gfac[i] = keep ? tanhf(sci) * m : 0.f;
    }
}

// ---------------- readout phase 1: per-(graph, sub-slice) partials ----------------

__global__ __launch_bounds__(128) void readout_part_kernel(const float* __restrict__ h,
        const float* __restrict__ mask, const float* __restrict__ gfac,
        const int* __restrict__ starts, const int* __restrict__ counts,
        float* __restrict__ partS, float* __restrict__ partM, float* __restrict__ partC) {
    int g = blockIdx.x >> 4;
    int sub = blockIdx.x & (RSUB - 1);
    int f = threadIdx.x;
    int s0 = starts[g], cnt = counts[g];
    float s = 0.f, mx = -INFINITY, c = 0.f;
    for (int i = sub; i < cnt; i += RSUB) {
        float m = mask[s0 + i];
        if (m > 0.f) {
            float v = h[(size_t)(s0 + i) * H + f] * gfac[s0 + i];
            s += v; mx = fmaxf(mx, v); c += 1.f;
        }
    }
    size_t pidx = (size_t)blockIdx.x * H + f;
    partS[pidx] = s;
    partM[pidx] = mx;
    if (f == 0) partC[blockIdx.x] = c;
}

// ---------------- readout phase 2: combine partials in fixed order -> rbuf ----------------

__global__ __launch_bounds__(128) void readout_comb_kernel(const float* __restrict__ partS,
        const float* __restrict__ partM, const float* __restrict__ partC,
        float* __restrict__ r) {
    int g = blockIdx.x;
    int f = threadIdx.x;
    float S = 0.f, M = -INFINITY, C = 0.f;
    for (int sub = 0; sub < RSUB; ++sub) {
        size_t pidx = (size_t)(g * RSUB + sub) * H + f;
        S += partS[pidx];
        M = fmaxf(M, partM[pidx]);
        C += partC[g * RSUB + sub];
    }
    float mean = S / fmaxf(C, 1.f);
    if (C == 0.f) M = 0.f;
    r[(size_t)g * 2 * H + f] += M;
    r[(size_t)g * 2 * H + H + f] += mean;
}

// ---------------- MLP head + log_softmax ----------------

__global__ __launch_bounds__(128) void mlp_kernel(const float* __restrict__ r,
        const float* __restrict__ Wl1, const float* __restrict__ bl1,
        const float* __restrict__ Wl2, const float* __restrict__ bl2,
        const float* __restrict__ Wl3, const float* __restrict__ bl3,
        float* __restrict__ out) {
    int g = blockIdx.x;
    int t = threadIdx.x;
    __shared__ float sz[256];
    __shared__ float sy1[128];
    __shared__ float sy2[64];
    __shared__ float sy3[10];
    __shared__ float sred[2];
    sz[t] = r[g * 256 + t];
    sz[t + 128] = r[g * 256 + 128 + t];
    __syncthreads();
    float a = bl1[t];
    for (int k = 0; k < 256; ++k) a = fmaf(sz[k], Wl1[k * 128 + t], a);
    sy1[t] = fmaxf(a, 0.f);
    __syncthreads();
    if (t < 64) {
        float a2 = bl2[t];
        for (int k = 0; k < 128; ++k) a2 = fmaf(sy1[k], Wl2[k * 64 + t], a2);
        sy2[t] = fmaxf(a2, 0.f);
    }
    __syncthreads();
    if (t < 10) {
        float a3 = bl3[t];
        for (int k = 0; k < 64; ++k) a3 = fmaf(sy2[k], Wl3[k * 10 + t], a3);
        sy3[t] = a3;
    }
    __syncthreads();
    if (t == 0) {
        float m = sy3[0];
        for (int c2 = 1; c2 < 10; ++c2) m = fmaxf(m, sy3[c2]);
        float se = 0.f;
        for (int c2 = 0; c2 < 10; ++c2) se += expf(sy3[c2] - m);
        sred[0] = m; sred[1] = logf(se);
    }
    __syncthreads();
    if (t < 10) out[g * 10 + t] = sy3[t] - sred[0] - sred[1];
}

// ---------------- launch ----------------

extern "C" void kernel_launch(void* const* d_in, const int* in_sizes, int n_in,
                              void* d_out, int out_size, void* d_ws, size_t ws_size,
                              hipStream_t stream) {
    const float* x     = (const float*)d_in[0];
    const int*   ei    = (const int*)d_in[1];
    const int*   batch = (const int*)d_in[2];
    const int* src  = ei;
    const int* dstp = ei + N_EDGES;
    const float* Wb[3]  = {(const float*)d_in[3], (const float*)d_in[7],  (const float*)d_in[11]};
    const float* bbv[3] = {(const float*)d_in[4], (const float*)d_in[8],  (const float*)d_in[12]};
    const float* Wsb[3] = {(const float*)d_in[5], (const float*)d_in[9],  (const float*)d_in[13]};
    const float* bsb[3] = {(const float*)d_in[6], (const float*)d_in[10], (const float*)d_in[14]};
    const float* Wl1 = (const float*)d_in[15];
    const float* bl1 = (const float*)d_in[16];
    const float* Wl2 = (const float*)d_in[17];
    const float* bl2 = (const float*)d_in[18];
    const float* Wl3 = (const float*)d_in[19];
    const float* bl3 = (const float*)d_in[20];
    float* out = (float*)d_out;

    // workspace carve (4B units)
    float* fws = (float*)d_ws;
    size_t off = 0;
    float* hA     = fws + off; off += (size_t)N_NODES * H;
    float* hB     = fws + off; off += (size_t)N_NODES * H;
    float* xw     = fws + off; off += (size_t)N_NODES * H;
    float* scorem = fws + off; off += N_NODES;
    float* xws    = fws + off; off += N_NODES;
    float* norm   = fws + off; off += N_NODES;
    float* mnorm  = fws + off; off += N_NODES;
    float* mA     = fws + off; off += N_NODES;
    float* mB     = fws + off; off += N_NODES;
    float* gfac   = fws + off; off += N_NODES;
    float* rbuf   = fws + off; off += (size_t)G_GRAPHS * 2 * H;
    float* partS  = fws + off; off += (size_t)G_GRAPHS * RSUB * H;
    float* partM  = fws + off; off += (size_t)G_GRAPHS * RSUB * H;
    float* partC  = fws + off; off += (size_t)G_GRAPHS * RSUB;
    int* counts   = (int*)(fws + off); off += G_GRAPHS;
    int* starts   = (int*)(fws + off); off += G_GRAPHS;
    int* kkarr    = (int*)(fws + off); off += G_GRAPHS;
    int* rowptr   = (int*)(fws + off); off += N_NODES + 1;
    int* indeg    = (int*)(fws + off); off += N_NODES;
    int* cursor   = (int*)(fws + off); off += N_NODES;
    int* bsum     = (int*)(fws + off); off += NBLK_SCAN;
    int* boff     = (int*)(fws + off); off += NBLK_SCAN;
    int* srcC     = (int*)(fws + off); off += N_EDGES;

    int nblkN  = (N_NODES + 255) / 256;
    int nblkN8 = (N_NODES * 8 + 255) / 256;
    int nblkE  = (N_EDGES + 255) / 256;

    // graph segment structure (batch is sorted -> boundary detect, no atomics)
    starts_kernel<<<nblkN, 256, 0, stream>>>(batch, starts, N_NODES);
    counts_kernel<<<1, 128, 0, stream>>>(starts, counts);

    // CSR build (dst-grouped), deterministic via per-node wave sort
    hipMemsetAsync(indeg, 0, N_NODES * sizeof(int), stream);
    hipMemsetAsync(cursor, 0, N_NODES * sizeof(int), stream);
    indeg_kernel<<<nblkE, 256, 0, stream>>>(dstp, indeg, N_EDGES);
    bsum_kernel<<<NBLK_SCAN, 256, 0, stream>>>(indeg, bsum, N_NODES);
    bscan_kernel<<<1, 256, 0, stream>>>(bsum, boff, NBLK_SCAN);
    rowptr_kernel<<<NBLK_SCAN, 256, 0, stream>>>(indeg, boff, rowptr, N_NODES);
    scatter_kernel<<<nblkE, 256, 0, stream>>>(src, dstp, rowptr, cursor, srcC, N_EDGES);
    wsort_kernel<<<(N_NODES + 3) / 4, 256, 0, stream>>>(rowptr, srcC, N_NODES);

    fill_kernel<<<nblkN, 256, 0, stream>>>(mA, 1.f, N_NODES);
    fill_kernel<<<nblkN, 256, 0, stream>>>(gfac, 1.f, N_NODES);
    hipMemsetAsync(rbuf, 0, G_GRAPHS * 2 * H * sizeof(float), stream);

    const float* hin = x;
    float* hout = hA;
    const float* mcur = mA;
    float* mnext = mB;

    for (int blk = 0; blk < 3; ++blk) {
        degnorm_kernel<<<nblkN8, 256, 0, stream>>>(rowptr, srcC, mcur, norm, mnorm, N_NODES);
        gemm128_kernel<<<(N_NODES + 63) / 64, 256, 0, stream>>>(hin, Wb[blk], gfac, xw, N_NODES);
        agg_fused_kernel<<<(N_NODES + 3) / 4, 256, 0, stream>>>(xw, rowptr, srcC, mcur, norm,
                                                                mnorm, bbv[blk], Wsb[blk],
                                                                hout, xws, N_NODES);
        score_gather_kernel<<<nblkN8, 256, 0, stream>>>(rowptr, srcC, xws, mcur, norm, mnorm,
                                                        bsb[blk], scorem, N_NODES);
        kk_kernel<<<G_GRAPHS, 256, 0, stream>>>(scorem, starts, counts, kkarr);
        rank_kernel<<<(N_NODES + 3) / 4, 256, 0, stream>>>(scorem, mcur, batch, starts, counts,
                                                           kkarr, mnext, gfac, N_NODES);
        readout_part_kernel<<<G_GRAPHS * RSUB, 128, 0, stream>>>(hout, mnext, gfac, starts,
                                                                 counts, partS, partM, partC);
        readout_comb_kernel<<<G_GRAPHS, 128, 0, stream>>>(partS, partM, partC, rbuf);
        hin = hout;
        hout = (hout == hA) ? hB : hA;
        const float* tm = mcur; mcur = mnext; mnext = (float*)tm;
    }

    mlp_kernel<<<G_GRAPHS, 128, 0, stream>>>(rbuf, Wl1, bl1, Wl2, bl2, Wl3, bl3, out);
}

// Round 20
// 458.737 us; speedup vs baseline: 3.4684x; 1.0000x over previous
//
#include <hip/hip_runtime.h>
#include <math.h>

#define N_NODES 50000
#define N_EDGES 600000
#define H 128
#define G_GRAPHS 100
#define C_CLS 10
#define NBLK_SCAN ((N_NODES + 255) / 256)
#define RSUB 16

// ---------------- graph segment structure (batch sorted -> boundary detect) ----------------

__global__ void fill_kernel(float* __restrict__ p, float v, int n) {
    int i = blockIdx.x * 256 + threadIdx.x;
    if (i < n) p[i] = v;
}

__global__ void starts_kernel(const int* __restrict__ batch, int* __restrict__ starts, int n) {
    int i = blockIdx.x * 256 + threadIdx.x;
    if (i >= n) return;
    int b = batch[i];
    int prev = (i == 0) ? -1 : batch[i - 1];
    for (int g = prev + 1; g <= b; ++g) starts[g] = i;
    if (i == n - 1) {
        for (int g = b + 1; g < G_GRAPHS; ++g) starts[g] = n;
    }
}

__global__ void counts_kernel(const int* __restrict__ starts, int* __restrict__ counts) {
    int g = threadIdx.x;
    if (g < G_GRAPHS) {
        int e = (g == G_GRAPHS - 1) ? N_NODES : starts[g + 1];
        counts[g] = e - starts[g];
    }
}

// ---------------- CSR build (dst-grouped, deterministic) ----------------

__global__ void indeg_kernel(const int* __restrict__ dst, int* __restrict__ indeg, int ne) {
    int e = blockIdx.x * 256 + threadIdx.x;
    if (e < ne) atomicAdd(&indeg[dst[e]], 1);
}

__global__ void bsum_kernel(const int* __restrict__ indeg, int* __restrict__ bsum, int n) {
    __shared__ int red[256];
    int i = blockIdx.x * 256 + threadIdx.x;
    red[threadIdx.x] = (i < n) ? indeg[i] : 0;
    __syncthreads();
    for (int o = 128; o > 0; o >>= 1) {
        if (threadIdx.x < o) red[threadIdx.x] += red[threadIdx.x + o];
        __syncthreads();
    }
    if (threadIdx.x == 0) bsum[blockIdx.x] = red[0];
}

__global__ void bscan_kernel(const int* __restrict__ bsum, int* __restrict__ boff, int nb) {
    __shared__ int s[256];
    int t = threadIdx.x;
    s[t] = (t < nb) ? bsum[t] : 0;
    __syncthreads();
    for (int o = 1; o < 256; o <<= 1) {
        int v = (t >= o) ? s[t - o] : 0;
        __syncthreads();
        s[t] += v;
        __syncthreads();
    }
    if (t < nb) boff[t] = (t == 0) ? 0 : s[t - 1];
}

__global__ void rowptr_kernel(const int* __restrict__ indeg, const int* __restrict__ boff,
                              int* __restrict__ rowptr, int n) {
    __shared__ int s[256];
    int i = blockIdx.x * 256 + threadIdx.x;
    int t = threadIdx.x;
    int v = (i < n) ? indeg[i] : 0;
    s[t] = v;
    __syncthreads();
    for (int o = 1; o < 256; o <<= 1) {
        int u = (t >= o) ? s[t - o] : 0;
        __syncthreads();
        s[t] += u;
        __syncthreads();
    }
    int incl = s[t];
    int excl = incl - v;
    if (i < n) rowptr[i] = boff[blockIdx.x] + excl;
    if (i == n - 1) rowptr[n] = boff[blockIdx.x] + incl;
}

__global__ void scatter_kernel(const int* __restrict__ src, const int* __restrict__ dst,
                               const int* __restrict__ rowptr, int* __restrict__ cursor,
                               int* __restrict__ srcC, int ne) {
    int e = blockIdx.x * 256 + threadIdx.x;
    if (e >= ne) return;
    int d = dst[e];
    int pos = rowptr[d] + atomicAdd(&cursor[d], 1);
    srcC[pos] = src[e];
}

// ---------------- wave-per-node odd-even sort (canonical ascending; deterministic) ----------

__global__ __launch_bounds__(256) void wsort_kernel(const int* __restrict__ rowptr,
                                                    int* __restrict__ srcC, int n) {
    int node = blockIdx.x * 4 + (threadIdx.x >> 6);
    if (node >= n) return;
    int lane = threadIdx.x & 63;
    int e0 = rowptr[node], e1 = rowptr[node + 1];
    int len = e1 - e0;
    if (len <= 1) return;
    if (len <= 64) {
        int key = (lane < len) ? srcC[e0 + lane] : 0x7fffffff;
        for (int p = 0; p < len; ++p) {
            int partner = ((lane ^ p) & 1) ? lane - 1 : lane + 1;
            int pv = __shfl(key, partner & 63, 64);
            if (partner >= 0 && partner < 64) {
                key = (partner > lane) ? min(key, pv) : max(key, pv);
            }
        }
        if (lane < len) srcC[e0 + lane] = key;
    } else {
        if (lane == 0) {
            for (int i = e0 + 1; i < e1; ++i) {
                int k = srcC[i];
                int j = i - 1;
                while (j >= e0 && srcC[j] > k) { srcC[j + 1] = srcC[j]; --j; }
                srcC[j + 1] = k;
            }
        }
    }
}

// ---------------- degree / norm: 8 lanes per node (parallel gather) ----------------

__global__ void degnorm_kernel(const int* __restrict__ rowptr, const int* __restrict__ srcC,
                               const float* __restrict__ mask, float* __restrict__ norm,
                               float* __restrict__ mnorm, int n) {
    int idx = blockIdx.x * 256 + threadIdx.x;
    int d = idx >> 3;
    if (d >= n) return;
    int l = idx & 7;
    float md = mask[d];
    float s = 0.f;
    if (md != 0.f) {
        int e0 = rowptr[d], e1 = rowptr[d + 1];
        for (int e = e0 + l; e < e1; e += 8) s += mask[srcC[e]];
    }
#pragma unroll
    for (int o = 4; o > 0; o >>= 1) s += __shfl_down(s, o, 8);
    if (l == 0) {
        float nd = rsqrtf(1.f + md * s);
        norm[d] = nd;
        mnorm[d] = md * nd;
    }
}

// ---------------- GEMM: out[n][128] = (gfac[n] * A[n][128]) @ W[128][128] ----------------

__global__ __launch_bounds__(256) void gemm128_kernel(const float* __restrict__ A,
                                                      const float* __restrict__ W,
                                                      const float* __restrict__ gf,
                                                      float* __restrict__ out, int nrows) {
    __shared__ float sT[128][68];
    int row0 = blockIdx.x * 64;
    int tid = threadIdx.x;
    for (int i = tid; i < 2048; i += 256) {
        int r = i >> 5, c4 = i & 31;
        int row = row0 + r;
        float4 v = make_float4(0.f, 0.f, 0.f, 0.f);
        if (row < nrows) {
            float g = gf[row];
            v = ((const float4*)(A + (size_t)row * H))[c4];
            v.x *= g; v.y *= g; v.z *= g; v.w *= g;
        }
        sT[c4 * 4 + 0][r] = v.x; sT[c4 * 4 + 1][r] = v.y;
        sT[c4 * 4 + 2][r] = v.z; sT[c4 * 4 + 3][r] = v.w;
    }
    __syncthreads();
    int cg = tid & 31;
    int rg = tid >> 5;
    float acc[8][4];
#pragma unroll
    for (int i = 0; i < 8; ++i)
#pragma unroll
        for (int j = 0; j < 4; ++j) acc[i][j] = 0.f;

#pragma unroll 4
    for (int k = 0; k < 128; ++k) {
        float4 w4 = ((const float4*)(W + k * H))[cg];
        const float4* pa = (const float4*)(&sT[k][rg * 8]);
        float4 a0 = pa[0], a1 = pa[1];
        float av[8] = {a0.x, a0.y, a0.z, a0.w, a1.x, a1.y, a1.z, a1.w};
#pragma unroll
        for (int i = 0; i < 8; ++i) {
            acc[i][0] = fmaf(av[i], w4.x, acc[i][0]);
            acc[i][1] = fmaf(av[i], w4.y, acc[i][1]);
            acc[i][2] = fmaf(av[i], w4.z, acc[i][2]);
            acc[i][3] = fmaf(av[i], w4.w, acc[i][3]);
        }
    }
#pragma unroll
    for (int i = 0; i < 8; ++i) {
        int row = row0 + rg * 8 + i;
        if (row < nrows) {
            float4 o = make_float4(acc[i][0], acc[i][1], acc[i][2], acc[i][3]);
            ((float4*)(out + (size_t)row * H))[cg] = o;
        }
    }
}

// ---------------- fused gather agg + self + bias + relu + score-dot ----------------
// 8 nodes/block, 32 threads/node, 4-edge unroll; gathers GUARDED on c!=0:
// masked sources (c==0) contribute exactly 0 -> skipping the 512B row load is
// bit-exact and saves ~50%/75% of gather traffic in blocks 2/3.

__global__ __launch_bounds__(256) void agg_fused_kernel(const float* __restrict__ xw,
        const int* __restrict__ rowptr, const int* __restrict__ srcC,
        const float* __restrict__ mask, const float* __restrict__ norm,
        const float* __restrict__ mnorm,
        const float* __restrict__ b, const float* __restrict__ Ws,
        float* __restrict__ hout, float* __restrict__ xws, int n) {
    int node = blockIdx.x * 8 + (threadIdx.x >> 5);
    if (node >= n) return;
    int t = threadIdx.x & 31;
    const float4* xw4 = (const float4*)xw;
    float md = mask[node];
    float nd = norm[node];
    float4 a0 = make_float4(0.f, 0.f, 0.f, 0.f);
    float4 a1 = a0, a2 = a0, a3 = a0;
    if (md != 0.f) {
        int e0 = rowptr[node], e1 = rowptr[node + 1];
        int e = e0;
        for (; e + 3 < e1; e += 4) {
            int s0 = srcC[e], s1 = srcC[e + 1], s2 = srcC[e + 2], s3 = srcC[e + 3];
            float c0 = mnorm[s0];
            float c1 = mnorm[s1];
            float c2 = mnorm[s2];
            float c3 = mnorm[s3];
            if (c0 != 0.f) {
                float4 v = xw4[(size_t)s0 * 32 + t];
                a0.x = fmaf(v.x, c0, a0.x); a0.y = fmaf(v.y, c0, a0.y);
                a0.z = fmaf(v.z, c0, a0.z); a0.w = fmaf(v.w, c0, a0.w);
            }
            if (c1 != 0.f) {
                float4 v = xw4[(size_t)s1 * 32 + t];
                a1.x = fmaf(v.x, c1, a1.x); a1.y = fmaf(v.y, c1, a1.y);
                a1.z = fmaf(v.z, c1, a1.z); a1.w = fmaf(v.w, c1, a1.w);
            }
            if (c2 != 0.f) {
                float4 v = xw4[(size_t)s2 * 32 + t];
                a2.x = fmaf(v.x, c2, a2.x); a2.y = fmaf(v.y, c2, a2.y);
                a2.z = fmaf(v.z, c2, a2.z); a2.w = fmaf(v.w, c2, a2.w);
            }
            if (c3 != 0.f) {
                float4 v = xw4[(size_t)s3 * 32 + t];
                a3.x = fmaf(v.x, c3, a3.x); a3.y = fmaf(v.y, c3, a3.y);
                a3.z = fmaf(v.z, c3, a3.z); a3.w = fmaf(v.w, c3, a3.w);
            }
        }
        for (; e < e1; ++e) {
            int s = srcC[e];
            float c = mnorm[s];
            if (c != 0.f) {
                float4 v = xw4[(size_t)s * 32 + t];
                a0.x = fmaf(v.x, c, a0.x); a0.y = fmaf(v.y, c, a0.y);
                a0.z = fmaf(v.z, c, a0.z); a0.w = fmaf(v.w, c, a0.w);
            }
        }
        float sc = md * nd;
        a0.x = (((a0.x + a1.x) + a2.x) + a3.x) * sc;
        a0.y = (((a0.y + a1.y) + a2.y) + a3.y) * sc;
        a0.z = (((a0.z + a1.z) + a2.z) + a3.z) * sc;
        a0.w = (((a0.w + a1.w) + a2.w) + a3.w) * sc;
    }
    float4 self = xw4[(size_t)node * 32 + t];
    float4 bb = ((const float4*)b)[t];
    float n2 = nd * nd;
    float4 v;
    v.x = fmaxf(fmaf(self.x, n2, a0.x) + bb.x, 0.f);
    v.y = fmaxf(fmaf(self.y, n2, a0.y) + bb.y, 0.f);
    v.z = fmaxf(fmaf(self.z, n2, a0.z) + bb.z, 0.f);
    v.w = fmaxf(fmaf(self.w, n2, a0.w) + bb.w, 0.f);
    ((float4*)hout)[(size_t)node * 32 + t] = v;
    // fused score projection: xws[node] = dot(hout_row, Ws)
    float4 w = ((const float4*)Ws)[t];
    float p = ((v.x * w.x + v.y * w.y) + v.z * w.z) + v.w * w.w;
#pragma unroll
    for (int o = 16; o > 0; o >>= 1) p += __shfl_down(p, o, 32);
    if (t == 0) xws[node] = p;
}

// ---------------- score gather: 8 lanes per node -> masked score ----------------

__global__ void score_gather_kernel(const int* __restrict__ rowptr, const int* __restrict__ srcC,
        const float* __restrict__ xws, const float* __restrict__ mask,
        const float* __restrict__ norm, const float* __restrict__ mnorm,
        const float* __restrict__ bs, float* __restrict__ scorem, int n) {
    int idx = blockIdx.x * 256 + threadIdx.x;
    int d = idx >> 3;
    if (d >= n) return;
    int l = idx & 7;
    float md = mask[d];
    float nd = norm[d];
    float acc = 0.f;
    if (md != 0.f) {
        int e0 = rowptr[d], e1 = rowptr[d + 1];
        for (int e = e0 + l; e < e1; e += 8) {
            int s = srcC[e];
            acc = fmaf(xws[s], mnorm[s], acc);
        }
    }
#pragma unroll
    for (int o = 4; o > 0; o >>= 1) acc += __shfl_down(acc, o, 8);
    if (l == 0) {
        float out;
        if (md != 0.f) out = acc * (md * nd) + xws[d] * nd * nd + bs[0];
        else out = -INFINITY;
        scorem[d] = out;
    }
}

// ---------------- per-graph k (ceil(0.5 * active)) ----------------

__global__ __launch_bounds__(256) void kk_kernel(const float* __restrict__ scorem,
        const int* __restrict__ starts, const int* __restrict__ counts,
        int* __restrict__ kkarr) {
    int g = blockIdx.x;
    int s0 = starts[g], cnt = counts[g];
    __shared__ int red[256];
    int c = 0;
    for (int i = threadIdx.x; i < cnt; i += 256)
        if (scorem[s0 + i] != -INFINITY) ++c;
    red[threadIdx.x] = c;
    __syncthreads();
    for (int o = 128; o > 0; o >>= 1) {
        if (threadIdx.x < o) red[threadIdx.x] += red[threadIdx.x + o];
        __syncthreads();
    }
    if (threadIdx.x == 0) kkarr[g] = (int)ceilf(0.5f * (float)red[0]);
}

// ---------------- rank-based top-k: one 64-lane wave per node ----------------

__global__ __launch_bounds__(256) void rank_kernel(const float* __restrict__ scorem,
        const float* __restrict__ mask, const int* __restrict__ batch,
        const int* __restrict__ starts, const int* __restrict__ counts,
        const int* __restrict__ kkarr,
        float* __restrict__ nmask, float* __restrict__ gfac, int n) {
    int i = blockIdx.x * 4 + (threadIdx.x >> 6);
    if (i >= n) return;
    int lane = threadIdx.x & 63;
    float sci = scorem[i];
    if (sci == -INFINITY) {
        if (lane == 0) { nmask[i] = 0.f; gfac[i] = 0.f; }
        return;
    }
    int g = batch[i];
    int s0 = starts[g], cnt = counts[g];
    int r = 0;
    for (int j = lane; j < cnt; j += 64) {
        float sj = scorem[s0 + j];
        if (sj > sci || (sj == sci && (s0 + j) < i)) ++r;
    }
#pragma unroll
    for (int o = 32; o > 0; o >>= 1) r += __shfl_down(r, o);
    if (lane == 0) {
        bool keep = (r < kkarr[g]);
        float m = mask[i];
        nmask[i] = keep ? m : 0.f;
        gfac[i] = keep ? tanhf(sci) * m : 0.f;
    }
}

// ---------------- readout phase 1: per-(graph, sub-slice) partials ----------------

__global__ __launch_bounds__(128) void readout_part_kernel(const float* __restrict__ h,
        const float* __restrict__ mask, const float* __restrict__ gfac,
        const int* __restrict__ starts, const int* __restrict__ counts,
        float* __restrict__ partS, float* __restrict__ partM, float* __restrict__ partC) {
    int g = blockIdx.x >> 4;
    int sub = blockIdx.x & (RSUB - 1);
    int f = threadIdx.x;
    int s0 = starts[g], cnt = counts[g];
    float s = 0.f, mx = -INFINITY, c = 0.f;
    for (int i = sub; i < cnt; i += RSUB) {
        float m = mask[s0 + i];
        if (m > 0.f) {
            float v = h[(size_t)(s0 + i) * H + f] * gfac[s0 + i];
            s += v; mx = fmaxf(mx, v); c += 1.f;
        }
    }
    size_t pidx = (size_t)blockIdx.x * H + f;
    partS[pidx] = s;
    partM[pidx] = mx;
    if (f == 0) partC[blockIdx.x] = c;
}

// ---------------- readout phase 2: combine partials in fixed order -> rbuf ----------------

__global__ __launch_bounds__(128) void readout_comb_kernel(const float* __restrict__ partS,
        const float* __restrict__ partM, const float* __restrict__ partC,
        float* __restrict__ r) {
    int g = blockIdx.x;
    int f = threadIdx.x;
    float S = 0.f, M = -INFINITY, C = 0.f;
    for (int sub = 0; sub < RSUB; ++sub) {
        size_t pidx = (size_t)(g * RSUB + sub) * H + f;
        S += partS[pidx];
        M = fmaxf(M, partM[pidx]);
        C += partC[g * RSUB + sub];
    }
    float mean = S / fmaxf(C, 1.f);
    if (C == 0.f) M = 0.f;
    r[(size_t)g * 2 * H + f] += M;
    r[(size_t)g * 2 * H + H + f] += mean;
}

// ---------------- MLP head + log_softmax ----------------

__global__ __launch_bounds__(128) void mlp_kernel(const float* __restrict__ r,
        const float* __restrict__ Wl1, const float* __restrict__ bl1,
        const float* __restrict__ Wl2, const float* __restrict__ bl2,
        const float* __restrict__ Wl3, const float* __restrict__ bl3,
        float* __restrict__ out) {
    int g = blockIdx.x;
    int t = threadIdx.x;
    __shared__ float sz[256];
    __shared__ float sy1[128];
    __shared__ float sy2[64];
    __shared__ float sy3[10];
    __shared__ float sred[2];
    sz[t] = r[g * 256 + t];
    sz[t + 128] = r[g * 256 + 128 + t];
    __syncthreads();
    float a = bl1[t];
    for (int k = 0; k < 256; ++k) a = fmaf(sz[k], Wl1[k * 128 + t], a);
    sy1[t] = fmaxf(a, 0.f);
    __syncthreads();
    if (t < 64) {
        float a2 = bl2[t];
        for (int k = 0; k < 128; ++k) a2 = fmaf(sy1[k], Wl2[k * 64 + t], a2);
        sy2[t] = fmaxf(a2, 0.f);
    }
    __syncthreads();
    if (t < 10) {
        float a3 = bl3[t];
        for (int k = 0; k < 64; ++k) a3 = fmaf(sy2[k], Wl3[k * 10 + t], a3);
        sy3[t] = a3;
    }
    __syncthreads();
    if (t == 0) {
        float m = sy3[0];
        for (int c2 = 1; c2 < 10; ++c2) m = fmaxf(m, sy3[c2]);
        float se = 0.f;
        for (int c2 = 0; c2 < 10; ++c2) se += expf(sy3[c2] - m);
        sred[0] = m; sred[1] = logf(se);
    }
    __syncthreads();
    if (t < 10) out[g * 10 + t] = sy3[t] - sred[0] - sred[1];
}

// ---------------- launch ----------------

extern "C" void kernel_launch(void* const* d_in, const int* in_sizes, int n_in,
                              void* d_out, int out_size, void* d_ws, size_t ws_size,
                              hipStream_t stream) {
    const float* x     = (const float*)d_in[0];
    const int*   ei    = (const int*)d_in[1];
    const int*   batch = (const int*)d_in[2];
    const int* src  = ei;
    const int* dstp = ei + N_EDGES;
    const float* Wb[3]  = {(const float*)d_in[3], (const float*)d_in[7],  (const float*)d_in[11]};
    const float* bbv[3] = {(const float*)d_in[4], (const float*)d_in[8],  (const float*)d_in[12]};
    const float* Wsb[3] = {(const float*)d_in[5], (const float*)d_in[9],  (const float*)d_in[13]};
    const float* bsb[3] = {(const float*)d_in[6], (const float*)d_in[10], (const float*)d_in[14]};
    const float* Wl1 = (const float*)d_in[15];
    const float* bl1 = (const float*)d_in[16];
    const float* Wl2 = (const float*)d_in[17];
    const float* bl2 = (const float*)d_in[18];
    const float* Wl3 = (const float*)d_in[19];
    const float* bl3 = (const float*)d_in[20];
    float* out = (float*)d_out;

    // workspace carve (4B units)
    float* fws = (float*)d_ws;
    size_t off = 0;
    float* hA     = fws + off; off += (size_t)N_NODES * H;
    float* hB     = fws + off; off += (size_t)N_NODES * H;
    float* xw     = fws + off; off += (size_t)N_NODES * H;
    float* scorem = fws + off; off += N_NODES;
    float* xws    = fws + off; off += N_NODES;
    float* norm   = fws + off; off += N_NODES;
    float* mnorm  = fws + off; off += N_NODES;
    float* mA     = fws + off; off += N_NODES;
    float* mB     = fws + off; off += N_NODES;
    float* gfac   = fws + off; off += N_NODES;
    float* rbuf   = fws + off; off += (size_t)G_GRAPHS * 2 * H;
    float* partS  = fws + off; off += (size_t)G_GRAPHS * RSUB * H;
    float* partM  = fws + off; off += (size_t)G_GRAPHS * RSUB * H;
    float* partC  = fws + off; off += (size_t)G_GRAPHS * RSUB;
    int* counts   = (int*)(fws + off); off += G_GRAPHS;
    int* starts   = (int*)(fws + off); off += G_GRAPHS;
    int* kkarr    = (int*)(fws + off); off += G_GRAPHS;
    int* rowptr   = (int*)(fws + off); off += N_NODES + 1;
    int* indeg    = (int*)(fws + off); off += N_NODES;
    int* cursor   = (int*)(fws + off); off += N_NODES;
    int* bsum     = (int*)(fws + off); off += NBLK_SCAN;
    int* boff     = (int*)(fws + off); off += NBLK_SCAN;
    int* srcC     = (int*)(fws + off); off += N_EDGES;

    int nblkN  = (N_NODES + 255) / 256;
    int nblkN8 = (N_NODES * 8 + 255) / 256;
    int nblkE  = (N_EDGES + 255) / 256;

    // graph segment structure (batch is sorted -> boundary detect, no atomics)
    starts_kernel<<<nblkN, 256, 0, stream>>>(batch, starts, N_NODES);
    counts_kernel<<<1, 128, 0, stream>>>(starts, counts);

    // CSR build (dst-grouped), deterministic via per-node wave sort
    hipMemsetAsync(indeg, 0, N_NODES * sizeof(int), stream);
    hipMemsetAsync(cursor, 0, N_NODES * sizeof(int), stream);
    indeg_kernel<<<nblkE, 256, 0, stream>>>(dstp, indeg, N_EDGES);
    bsum_kernel<<<NBLK_SCAN, 256, 0, stream>>>(indeg, bsum, N_NODES);
    bscan_kernel<<<1, 256, 0, stream>>>(bsum, boff, NBLK_SCAN);
    rowptr_kernel<<<NBLK_SCAN, 256, 0, stream>>>(indeg, boff, rowptr, N_NODES);
    scatter_kernel<<<nblkE, 256, 0, stream>>>(src, dstp, rowptr, cursor, srcC, N_EDGES);
    wsort_kernel<<<(N_NODES + 3) / 4, 256, 0, stream>>>(rowptr, srcC, N_NODES);

    fill_kernel<<<nblkN, 256, 0, stream>>>(mA, 1.f, N_NODES);
    fill_kernel<<<nblkN, 256, 0, stream>>>(gfac, 1.f, N_NODES);
    hipMemsetAsync(rbuf, 0, G_GRAPHS * 2 * H * sizeof(float), stream);

    const float* hin = x;
    float* hout = hA;
    const float* mcur = mA;
    float* mnext = mB;

    for (int blk = 0; blk < 3; ++blk) {
        degnorm_kernel<<<nblkN8, 256, 0, stream>>>(rowptr, srcC, mcur, norm, mnorm, N_NODES);
        gemm128_kernel<<<(N_NODES + 63) / 64, 256, 0, stream>>>(hin, Wb[blk], gfac, xw, N_NODES);
        agg_fused_kernel<<<(N_NODES + 7) / 8, 256, 0, stream>>>(xw, rowptr, srcC, mcur, norm,
                                                                mnorm, bbv[blk], Wsb[blk],
                                                                hout, xws, N_NODES);
        score_gather_kernel<<<nblkN8, 256, 0, stream>>>(rowptr, srcC, xws, mcur, norm, mnorm,
                                                        bsb[blk], scorem, N_NODES);
        kk_kernel<<<G_GRAPHS, 256, 0, stream>>>(scorem, starts, counts, kkarr);
        rank_kernel<<<(N_NODES + 3) / 4, 256, 0, stream>>>(scorem, mcur, batch, starts, counts,
                                                           kkarr, mnext, gfac, N_NODES);
        readout_part_kernel<<<G_GRAPHS * RSUB, 128, 0, stream>>>(hout, mnext, gfac, starts,
                                                                 counts, partS, partM, partC);
        readout_comb_kernel<<<G_GRAPHS, 128, 0, stream>>>(partS, partM, partC, rbuf);
        hin = hout;
        hout = (hout == hA) ? hB : hA;
        const float* tm = mcur; mcur = mnext; mnext = (float*)tm;
    }

    mlp_kernel<<<G_GRAPHS, 128, 0, stream>>>(rbuf, Wl1, bl1, Wl2, bl2, Wl3, bl3, out);
}

// Round 21
// 451.240 us; speedup vs baseline: 3.5261x; 1.0166x over previous
//
#include <hip/hip_runtime.h>
#include <math.h>

#define N_NODES 50000
#define N_EDGES 600000
#define H 128
#define G_GRAPHS 100
#define C_CLS 10
#define NBLK_SCAN ((N_NODES + 255) / 256)
#define RSUB 16

// ---------------- graph segment structure (batch sorted -> boundary detect) ----------------

__global__ void fill_kernel(float* __restrict__ p, float v, int n) {
    int i = blockIdx.x * 256 + threadIdx.x;
    if (i < n) p[i] = v;
}

__global__ void starts_kernel(const int* __restrict__ batch, int* __restrict__ starts, int n) {
    int i = blockIdx.x * 256 + threadIdx.x;
    if (i >= n) return;
    int b = batch[i];
    int prev = (i == 0) ? -1 : batch[i - 1];
    for (int g = prev + 1; g <= b; ++g) starts[g] = i;
    if (i == n - 1) {
        for (int g = b + 1; g < G_GRAPHS; ++g) starts[g] = n;
    }
}

__global__ void counts_kernel(const int* __restrict__ starts, int* __restrict__ counts) {
    int g = threadIdx.x;
    if (g < G_GRAPHS) {
        int e = (g == G_GRAPHS - 1) ? N_NODES : starts[g + 1];
        counts[g] = e - starts[g];
    }
}

// ---------------- CSR build (dst-grouped, deterministic) ----------------

__global__ void indeg_kernel(const int* __restrict__ dst, int* __restrict__ indeg, int ne) {
    int e = blockIdx.x * 256 + threadIdx.x;
    if (e < ne) atomicAdd(&indeg[dst[e]], 1);
}

__global__ void bsum_kernel(const int* __restrict__ indeg, int* __restrict__ bsum, int n) {
    __shared__ int red[256];
    int i = blockIdx.x * 256 + threadIdx.x;
    red[threadIdx.x] = (i < n) ? indeg[i] : 0;
    __syncthreads();
    for (int o = 128; o > 0; o >>= 1) {
        if (threadIdx.x < o) red[threadIdx.x] += red[threadIdx.x + o];
        __syncthreads();
    }
    if (threadIdx.x == 0) bsum[blockIdx.x] = red[0];
}

__global__ void bscan_kernel(const int* __restrict__ bsum, int* __restrict__ boff, int nb) {
    __shared__ int s[256];
    int t = threadIdx.x;
    s[t] = (t < nb) ? bsum[t] : 0;
    __syncthreads();
    for (int o = 1; o < 256; o <<= 1) {
        int v = (t >= o) ? s[t - o] : 0;
        __syncthreads();
        s[t] += v;
        __syncthreads();
    }
    if (t < nb) boff[t] = (t == 0) ? 0 : s[t - 1];
}

__global__ void rowptr_kernel(const int* __restrict__ indeg, const int* __restrict__ boff,
                              int* __restrict__ rowptr, int n) {
    __shared__ int s[256];
    int i = blockIdx.x * 256 + threadIdx.x;
    int t = threadIdx.x;
    int v = (i < n) ? indeg[i] : 0;
    s[t] = v;
    __syncthreads();
    for (int o = 1; o < 256; o <<= 1) {
        int u = (t >= o) ? s[t - o] : 0;
        __syncthreads();
        s[t] += u;
        __syncthreads();
    }
    int incl = s[t];
    int excl = incl - v;
    if (i < n) rowptr[i] = boff[blockIdx.x] + excl;
    if (i == n - 1) rowptr[n] = boff[blockIdx.x] + incl;
}

__global__ void scatter_kernel(const int* __restrict__ src, const int* __restrict__ dst,
                               const int* __restrict__ rowptr, int* __restrict__ cursor,
                               int* __restrict__ srcC, int ne) {
    int e = blockIdx.x * 256 + threadIdx.x;
    if (e >= ne) return;
    int d = dst[e];
    int pos = rowptr[d] + atomicAdd(&cursor[d], 1);
    srcC[pos] = src[e];
}

// ---------------- wave-per-node odd-even sort (canonical ascending; deterministic) ----------

__global__ __launch_bounds__(256) void wsort_kernel(const int* __restrict__ rowptr,
                                                    int* __restrict__ srcC, int n) {
    int node = blockIdx.x * 4 + (threadIdx.x >> 6);
    if (node >= n) return;
    int lane = threadIdx.x & 63;
    int e0 = rowptr[node], e1 = rowptr[node + 1];
    int len = e1 - e0;
    if (len <= 1) return;
    if (len <= 64) {
        int key = (lane < len) ? srcC[e0 + lane] : 0x7fffffff;
        for (int p = 0; p < len; ++p) {
            int partner = ((lane ^ p) & 1) ? lane - 1 : lane + 1;
            int pv = __shfl(key, partner & 63, 64);
            if (partner >= 0 && partner < 64) {
                key = (partner > lane) ? min(key, pv) : max(key, pv);
            }
        }
        if (lane < len) srcC[e0 + lane] = key;
    } else {
        if (lane == 0) {
            for (int i = e0 + 1; i < e1; ++i) {
                int k = srcC[i];
                int j = i - 1;
                while (j >= e0 && srcC[j] > k) { srcC[j + 1] = srcC[j]; --j; }
                srcC[j + 1] = k;
            }
        }
    }
}

// ---------------- degree / norm: 8 lanes per node (parallel gather) ----------------

__global__ void degnorm_kernel(const int* __restrict__ rowptr, const int* __restrict__ srcC,
                               const float* __restrict__ mask, float* __restrict__ norm,
                               float* __restrict__ mnorm, int n) {
    int idx = blockIdx.x * 256 + threadIdx.x;
    int d = idx >> 3;
    if (d >= n) return;
    int l = idx & 7;
    float md = mask[d];
    float s = 0.f;
    if (md != 0.f) {
        int e0 = rowptr[d], e1 = rowptr[d + 1];
        for (int e = e0 + l; e < e1; e += 8) s += mask[srcC[e]];
    }
#pragma unroll
    for (int o = 4; o > 0; o >>= 1) s += __shfl_down(s, o, 8);
    if (l == 0) {
        float nd = rsqrtf(1.f + md * s);
        norm[d] = nd;
        mnorm[d] = md * nd;
    }
}

// ---------------- active-node compaction (order-independent per-row results) ----------------

__global__ void compact_kernel(const float* __restrict__ nmask, int* __restrict__ alist,
                               int* __restrict__ alcnt, int n) {
    int i = blockIdx.x * 256 + threadIdx.x;
    if (i < n && nmask[i] > 0.f) {
        int pos = atomicAdd(alcnt, 1);
        alist[pos] = i;
    }
}

// ---------------- GEMM (full): out[n][128] = (gfac[n] * A[n][128]) @ W[128][128] ----------------

__global__ __launch_bounds__(256) void gemm128_kernel(const float* __restrict__ A,
                                                      const float* __restrict__ W,
                                                      const float* __restrict__ gf,
                                                      float* __restrict__ out, int nrows) {
    __shared__ float sT[128][68];
    int row0 = blockIdx.x * 64;
    int tid = threadIdx.x;
    for (int i = tid; i < 2048; i += 256) {
        int r = i >> 5, c4 = i & 31;
        int row = row0 + r;
        float4 v = make_float4(0.f, 0.f, 0.f, 0.f);
        if (row < nrows) {
            float g = gf[row];
            v = ((const float4*)(A + (size_t)row * H))[c4];
            v.x *= g; v.y *= g; v.z *= g; v.w *= g;
        }
        sT[c4 * 4 + 0][r] = v.x; sT[c4 * 4 + 1][r] = v.y;
        sT[c4 * 4 + 2][r] = v.z; sT[c4 * 4 + 3][r] = v.w;
    }
    __syncthreads();
    int cg = tid & 31;
    int rg = tid >> 5;
    float acc[8][4];
#pragma unroll
    for (int i = 0; i < 8; ++i)
#pragma unroll
        for (int j = 0; j < 4; ++j) acc[i][j] = 0.f;

#pragma unroll 4
    for (int k = 0; k < 128; ++k) {
        float4 w4 = ((const float4*)(W + k * H))[cg];
        const float4* pa = (const float4*)(&sT[k][rg * 8]);
        float4 a0 = pa[0], a1 = pa[1];
        float av[8] = {a0.x, a0.y, a0.z, a0.w, a1.x, a1.y, a1.z, a1.w};
#pragma unroll
        for (int i = 0; i < 8; ++i) {
            acc[i][0] = fmaf(av[i], w4.x, acc[i][0]);
            acc[i][1] = fmaf(av[i], w4.y, acc[i][1]);
            acc[i][2] = fmaf(av[i], w4.z, acc[i][2]);
            acc[i][3] = fmaf(av[i], w4.w, acc[i][3]);
        }
    }
#pragma unroll
    for (int i = 0; i < 8; ++i) {
        int row = row0 + rg * 8 + i;
        if (row < nrows) {
            float4 o = make_float4(acc[i][0], acc[i][1], acc[i][2], acc[i][3]);
            ((float4*)(out + (size_t)row * H))[cg] = o;
        }
    }
}

// ---------------- GEMM (compacted rows): only active-list rows; per-row math identical ------

__global__ __launch_bounds__(256) void gemm128c_kernel(const float* __restrict__ A,
                                                       const float* __restrict__ W,
                                                       const float* __restrict__ gf,
                                                       const int* __restrict__ alist,
                                                       const int* __restrict__ alcnt,
                                                       float* __restrict__ out) {
    int nact = *alcnt;
    int row0 = blockIdx.x * 64;
    if (row0 >= nact) return;
    __shared__ float sT[128][68];
    __shared__ int ridx[64];
    int tid = threadIdx.x;
    if (tid < 64) ridx[tid] = (row0 + tid < nact) ? alist[row0 + tid] : -1;
    __syncthreads();
    for (int i = tid; i < 2048; i += 256) {
        int r = i >> 5, c4 = i & 31;
        int row = ridx[r];
        float4 v = make_float4(0.f, 0.f, 0.f, 0.f);
        if (row >= 0) {
            float g = gf[row];
            v = ((const float4*)(A + (size_t)row * H))[c4];
            v.x *= g; v.y *= g; v.z *= g; v.w *= g;
        }
        sT[c4 * 4 + 0][r] = v.x; sT[c4 * 4 + 1][r] = v.y;
        sT[c4 * 4 + 2][r] = v.z; sT[c4 * 4 + 3][r] = v.w;
    }
    __syncthreads();
    int cg = tid & 31;
    int rg = tid >> 5;
    float acc[8][4];
#pragma unroll
    for (int i = 0; i < 8; ++i)
#pragma unroll
        for (int j = 0; j < 4; ++j) acc[i][j] = 0.f;

#pragma unroll 4
    for (int k = 0; k < 128; ++k) {
        float4 w4 = ((const float4*)(W + k * H))[cg];
        const float4* pa = (const float4*)(&sT[k][rg * 8]);
        float4 a0 = pa[0], a1 = pa[1];
        float av[8] = {a0.x, a0.y, a0.z, a0.w, a1.x, a1.y, a1.z, a1.w};
#pragma unroll
        for (int i = 0; i < 8; ++i) {
            acc[i][0] = fmaf(av[i], w4.x, acc[i][0]);
            acc[i][1] = fmaf(av[i], w4.y, acc[i][1]);
            acc[i][2] = fmaf(av[i], w4.z, acc[i][2]);
            acc[i][3] = fmaf(av[i], w4.w, acc[i][3]);
        }
    }
#pragma unroll
    for (int i = 0; i < 8; ++i) {
        int row = ridx[rg * 8 + i];
        if (row >= 0) {
            float4 o = make_float4(acc[i][0], acc[i][1], acc[i][2], acc[i][3]);
            ((float4*)(out + (size_t)row * H))[cg] = o;
        }
    }
}

// ---------------- fused gather agg + self + bias + relu + score-dot ----------------
// 8 nodes/block, 32 threads/node, 4-edge unroll. GUARD=true skips loads for
// masked sources (bit-exact: c==0 contributes exactly 0); GUARD=false for the
// first block where mask is all-ones (no branch overhead).

template <bool GUARD>
__global__ __launch_bounds__(256) void agg_fused_kernel(const float* __restrict__ xw,
        const int* __restrict__ rowptr, const int* __restrict__ srcC,
        const float* __restrict__ mask, const float* __restrict__ norm,
        const float* __restrict__ mnorm,
        const float* __restrict__ b, const float* __restrict__ Ws,
        float* __restrict__ hout, float* __restrict__ xws, int n) {
    int node = blockIdx.x * 8 + (threadIdx.x >> 5);
    if (node >= n) return;
    int t = threadIdx.x & 31;
    const float4* xw4 = (const float4*)xw;
    float md = mask[node];
    float nd = norm[node];
    float4 a0 = make_float4(0.f, 0.f, 0.f, 0.f);
    float4 a1 = a0, a2 = a0, a3 = a0;
    if (md != 0.f) {
        int e0 = rowptr[node], e1 = rowptr[node + 1];
        int e = e0;
        for (; e + 3 < e1; e += 4) {
            int s0 = srcC[e], s1 = srcC[e + 1], s2 = srcC[e + 2], s3 = srcC[e + 3];
            float c0 = mnorm[s0];
            float c1 = mnorm[s1];
            float c2 = mnorm[s2];
            float c3 = mnorm[s3];
            if (!GUARD || c0 != 0.f) {
                float4 v = xw4[(size_t)s0 * 32 + t];
                a0.x = fmaf(v.x, c0, a0.x); a0.y = fmaf(v.y, c0, a0.y);
                a0.z = fmaf(v.z, c0, a0.z); a0.w = fmaf(v.w, c0, a0.w);
            }
            if (!GUARD || c1 != 0.f) {
                float4 v = xw4[(size_t)s1 * 32 + t];
                a1.x = fmaf(v.x, c1, a1.x); a1.y = fmaf(v.y, c1, a1.y);
                a1.z = fmaf(v.z, c1, a1.z); a1.w = fmaf(v.w, c1, a1.w);
            }
            if (!GUARD || c2 != 0.f) {
                float4 v = xw4[(size_t)s2 * 32 + t];
                a2.x = fmaf(v.x, c2, a2.x); a2.y = fmaf(v.y, c2, a2.y);
                a2.z = fmaf(v.z, c2, a2.z); a2.w = fmaf(v.w, c2, a2.w);
            }
            if (!GUARD || c3 != 0.f) {
                float4 v = xw4[(size_t)s3 * 32 + t];
                a3.x = fmaf(v.x, c3, a3.x); a3.y = fmaf(v.y, c3, a3.y);
                a3.z = fmaf(v.z, c3, a3.z); a3.w = fmaf(v.w, c3, a3.w);
            }
        }
        for (; e < e1; ++e) {
            int s = srcC[e];
            float c = mnorm[s];
            if (!GUARD || c != 0.f) {
                float4 v = xw4[(size_t)s * 32 + t];
                a0.x = fmaf(v.x, c, a0.x); a0.y = fmaf(v.y, c, a0.y);
                a0.z = fmaf(v.z, c, a0.z); a0.w = fmaf(v.w, c, a0.w);
            }
        }
        float sc = md * nd;
        a0.x = (((a0.x + a1.x) + a2.x) + a3.x) * sc;
        a0.y = (((a0.y + a1.y) + a2.y) + a3.y) * sc;
        a0.z = (((a0.z + a1.z) + a2.z) + a3.z) * sc;
        a0.w = (((a0.w + a1.w) + a2.w) + a3.w) * sc;
    }
    float4 self = xw4[(size_t)node * 32 + t];
    float4 bb = ((const float4*)b)[t];
    float n2 = nd * nd;
    float4 v;
    v.x = fmaxf(fmaf(self.x, n2, a0.x) + bb.x, 0.f);
    v.y = fmaxf(fmaf(self.y, n2, a0.y) + bb.y, 0.f);
    v.z = fmaxf(fmaf(self.z, n2, a0.z) + bb.z, 0.f);
    v.w = fmaxf(fmaf(self.w, n2, a0.w) + bb.w, 0.f);
    ((float4*)hout)[(size_t)node * 32 + t] = v;
    // fused score projection: xws[node] = dot(hout_row, Ws)
    float4 w = ((const float4*)Ws)[t];
    float p = ((v.x * w.x + v.y * w.y) + v.z * w.z) + v.w * w.w;
#pragma unroll
    for (int o = 16; o > 0; o >>= 1) p += __shfl_down(p, o, 32);
    if (t == 0) xws[node] = p;
}

// ---------------- score gather: 8 lanes per node -> masked score ----------------

__global__ void score_gather_kernel(const int* __restrict__ rowptr, const int* __restrict__ srcC,
        const float* __restrict__ xws, const float* __restrict__ mask,
        const float* __restrict__ norm, const float* __restrict__ mnorm,
        const float* __restrict__ bs, float* __restrict__ scorem, int n) {
    int idx = blockIdx.x * 256 + threadIdx.x;
    int d = idx >> 3;
    if (d >= n) return;
    int l = idx & 7;
    float md = mask[d];
    float nd = norm[d];
    float acc = 0.f;
    if (md != 0.f) {
        int e0 = rowptr[d], e1 = rowptr[d + 1];
        for (int e = e0 + l; e < e1; e += 8) {
            int s = srcC[e];
            float c = mnorm[s];
            if (c != 0.f) acc = fmaf(xws[s], c, acc);
        }
    }
#pragma unroll
    for (int o = 4; o > 0; o >>= 1) acc += __shfl_down(acc, o, 8);
    if (l == 0) {
        float out;
        if (md != 0.f) out = acc * (md * nd) + xws[d] * nd * nd + bs[0];
        else out = -INFINITY;
        scorem[d] = out;
    }
}

// ---------------- rank-based top-k (kk fused): one 64-lane wave per node ----------------
// Wave scans its graph's scores once: counts both rank and active total, derives
// kk = ceil(0.5*active) locally (integer-exact, identical to old kk_kernel).

__global__ __launch_bounds__(256) void rank_kernel(const float* __restrict__ scorem,
        const float* __restrict__ mask, const int* __restrict__ batch,
        const int* __restrict__ starts, const int* __restrict__ counts,
        float* __restrict__ nmask, float* __restrict__ gfac, int n) {
    int i = blockIdx.x * 4 + (threadIdx.x >> 6);
    if (i >= n) return;
    int lane = threadIdx.x & 63;
    float sci = scorem[i];
    if (sci == -INFINITY) {
        if (lane == 0) { nmask[i] = 0.f; gfac[i] = 0.f; }
        return;
    }
    int g = batch[i];
    int s0 = starts[g], cnt = counts[g];
    int r = 0, act = 0;
    for (int j = lane; j < cnt; j += 64) {
        float sj = scorem[s0 + j];
        if (sj != -INFINITY) {
            ++act;
            if (sj > sci || (sj == sci && (s0 + j) < i)) ++r;
        }
    }
#pragma unroll
    for (int o = 32; o > 0; o >>= 1) {
        r += __shfl_down(r, o);
        act += __shfl_down(act, o);
    }
    if (lane == 0) {
        int kk = (int)ceilf(0.5f * (float)act);
        bool keep = (r < kk);
        float m = mask[i];
        nmask[i] = keep ? m : 0.f;
        gfac[i] = keep ? tanhf(sci) * m : 0.f;
    }
}

// ---------------- readout phase 1: per-(graph, sub-slice) partials ----------------

__global__ __launch_bounds__(128) void readout_part_kernel(const float* __restrict__ h,
        const float* __restrict__ mask, const float* __restrict__ gfac,
        const int* __restrict__ starts, const int* __restrict__ counts,
        float* __restrict__ partS, float* __restrict__ partM, float* __restrict__ partC) {
    int g = blockIdx.x >> 4;
    int sub = blockIdx.x & (RSUB - 1);
    int f = threadIdx.x;
    int s0 = starts[g], cnt = counts[g];
    float s = 0.f, mx = -INFINITY, c = 0.f;
    for (int i = sub; i < cnt; i += RSUB) {
        float m = mask[s0 + i];
        if (m > 0.f) {
            float v = h[(size_t)(s0 + i) * H + f] * gfac[s0 + i];
            s += v; mx = fmaxf(mx, v); c += 1.f;
        }
    }
    size_t pidx = (size_t)blockIdx.x * H + f;
    partS[pidx] = s;
    partM[pidx] = mx;
    if (f == 0) partC[blockIdx.x] = c;
}

// ---------------- readout phase 2: combine partials in fixed order -> rbuf ----------------

__global__ __launch_bounds__(128) void readout_comb_kernel(const float* __restrict__ partS,
        const float* __restrict__ partM, const float* __restrict__ partC,
        float* __restrict__ r) {
    int g = blockIdx.x;
    int f = threadIdx.x;
    float S = 0.f, M = -INFINITY, C = 0.f;
    for (int sub = 0; sub < RSUB; ++sub) {
        size_t pidx = (size_t)(g * RSUB + sub) * H + f;
        S += partS[pidx];
        M = fmaxf(M, partM[pidx]);
        C += partC[g * RSUB + sub];
    }
    float mean = S / fmaxf(C, 1.f);
    if (C == 0.f) M = 0.f;
    r[(size_t)g * 2 * H + f] += M;
    r[(size_t)g * 2 * H + H + f] += mean;
}

// ---------------- MLP head + log_softmax ----------------

__global__ __launch_bounds__(128) void mlp_kernel(const float* __restrict__ r,
        const float* __restrict__ Wl1, const float* __restrict__ bl1,
        const float* __restrict__ Wl2, const float* __restrict__ bl2,
        const float* __restrict__ Wl3, const float* __restrict__ bl3,
        float* __restrict__ out) {
    int g = blockIdx.x;
    int t = threadIdx.x;
    __shared__ float sz[256];
    __shared__ float sy1[128];
    __shared__ float sy2[64];
    __shared__ float sy3[10];
    __shared__ float sred[2];
    sz[t] = r[g * 256 + t];
    sz[t + 128] = r[g * 256 + 128 + t];
    __syncthreads();
    float a = bl1[t];
    for (int k = 0; k < 256; ++k) a = fmaf(sz[k], Wl1[k * 128 + t], a);
    sy1[t] = fmaxf(a, 0.f);
    __syncthreads();
    if (t < 64) {
        float a2 = bl2[t];
        for (int k = 0; k < 128; ++k) a2 = fmaf(sy1[k], Wl2[k * 64 + t], a2);
        sy2[t] = fmaxf(a2, 0.f);
    }
    __syncthreads();
    if (t < 10) {
        float a3 = bl3[t];
        for (int k = 0; k < 64; ++k) a3 = fmaf(sy2[k], Wl3[k * 10 + t], a3);
        sy3[t] = a3;
    }
    __syncthreads();
    if (t == 0) {
        float m = sy3[0];
        for (int c2 = 1; c2 < 10; ++c2) m = fmaxf(m, sy3[c2]);
        float se = 0.f;
        for (int c2 = 0; c2 < 10; ++c2) se += expf(sy3[c2] - m);
        sred[0] = m; sred[1] = logf(se);
    }
    __syncthreads();
    if (t < 10) out[g * 10 + t] = sy3[t] - sred[0] - sred[1];
}

// ---------------- launch ----------------

extern "C" void kernel_launch(void* const* d_in, const int* in_sizes, int n_in,
                              void* d_out, int out_size, void* d_ws, size_t ws_size,
                              hipStream_t stream) {
    const float* x     = (const float*)d_in[0];
    const int*   ei    = (const int*)d_in[1];
    const int*   batch = (const int*)d_in[2];
    const int* src  = ei;
    const int* dstp = ei + N_EDGES;
    const float* Wb[3]  = {(const float*)d_in[3], (const float*)d_in[7],  (const float*)d_in[11]};
    const float* bbv[3] = {(const float*)d_in[4], (const float*)d_in[8],  (const float*)d_in[12]};
    const float* Wsb[3] = {(const float*)d_in[5], (const float*)d_in[9],  (const float*)d_in[13]};
    const float* bsb[3] = {(const float*)d_in[6], (const float*)d_in[10], (const float*)d_in[14]};
    const float* Wl1 = (const float*)d_in[15];
    const float* bl1 = (const float*)d_in[16];
    const float* Wl2 = (const float*)d_in[17];
    const float* bl2 = (const float*)d_in[18];
    const float* Wl3 = (const float*)d_in[19];
    const float* bl3 = (const float*)d_in[20];
    float* out = (float*)d_out;

    // workspace carve (4B units)
    float* fws = (float*)d_ws;
    size_t off = 0;
    float* hA     = fws + off; off += (size_t)N_NODES * H;
    float* hB     = fws + off; off += (size_t)N_NODES * H;
    float* xw     = fws + off; off += (size_t)N_NODES * H;
    float* scorem = fws + off; off += N_NODES;
    float* xws    = fws + off; off += N_NODES;
    float* norm   = fws + off; off += N_NODES;
    float* mnorm  = fws + off; off += N_NODES;
    float* mA     = fws + off; off += N_NODES;
    float* mB     = fws + off; off += N_NODES;
    float* gfac   = fws + off; off += N_NODES;
    float* rbuf   = fws + off; off += (size_t)G_GRAPHS * 2 * H;
    float* partS  = fws + off; off += (size_t)G_GRAPHS * RSUB * H;
    float* partM  = fws + off; off += (size_t)G_GRAPHS * RSUB * H;
    float* partC  = fws + off; off += (size_t)G_GRAPHS * RSUB;
    int* counts   = (int*)(fws + off); off += G_GRAPHS;
    int* starts   = (int*)(fws + off); off += G_GRAPHS;
    int* rowptr   = (int*)(fws + off); off += N_NODES + 1;
    int* indeg    = (int*)(fws + off); off += N_NODES;
    int* cursor   = (int*)(fws + off); off += N_NODES;
    int* bsum     = (int*)(fws + off); off += NBLK_SCAN;
    int* boff     = (int*)(fws + off); off += NBLK_SCAN;
    int* alist    = (int*)(fws + off); off += N_NODES;
    int* alcnt    = (int*)(fws + off); off += 1;
    int* srcC     = (int*)(fws + off); off += N_EDGES;

    int nblkN  = (N_NODES + 255) / 256;
    int nblkN8 = (N_NODES * 8 + 255) / 256;
    int nblkE  = (N_EDGES + 255) / 256;
    int nblkG  = (N_NODES + 63) / 64;

    // graph segment structure (batch is sorted -> boundary detect, no atomics)
    starts_kernel<<<nblkN, 256, 0, stream>>>(batch, starts, N_NODES);
    counts_kernel<<<1, 128, 0, stream>>>(starts, counts);

    // CSR build (dst-grouped), deterministic via per-node wave sort
    hipMemsetAsync(indeg, 0, N_NODES * sizeof(int), stream);
    hipMemsetAsync(cursor, 0, N_NODES * sizeof(int), stream);
    indeg_kernel<<<nblkE, 256, 0, stream>>>(dstp, indeg, N_EDGES);
    bsum_kernel<<<NBLK_SCAN, 256, 0, stream>>>(indeg, bsum, N_NODES);
    bscan_kernel<<<1, 256, 0, stream>>>(bsum, boff, NBLK_SCAN);
    rowptr_kernel<<<NBLK_SCAN, 256, 0, stream>>>(indeg, boff, rowptr, N_NODES);
    scatter_kernel<<<nblkE, 256, 0, stream>>>(src, dstp, rowptr, cursor, srcC, N_EDGES);
    wsort_kernel<<<(N_NODES + 3) / 4, 256, 0, stream>>>(rowptr, srcC, N_NODES);

    fill_kernel<<<nblkN, 256, 0, stream>>>(mA, 1.f, N_NODES);
    fill_kernel<<<nblkN, 256, 0, stream>>>(gfac, 1.f, N_NODES);
    hipMemsetAsync(rbuf, 0, G_GRAPHS * 2 * H * sizeof(float), stream);

    const float* hin = x;
    float* hout = hA;
    const float* mcur = mA;
    float* mnext = mB;

    for (int blk = 0; blk < 3; ++blk) {
        degnorm_kernel<<<nblkN8, 256, 0, stream>>>(rowptr, srcC, mcur, norm, mnorm, N_NODES);
        if (blk == 0) {
            gemm128_kernel<<<nblkG, 256, 0, stream>>>(hin, Wb[blk], gfac, xw, N_NODES);
            agg_fused_kernel<false><<<(N_NODES + 7) / 8, 256, 0, stream>>>(
                xw, rowptr, srcC, mcur, norm, mnorm, bbv[blk], Wsb[blk], hout, xws, N_NODES);
        } else {
            gemm128c_kernel<<<nblkG, 256, 0, stream>>>(hin, Wb[blk], gfac, alist, alcnt, xw);
            agg_fused_kernel<true><<<(N_NODES + 7) / 8, 256, 0, stream>>>(
                xw, rowptr, srcC, mcur, norm, mnorm, bbv[blk], Wsb[blk], hout, xws, N_NODES);
        }
        score_gather_kernel<<<nblkN8, 256, 0, stream>>>(rowptr, srcC, xws, mcur, norm, mnorm,
                                                        bsb[blk], scorem, N_NODES);
        rank_kernel<<<(N_NODES + 3) / 4, 256, 0, stream>>>(scorem, mcur, batch, starts, counts,
                                                           mnext, gfac, N_NODES);
        if (blk < 2) {
            hipMemsetAsync(alcnt, 0, sizeof(int), stream);
            compact_kernel<<<nblkN, 256, 0, stream>>>(mnext, alist, alcnt, N_NODES);
        }
        readout_part_kernel<<<G_GRAPHS * RSUB, 128, 0, stream>>>(hout, mnext, gfac, starts,
                                                                 counts, partS, partM, partC);
        readout_comb_kernel<<<G_GRAPHS, 128, 0, stream>>>(partS, partM, partC, rbuf);
        hin = hout;
        hout = (hout == hA) ? hB : hA;
        const float* tm = mcur; mcur = mnext; mnext = (float*)tm;
    }

    mlp_kernel<<<G_GRAPHS, 128, 0, stream>>>(rbuf, Wl1, bl1, Wl2, bl2, Wl3, bl3, out);
}